// Round 2
// baseline (722.826 us; speedup 1.0000x reference)
//
#include <hip/hip_runtime.h>
#include <math.h>

#define B 64
#define S 1024
#define H 512
#define OUT 256
#define STEPS 32
#define NG 2048   // 4*H
#define X 768     // OUT + H

__device__ __forceinline__ float sigf(float x) { return 1.0f / (1.0f + __expf(-x)); }

// ---------------- context: flash softmax-weighted sum over S ----------------
__global__ __launch_bounds__(256) void k_ctx_partial(
    const float* __restrict__ enc, const float* __restrict__ attn_w,
    float* __restrict__ part_ctx, float* __restrict__ part_ml) {
  const int b = blockIdx.y, chunk = blockIdx.x;
  const int wave = threadIdx.x >> 6, lane = threadIdx.x & 63;
  const float4 wa0 = *(const float4*)(attn_w + lane * 8);
  const float4 wa1 = *(const float4*)(attn_w + lane * 8 + 4);
  const float* eb = enc + (long)b * S * H;
  float m = -1e30f, l = 0.0f;
  float acc[8];
#pragma unroll
  for (int r = 0; r < 8; ++r) acc[r] = 0.0f;
  for (int i = 0; i < 32; ++i) {
    const int s = chunk * 128 + i * 4 + wave;
    const float* row = eb + (long)s * H + lane * 8;
    const float4 v0 = *(const float4*)row;
    const float4 v1 = *(const float4*)(row + 4);
    float e = v0.x * wa0.x + v0.y * wa0.y + v0.z * wa0.z + v0.w * wa0.w +
              v1.x * wa1.x + v1.y * wa1.y + v1.z * wa1.z + v1.w * wa1.w;
#pragma unroll
    for (int msk = 1; msk < 64; msk <<= 1) e += __shfl_xor(e, msk, 64);
    const float mn = fmaxf(m, e);
    const float sc = __expf(m - mn);
    const float p = __expf(e - mn);
    l = l * sc + p;
    m = mn;
    acc[0] = acc[0] * sc + p * v0.x; acc[1] = acc[1] * sc + p * v0.y;
    acc[2] = acc[2] * sc + p * v0.z; acc[3] = acc[3] * sc + p * v0.w;
    acc[4] = acc[4] * sc + p * v1.x; acc[5] = acc[5] * sc + p * v1.y;
    acc[6] = acc[6] * sc + p * v1.z; acc[7] = acc[7] * sc + p * v1.w;
  }
  __shared__ float sm_acc[4][H];
  __shared__ float sm_m[4], sm_l[4];
#pragma unroll
  for (int r = 0; r < 8; ++r) sm_acc[wave][lane * 8 + r] = acc[r];
  if (lane == 0) { sm_m[wave] = m; sm_l[wave] = l; }
  __syncthreads();
  const float mb = fmaxf(fmaxf(sm_m[0], sm_m[1]), fmaxf(sm_m[2], sm_m[3]));
  float e0[4];
#pragma unroll
  for (int w = 0; w < 4; ++w) e0[w] = __expf(sm_m[w] - mb);
  const int h0 = threadIdx.x * 2;
  float s0 = 0.f, s1 = 0.f;
#pragma unroll
  for (int w = 0; w < 4; ++w) { s0 += sm_acc[w][h0] * e0[w]; s1 += sm_acc[w][h0 + 1] * e0[w]; }
  float* pc = part_ctx + ((long)chunk * B + b) * H;
  pc[h0] = s0; pc[h0 + 1] = s1;
  if (threadIdx.x == 0) {
    const float lb = sm_l[0] * e0[0] + sm_l[1] * e0[1] + sm_l[2] * e0[2] + sm_l[3] * e0[3];
    part_ml[(chunk * B + b) * 2] = mb;
    part_ml[(chunk * B + b) * 2 + 1] = lb;
  }
}

__global__ __launch_bounds__(256) void k_ctx_reduce(
    const float* __restrict__ part_ctx, const float* __restrict__ part_ml,
    float* __restrict__ ctx) {
  const int b = blockIdx.x;
  float m = -1e30f;
#pragma unroll
  for (int c = 0; c < 8; ++c) m = fmaxf(m, part_ml[(c * B + b) * 2]);
  float L = 0.f, sc[8];
#pragma unroll
  for (int c = 0; c < 8; ++c) {
    sc[c] = __expf(part_ml[(c * B + b) * 2] - m);
    L += part_ml[(c * B + b) * 2 + 1] * sc[c];
  }
  const float inv = 1.0f / L;
  const int h0 = threadIdx.x * 2;
  float s0 = 0.f, s1 = 0.f;
#pragma unroll
  for (int c = 0; c < 8; ++c) {
    const float* pc = part_ctx + ((long)c * B + b) * H;
    s0 += pc[h0] * sc[c]; s1 += pc[h0 + 1] * sc[c];
  }
  ctx[(long)b * H + h0] = s0 * inv;
  ctx[(long)b * H + h0 + 1] = s1 * inv;
}

// ---------------- Weff = w_hh + Wd @ fc_w  (2048 x 512) ----------------
__global__ __launch_bounds__(256) void k_weff(
    const float* __restrict__ w_ih, const float* __restrict__ w_hh,
    const float* __restrict__ fc_w, float* __restrict__ weff) {
  const int flat4 = blockIdx.x * 256 + threadIdx.x;
  const int n = flat4 >> 7;
  const int k = (flat4 & 127) << 2;
  const float* wd = w_ih + (long)n * X;
  float ax = 0.f, ay = 0.f, az = 0.f, aw = 0.f;
  for (int j = 0; j < OUT; ++j) {
    const float w = wd[j];
    const float4 f = *(const float4*)(fc_w + (long)j * H + k);
    ax = fmaf(w, f.x, ax); ay = fmaf(w, f.y, ay);
    az = fmaf(w, f.z, az); aw = fmaf(w, f.w, aw);
  }
  const float4 hh = *(const float4*)(w_hh + (long)n * H + k);
  float4 o; o.x = ax + hh.x; o.y = ay + hh.y; o.z = az + hh.z; o.w = aw + hh.w;
  *(float4*)(weff + (long)n * H + k) = o;
}

// ---------------- gbase / gbase2 ----------------
__global__ __launch_bounds__(256) void k_gbase(
    const float* __restrict__ w_ih, const float* __restrict__ b_ih,
    const float* __restrict__ b_hh, const float* __restrict__ fc_b,
    const float* __restrict__ ctx, float* __restrict__ gbase,
    float* __restrict__ gbase2) {
  __shared__ float lctx[16][H + 4];
  const int nt = blockIdx.x, bq = blockIdx.y;
  for (int i = threadIdx.x; i < 16 * 128; i += 256) {
    const int bb = i >> 7, kk = (i & 127) << 2;
    *(float4*)&lctx[bb][kk] = *(const float4*)(ctx + (long)(bq * 16 + bb) * H + kk);
  }
  __syncthreads();
  const int n_l = threadIdx.x & 15, b_l = threadIdx.x >> 4;
  const int n = nt * 16 + n_l;
  const float* wr = w_ih + (long)n * X;
  float acc = 0.f;
  for (int k = 0; k < H; k += 4) {
    const float4 c4 = *(float4*)&lctx[b_l][k];
    const float4 w4 = *(const float4*)(wr + OUT + k);
    acc += c4.x * w4.x + c4.y * w4.y + c4.z * w4.z + c4.w * w4.w;
  }
  float db = 0.f;
  for (int j = 0; j < OUT; j += 4) {
    const float4 w4 = *(const float4*)(wr + j);
    const float4 f4v = *(const float4*)(fc_b + j);
    db += w4.x * f4v.x + w4.y * f4v.y + w4.z * f4v.z + w4.w * f4v.w;
  }
  const float g = acc + b_ih[n] + b_hh[n];
  const int b = bq * 16 + b_l;
  gbase[(long)b * NG + n] = g;
  gbase2[(long)b * NG + n] = g + db;
}

// ---------------- persistent cooperative recurrence ----------------
// 256 blocks x 512 thr, 1 block/CU. Block = (bgroup = blk>>5 : 8 batches,
// cslice = blk&31 : 16 hidden cols -> 64 gate rows, LDS-resident weights).
// Per-step sync: per-bgroup 32-block barrier on agent-scope atomics.
#define WSTR 516   // padded row stride (floats) for W and h tiles
__global__ __launch_bounds__(512, 1) void k_recur(
    const float* __restrict__ hidden, const float* __restrict__ w_hh,
    const float* __restrict__ weff, const float* __restrict__ gbase,
    const float* __restrict__ gbase2, float* __restrict__ hs,
    unsigned int* __restrict__ bar) {
  extern __shared__ float smem[];
  float* sW = smem;                 // 64 * 516 = 33024
  float* sh = sW + 64 * WSTR;       // 8 * 516  = 4128
  float* sgb = sh + 8 * WSTR;       // 2 * 8 * 64 = 1024
  float* sG = sgb + 1024;           // 8 * 68 = 544
  float* scell = sG + 8 * 68;       // 128

  const int blk = blockIdx.x;
  const int bgroup = blk >> 5;          // 0..7
  const int b8 = bgroup << 3;           // first batch
  const int hc0 = (blk & 31) << 4;      // first hidden col
  const int tid = threadIdx.x;

  // prologue: step-0 weights (w_hh) and both gbase slices
  for (int idx = tid; idx < 64 * 128; idx += 512) {
    const int r = idx >> 7, k4 = idx & 127;
    const int g = r >> 4, j = r & 15;
    *(float4*)(sW + r * WSTR + (k4 << 2)) =
        *(const float4*)(w_hh + (long)((g << 9) + hc0 + j) * H + (k4 << 2));
  }
  for (int idx = tid; idx < 1024; idx += 512) {
    const int ph = idx >> 9, rem = idx & 511;
    const int b = rem >> 6, gr = rem & 63;
    const int g = gr >> 4, j = gr & 15;
    const long col = (long)(g << 9) + hc0 + j;
    const float* src = ph ? gbase2 : gbase;
    sgb[idx] = src[(long)(b8 + b) * NG + col];
  }

  const int db = tid & 7;        // batch within group
  const int gr = tid >> 3;       // gate-row 0..63 (g = gr>>4, j = gr&15)

  for (int t = 0; t < STEPS; ++t) {
    if (t == 1) {  // switch to Weff for steps 1..31
      for (int idx = tid; idx < 64 * 128; idx += 512) {
        const int r = idx >> 7, k4 = idx & 127;
        const int g = r >> 4, j = r & 15;
        *(float4*)(sW + r * WSTR + (k4 << 2)) =
            *(const float4*)(weff + (long)((g << 9) + hc0 + j) * H + (k4 << 2));
      }
    }
    // stage h (8 rows)
    const float* hsrc = (t == 0) ? hidden : (hs + (long)(t - 1) * B * H);
    for (int idx = tid; idx < 8 * 128; idx += 512) {
      const int bb = idx >> 7, k4 = idx & 127;
      *(float4*)(sh + bb * WSTR + (k4 << 2)) =
          *(const float4*)(hsrc + (long)(b8 + bb) * H + (k4 << 2));
    }
    __syncthreads();
    // dot: one gate value per thread
    const float4* wr4 = (const float4*)(sW + gr * WSTR);
    const float4* hr4 = (const float4*)(sh + db * WSTR);
    float acc = 0.f;
#pragma unroll 8
    for (int k4 = 0; k4 < 128; ++k4) {
      const float4 w4 = wr4[k4];
      const float4 h4 = hr4[k4];
      acc = fmaf(h4.x, w4.x, fmaf(h4.y, w4.y, fmaf(h4.z, w4.z, fmaf(h4.w, w4.w, acc))));
    }
    const int ph = (t == 0) ? 0 : 1;
    sG[db * 68 + gr] = acc + sgb[(ph << 9) + (db << 6) + gr];
    __syncthreads();
    // cell update: 128 threads (8 b x 16 cols)
    if (tid < 128) {
      const int b = tid & 7, j = tid >> 3;
      const float gi = sG[b * 68 + j];
      const float gf = sG[b * 68 + 16 + j];
      const float gg = sG[b * 68 + 32 + j];
      const float go = sG[b * 68 + 48 + j];
      const float c_old = t ? scell[b * 16 + j] : 0.f;
      const float cn = sigf(gf) * c_old + sigf(gi) * tanhf(gg);
      const float hn = sigf(go) * tanhf(cn);
      scell[b * 16 + j] = cn;
      hs[(long)t * B * H + (long)(b8 + b) * H + hc0 + j] = hn;
    }
    __syncthreads();  // drain h stores (per-wave vmcnt(0) at barrier)
    if (t < STEPS - 1) {
      if (tid == 0) {
        unsigned int* flag = bar + (t << 3) + bgroup;
        __hip_atomic_fetch_add(flag, 1u, __ATOMIC_RELEASE, __HIP_MEMORY_SCOPE_AGENT);
        while (__hip_atomic_load(flag, __ATOMIC_RELAXED, __HIP_MEMORY_SCOPE_AGENT) < 32u) {
          __builtin_amdgcn_s_sleep(8);
        }
        (void)__hip_atomic_load(flag, __ATOMIC_ACQUIRE, __HIP_MEMORY_SCOPE_AGENT);
      }
      __syncthreads();
    }
  }
}

// ---------------- final dec GEMM: out[b,t,:] = hs[t,b,:] @ fc_w^T + fc_b ----
// M=2048 (m = t*64+b), N=256, K=512. grid (64 m-tiles of 32, 4 o-tiles of 64).
__global__ __launch_bounds__(256) void k_dec2(
    const float* __restrict__ hs, const float* __restrict__ fc_w,
    const float* __restrict__ fc_b, float* __restrict__ out) {
  __shared__ float A[32 * 68];
  __shared__ float Bm[64 * 68];
  const int m0 = blockIdx.x * 32;
  const int o0 = blockIdx.y * 64;
  const int tid = threadIdx.x;
  const int tn = tid & 15, tm = tid >> 4;
  float acc[2][4] = {{0.f, 0.f, 0.f, 0.f}, {0.f, 0.f, 0.f, 0.f}};
  for (int k0 = 0; k0 < H; k0 += 64) {
    for (int idx = tid; idx < 512; idx += 256) {
      const int r = idx >> 4, k4 = idx & 15;
      *(float4*)&A[r * 68 + k4 * 4] =
          *(const float4*)&hs[(long)(m0 + r) * H + k0 + k4 * 4];
    }
    for (int idx = tid; idx < 1024; idx += 256) {
      const int r = idx >> 4, k4 = idx & 15;
      *(float4*)&Bm[r * 68 + k4 * 4] =
          *(const float4*)&fc_w[(long)(o0 + r) * H + k0 + k4 * 4];
    }
    __syncthreads();
#pragma unroll
    for (int k4 = 0; k4 < 16; ++k4) {
      const float4 a0 = *(float4*)&A[tm * 68 + k4 * 4];
      const float4 a1 = *(float4*)&A[(tm + 16) * 68 + k4 * 4];
      const float4 b0 = *(float4*)&Bm[tn * 68 + k4 * 4];
      const float4 b1 = *(float4*)&Bm[(tn + 16) * 68 + k4 * 4];
      const float4 b2 = *(float4*)&Bm[(tn + 32) * 68 + k4 * 4];
      const float4 b3 = *(float4*)&Bm[(tn + 48) * 68 + k4 * 4];
      acc[0][0] += a0.x * b0.x + a0.y * b0.y + a0.z * b0.z + a0.w * b0.w;
      acc[0][1] += a0.x * b1.x + a0.y * b1.y + a0.z * b1.z + a0.w * b1.w;
      acc[0][2] += a0.x * b2.x + a0.y * b2.y + a0.z * b2.z + a0.w * b2.w;
      acc[0][3] += a0.x * b3.x + a0.y * b3.y + a0.z * b3.z + a0.w * b3.w;
      acc[1][0] += a1.x * b0.x + a1.y * b0.y + a1.z * b0.z + a1.w * b0.w;
      acc[1][1] += a1.x * b1.x + a1.y * b1.y + a1.z * b1.z + a1.w * b1.w;
      acc[1][2] += a1.x * b2.x + a1.y * b2.y + a1.z * b2.z + a1.w * b2.w;
      acc[1][3] += a1.x * b3.x + a1.y * b3.y + a1.z * b3.z + a1.w * b3.w;
    }
    __syncthreads();
  }
#pragma unroll
  for (int i = 0; i < 2; ++i) {
    const int m = m0 + tm + 16 * i;
    const int t = m >> 6, b = m & 63;
#pragma unroll
    for (int j = 0; j < 4; ++j) {
      const int o = o0 + tn + 16 * j;
      out[((long)b * STEPS + t) * OUT + o] = acc[i][j] + fc_b[o];
    }
  }
}

extern "C" void kernel_launch(void* const* d_in, const int* in_sizes, int n_in,
                              void* d_out, int out_size, void* d_ws, size_t ws_size,
                              hipStream_t stream) {
  const float* enc = (const float*)d_in[0];
  const float* hidden = (const float*)d_in[1];
  const float* attn_w = (const float*)d_in[2];
  // d_in[3] = attn_b: constant shift along softmax axis -> irrelevant.
  const float* w_ih = (const float*)d_in[4];
  const float* w_hh = (const float*)d_in[5];
  const float* b_ih = (const float*)d_in[6];
  const float* b_hh = (const float*)d_in[7];
  const float* fc_w = (const float*)d_in[8];
  const float* fc_b = (const float*)d_in[9];
  float* out = (float*)d_out;

  float* ws = (float*)d_ws;
  float* ctx      = ws;                  // 32768
  float* part_ctx = ctx + 32768;         // 262144
  float* part_ml  = part_ctx + 262144;   // 1024
  float* weff     = part_ml + 1024;      // 1048576
  float* gbase    = weff + 1048576;      // 131072
  float* gbase2   = gbase + 131072;      // 131072
  float* hs       = gbase2 + 131072;     // 32*32768 = 1048576
  unsigned int* bar = (unsigned int*)(hs + 1048576);  // 256 uints

  hipMemsetAsync(bar, 0, 256 * sizeof(unsigned int), stream);

  k_ctx_partial<<<dim3(8, 64), 256, 0, stream>>>(enc, attn_w, part_ctx, part_ml);
  k_weff<<<1024, 256, 0, stream>>>(w_ih, w_hh, fc_w, weff);
  k_ctx_reduce<<<64, 256, 0, stream>>>(part_ctx, part_ml, ctx);
  k_gbase<<<dim3(128, 4), 256, 0, stream>>>(w_ih, b_ih, b_hh, fc_b, ctx, gbase, gbase2);

  // persistent cooperative recurrence
  const unsigned int shbytes = (64 * WSTR + 8 * WSTR + 1024 + 8 * 68 + 128) * 4;
  hipFuncSetAttribute(reinterpret_cast<const void*>(k_recur),
                      hipFuncAttributeMaxDynamicSharedMemorySize, shbytes);
  const float* hidden_p = hidden;
  const float* whh_p = w_hh;
  const float* weff_p = weff;
  const float* gbase_p = gbase;
  const float* gbase2_p = gbase2;
  float* hs_p = hs;
  unsigned int* bar_p = bar;
  void* kargs[] = {(void*)&hidden_p, (void*)&whh_p, (void*)&weff_p,
                   (void*)&gbase_p, (void*)&gbase2_p, (void*)&hs_p, (void*)&bar_p};
  hipLaunchCooperativeKernel(reinterpret_cast<const void*>(k_recur), dim3(256),
                             dim3(512), kargs, shbytes, stream);

  k_dec2<<<dim3(64, 4), 256, 0, stream>>>(hs, fc_w, fc_b, out);
}

// Round 3
// 563.550 us; speedup vs baseline: 1.2826x; 1.2826x over previous
//
#include <hip/hip_runtime.h>
#include <math.h>

#define B 64
#define S 1024
#define H 512
#define OUT 256
#define STEPS 32
#define NG 2048   // 4*H
#define X 768     // OUT + H

typedef __attribute__((ext_vector_type(8))) short short8;   // 8 bf16 = 4 VGPR
typedef __attribute__((ext_vector_type(4))) short s16x4;
typedef __attribute__((ext_vector_type(4))) float f32x4;

__device__ __forceinline__ float sigf(float x) { return 1.0f / (1.0f + __expf(-x)); }

__device__ __forceinline__ short f2bf(float x) {  // RNE float->bf16 bits
  union { float f; unsigned u; } a; a.f = x;
  unsigned r = a.u + 0x7fffu + ((a.u >> 16) & 1u);
  return (short)(r >> 16);
}
__device__ __forceinline__ float bf2f(short s) {
  union { unsigned u; float f; } a; a.u = ((unsigned)(unsigned short)s) << 16;
  return a.f;
}

// ---------------- context: flash softmax-weighted sum over S ----------------
__global__ __launch_bounds__(256) void k_ctx_partial(
    const float* __restrict__ enc, const float* __restrict__ attn_w,
    float* __restrict__ part_ctx, float* __restrict__ part_ml) {
  const int b = blockIdx.y, chunk = blockIdx.x;
  const int wave = threadIdx.x >> 6, lane = threadIdx.x & 63;
  const float4 wa0 = *(const float4*)(attn_w + lane * 8);
  const float4 wa1 = *(const float4*)(attn_w + lane * 8 + 4);
  const float* eb = enc + (long)b * S * H;
  float m = -1e30f, l = 0.0f;
  float acc[8];
#pragma unroll
  for (int r = 0; r < 8; ++r) acc[r] = 0.0f;
  for (int i = 0; i < 32; ++i) {
    const int s = chunk * 128 + i * 4 + wave;
    const float* row = eb + (long)s * H + lane * 8;
    const float4 v0 = *(const float4*)row;
    const float4 v1 = *(const float4*)(row + 4);
    float e = v0.x * wa0.x + v0.y * wa0.y + v0.z * wa0.z + v0.w * wa0.w +
              v1.x * wa1.x + v1.y * wa1.y + v1.z * wa1.z + v1.w * wa1.w;
#pragma unroll
    for (int msk = 1; msk < 64; msk <<= 1) e += __shfl_xor(e, msk, 64);
    const float mn = fmaxf(m, e);
    const float sc = __expf(m - mn);
    const float p = __expf(e - mn);
    l = l * sc + p;
    m = mn;
    acc[0] = acc[0] * sc + p * v0.x; acc[1] = acc[1] * sc + p * v0.y;
    acc[2] = acc[2] * sc + p * v0.z; acc[3] = acc[3] * sc + p * v0.w;
    acc[4] = acc[4] * sc + p * v1.x; acc[5] = acc[5] * sc + p * v1.y;
    acc[6] = acc[6] * sc + p * v1.z; acc[7] = acc[7] * sc + p * v1.w;
  }
  __shared__ float sm_acc[4][H];
  __shared__ float sm_m[4], sm_l[4];
#pragma unroll
  for (int r = 0; r < 8; ++r) sm_acc[wave][lane * 8 + r] = acc[r];
  if (lane == 0) { sm_m[wave] = m; sm_l[wave] = l; }
  __syncthreads();
  const float mb = fmaxf(fmaxf(sm_m[0], sm_m[1]), fmaxf(sm_m[2], sm_m[3]));
  float e0[4];
#pragma unroll
  for (int w = 0; w < 4; ++w) e0[w] = __expf(sm_m[w] - mb);
  const int h0 = threadIdx.x * 2;
  float s0 = 0.f, s1 = 0.f;
#pragma unroll
  for (int w = 0; w < 4; ++w) { s0 += sm_acc[w][h0] * e0[w]; s1 += sm_acc[w][h0 + 1] * e0[w]; }
  float* pc = part_ctx + ((long)chunk * B + b) * H;
  pc[h0] = s0; pc[h0 + 1] = s1;
  if (threadIdx.x == 0) {
    const float lb = sm_l[0] * e0[0] + sm_l[1] * e0[1] + sm_l[2] * e0[2] + sm_l[3] * e0[3];
    part_ml[(chunk * B + b) * 2] = mb;
    part_ml[(chunk * B + b) * 2 + 1] = lb;
  }
}

__global__ __launch_bounds__(256) void k_ctx_reduce(
    const float* __restrict__ part_ctx, const float* __restrict__ part_ml,
    float* __restrict__ ctx) {
  const int b = blockIdx.x;
  float m = -1e30f;
#pragma unroll
  for (int c = 0; c < 8; ++c) m = fmaxf(m, part_ml[(c * B + b) * 2]);
  float L = 0.f, sc[8];
#pragma unroll
  for (int c = 0; c < 8; ++c) {
    sc[c] = __expf(part_ml[(c * B + b) * 2] - m);
    L += part_ml[(c * B + b) * 2 + 1] * sc[c];
  }
  const float inv = 1.0f / L;
  const int h0 = threadIdx.x * 2;
  float s0 = 0.f, s1 = 0.f;
#pragma unroll
  for (int c = 0; c < 8; ++c) {
    const float* pc = part_ctx + ((long)c * B + b) * H;
    s0 += pc[h0] * sc[c]; s1 += pc[h0 + 1] * sc[c];
  }
  ctx[(long)b * H + h0] = s0 * inv;
  ctx[(long)b * H + h0 + 1] = s1 * inv;
}

// ---------------- Weff = w_hh + Wd @ fc_w  (2048 x 512) ----------------
__global__ __launch_bounds__(256) void k_weff(
    const float* __restrict__ w_ih, const float* __restrict__ w_hh,
    const float* __restrict__ fc_w, float* __restrict__ weff) {
  const int flat4 = blockIdx.x * 256 + threadIdx.x;
  const int n = flat4 >> 7;
  const int k = (flat4 & 127) << 2;
  const float* wd = w_ih + (long)n * X;
  float ax = 0.f, ay = 0.f, az = 0.f, aw = 0.f;
  for (int j = 0; j < OUT; ++j) {
    const float w = wd[j];
    const float4 f = *(const float4*)(fc_w + (long)j * H + k);
    ax = fmaf(w, f.x, ax); ay = fmaf(w, f.y, ay);
    az = fmaf(w, f.z, az); aw = fmaf(w, f.w, aw);
  }
  const float4 hh = *(const float4*)(w_hh + (long)n * H + k);
  float4 o; o.x = ax + hh.x; o.y = ay + hh.y; o.z = az + hh.z; o.w = aw + hh.w;
  *(float4*)(weff + (long)n * H + k) = o;
}

// ---------------- gbase / gbase2 ----------------
__global__ __launch_bounds__(256) void k_gbase(
    const float* __restrict__ w_ih, const float* __restrict__ b_ih,
    const float* __restrict__ b_hh, const float* __restrict__ fc_b,
    const float* __restrict__ ctx, float* __restrict__ gbase,
    float* __restrict__ gbase2) {
  __shared__ float lctx[16][H + 4];
  const int nt = blockIdx.x, bq = blockIdx.y;
  for (int i = threadIdx.x; i < 16 * 128; i += 256) {
    const int bb = i >> 7, kk = (i & 127) << 2;
    *(float4*)&lctx[bb][kk] = *(const float4*)(ctx + (long)(bq * 16 + bb) * H + kk);
  }
  __syncthreads();
  const int n_l = threadIdx.x & 15, b_l = threadIdx.x >> 4;
  const int n = nt * 16 + n_l;
  const float* wr = w_ih + (long)n * X;
  float acc = 0.f;
  for (int k = 0; k < H; k += 4) {
    const float4 c4 = *(float4*)&lctx[b_l][k];
    const float4 w4 = *(const float4*)(wr + OUT + k);
    acc += c4.x * w4.x + c4.y * w4.y + c4.z * w4.z + c4.w * w4.w;
  }
  float db = 0.f;
  for (int j = 0; j < OUT; j += 4) {
    const float4 w4 = *(const float4*)(wr + j);
    const float4 f4v = *(const float4*)(fc_b + j);
    db += w4.x * f4v.x + w4.y * f4v.y + w4.z * f4v.z + w4.w * f4v.w;
  }
  const float g = acc + b_ih[n] + b_hh[n];
  const int b = bq * 16 + b_l;
  gbase[(long)b * NG + n] = g;
  gbase2[(long)b * NG + n] = g + db;
}

// ---------------- persistent cooperative recurrence (MFMA, reg-resident W) --
// 256 blocks x 256 thr (4 waves). Block = (bgroup = blk>>5 : 8 batches,
// colslice = blk&31 : 16 hidden cols). Wave w = gate w (i,f,g,o), owns the
// 16 gate rows {w*512 + hc0 + j}. Weights live in VGPRs as split-bf16 MFMA
// B-fragments for the whole kernel (w_hh for t=0, Weff after).
// Per step: stage h (fp32 global -> split-bf16 LDS), 16x(3 MFMA), cell update,
// per-bgroup 32-block barrier on agent-scope atomics.
#define HSTR 520  // shorts per h row (512 + 8 pad: bank spread, keeps 16B align)
__global__ __launch_bounds__(256, 1) void k_recur(
    const float* __restrict__ hidden, const float* __restrict__ w_hh,
    const float* __restrict__ weff, const float* __restrict__ gbase,
    const float* __restrict__ gbase2, float* __restrict__ hs,
    unsigned int* __restrict__ bar) {
  __shared__ short sh_hi[16 * HSTR];
  __shared__ short sh_lo[16 * HSTR];
  __shared__ float sG[4][8][20];
  __shared__ float sgb[2][8][64];
  __shared__ float scell[8][16];

  const int blk = blockIdx.x;
  const int bgroup = blk >> 5, b8 = bgroup << 3;
  const int hc0 = (blk & 31) << 4;
  const int tid = threadIdx.x;
  const int w = tid >> 6;        // wave = gate index 0..3
  const int l = tid & 63;
  const int ln = l & 15;         // A-row / B-col / D-col lane field
  const int lk = l >> 4;         // k-subgroup (0..3)

  // zero h tile once (rows 8..15 stay zero forever -> finite garbage-free A)
  for (int i = tid; i < 16 * HSTR; i += 256) { sh_hi[i] = 0; sh_lo[i] = 0; }

  // gbase slices into LDS: sgb[ph][b][g*16+j]
  for (int idx = tid; idx < 1024; idx += 256) {
    const int ph = idx >> 9, rem = idx & 511, b = rem >> 6, gr = rem & 63;
    const int g = gr >> 4, j = gr & 15;
    const float* src = ph ? gbase2 : gbase;
    sgb[ph][b][gr] = src[(long)(b8 + b) * NG + (g << 9) + hc0 + j];
  }

  // weight fragments: lane l elem e holds W[g*512+hc0+ln][32*kk + 8*lk + e]
  short8 wh[16], wl[16];
  auto load_w = [&](const float* Wm) {
    const float* wr = Wm + (long)((w << 9) + hc0 + ln) * H + (lk << 3);
#pragma unroll
    for (int kk = 0; kk < 16; ++kk) {
      float v[8];
      *(float4*)&v[0] = *(const float4*)(wr + kk * 32);
      *(float4*)&v[4] = *(const float4*)(wr + kk * 32 + 4);
#pragma unroll
      for (int e = 0; e < 8; ++e) {
        const short hb = f2bf(v[e]);
        wh[kk][e] = hb;
        wl[kk][e] = f2bf(v[e] - bf2f(hb));
      }
    }
  };
  load_w(w_hh);

  for (int t = 0; t < STEPS; ++t) {
    if (t == 1) load_w(weff);  // switch to folded weights for steps 1..31
    // stage h: fp32 global -> split bf16 LDS (8 rows x 512)
    const float* hsrc = t ? hs + (long)(t - 1) * B * H : hidden;
    for (int idx = tid; idx < 1024; idx += 256) {
      const int row = idx >> 7, kq = (idx & 127) << 2;
      float v[4];
      *(float4*)v = *(const float4*)(hsrc + (long)(b8 + row) * H + kq);
      s16x4 hi4, lo4;
#pragma unroll
      for (int e = 0; e < 4; ++e) {
        const short hb = f2bf(v[e]);
        hi4[e] = hb;
        lo4[e] = f2bf(v[e] - bf2f(hb));
      }
      *(s16x4*)&sh_hi[row * HSTR + kq] = hi4;
      *(s16x4*)&sh_lo[row * HSTR + kq] = lo4;
    }
    __syncthreads();

    // gates tile: D[b][j] = sum_k h[b][k] * W[row_j][k]
    f32x4 acc = {0.f, 0.f, 0.f, 0.f};
    const int abase = ln * HSTR + (lk << 3);
#pragma unroll
    for (int kk = 0; kk < 16; ++kk) {
      const short8 ah = *(const short8*)&sh_hi[abase + kk * 32];
      const short8 al = *(const short8*)&sh_lo[abase + kk * 32];
      acc = __builtin_amdgcn_mfma_f32_16x16x32_bf16(ah, wh[kk], acc, 0, 0, 0);
      acc = __builtin_amdgcn_mfma_f32_16x16x32_bf16(al, wh[kk], acc, 0, 0, 0);
      acc = __builtin_amdgcn_mfma_f32_16x16x32_bf16(ah, wl[kk], acc, 0, 0, 0);
    }
    // D layout: col = ln, row(batch) = lk*4 + r; batches 0..7 -> lk 0,1
    if (lk < 2) {
#pragma unroll
      for (int r = 0; r < 4; ++r) sG[w][(lk << 2) + r][ln] = acc[r];
    }
    __syncthreads();

    // cell update: 128 threads (8 b x 16 j)
    if (tid < 128) {
      const int b = tid >> 4, j = tid & 15;
      const int ph = t ? 1 : 0;
      const float gi = sG[0][b][j] + sgb[ph][b][j];
      const float gf = sG[1][b][j] + sgb[ph][b][16 + j];
      const float gg = sG[2][b][j] + sgb[ph][b][32 + j];
      const float go = sG[3][b][j] + sgb[ph][b][48 + j];
      const float c_old = t ? scell[b][j] : 0.f;
      const float cn = sigf(gf) * c_old + sigf(gi) * tanhf(gg);
      const float hn = sigf(go) * tanhf(cn);
      scell[b][j] = cn;
      hs[(long)t * B * H + (long)(b8 + b) * H + hc0 + j] = hn;
    }
    __syncthreads();

    if (t < STEPS - 1) {
      if (tid == 0) {
        unsigned int* flag = bar + (t << 3) + bgroup;
        __hip_atomic_fetch_add(flag, 1u, __ATOMIC_RELEASE, __HIP_MEMORY_SCOPE_AGENT);
        while (__hip_atomic_load(flag, __ATOMIC_RELAXED, __HIP_MEMORY_SCOPE_AGENT) < 32u) {
          __builtin_amdgcn_s_sleep(1);
        }
        (void)__hip_atomic_load(flag, __ATOMIC_ACQUIRE, __HIP_MEMORY_SCOPE_AGENT);
      }
      __syncthreads();
    }
  }
}

// ---------------- final dec GEMM: out[b,t,:] = hs[t,b,:] @ fc_w^T + fc_b ----
__global__ __launch_bounds__(256) void k_dec2(
    const float* __restrict__ hs, const float* __restrict__ fc_w,
    const float* __restrict__ fc_b, float* __restrict__ out) {
  __shared__ float A[32 * 68];
  __shared__ float Bm[64 * 68];
  const int m0 = blockIdx.x * 32;
  const int o0 = blockIdx.y * 64;
  const int tid = threadIdx.x;
  const int tn = tid & 15, tm = tid >> 4;
  float acc[2][4] = {{0.f, 0.f, 0.f, 0.f}, {0.f, 0.f, 0.f, 0.f}};
  for (int k0 = 0; k0 < H; k0 += 64) {
    for (int idx = tid; idx < 512; idx += 256) {
      const int r = idx >> 4, k4 = idx & 15;
      *(float4*)&A[r * 68 + k4 * 4] =
          *(const float4*)&hs[(long)(m0 + r) * H + k0 + k4 * 4];
    }
    for (int idx = tid; idx < 1024; idx += 256) {
      const int r = idx >> 4, k4 = idx & 15;
      *(float4*)&Bm[r * 68 + k4 * 4] =
          *(const float4*)&fc_w[(long)(o0 + r) * H + k0 + k4 * 4];
    }
    __syncthreads();
#pragma unroll
    for (int k4 = 0; k4 < 16; ++k4) {
      const float4 a0 = *(float4*)&A[tm * 68 + k4 * 4];
      const float4 a1 = *(float4*)&A[(tm + 16) * 68 + k4 * 4];
      const float4 b0 = *(float4*)&Bm[tn * 68 + k4 * 4];
      const float4 b1 = *(float4*)&Bm[(tn + 16) * 68 + k4 * 4];
      const float4 b2 = *(float4*)&Bm[(tn + 32) * 68 + k4 * 4];
      const float4 b3 = *(float4*)&Bm[(tn + 48) * 68 + k4 * 4];
      acc[0][0] += a0.x * b0.x + a0.y * b0.y + a0.z * b0.z + a0.w * b0.w;
      acc[0][1] += a0.x * b1.x + a0.y * b1.y + a0.z * b1.z + a0.w * b1.w;
      acc[0][2] += a0.x * b2.x + a0.y * b2.y + a0.z * b2.z + a0.w * b2.w;
      acc[0][3] += a0.x * b3.x + a0.y * b3.y + a0.z * b3.z + a0.w * b3.w;
      acc[1][0] += a1.x * b0.x + a1.y * b0.y + a1.z * b0.z + a1.w * b0.w;
      acc[1][1] += a1.x * b1.x + a1.y * b1.y + a1.z * b1.z + a1.w * b1.w;
      acc[1][2] += a1.x * b2.x + a1.y * b2.y + a1.z * b2.z + a1.w * b2.w;
      acc[1][3] += a1.x * b3.x + a1.y * b3.y + a1.z * b3.z + a1.w * b3.w;
    }
    __syncthreads();
  }
#pragma unroll
  for (int i = 0; i < 2; ++i) {
    const int m = m0 + tm + 16 * i;
    const int t = m >> 6, b = m & 63;
#pragma unroll
    for (int j = 0; j < 4; ++j) {
      const int o = o0 + tn + 16 * j;
      out[((long)b * STEPS + t) * OUT + o] = acc[i][j] + fc_b[o];
    }
  }
}

extern "C" void kernel_launch(void* const* d_in, const int* in_sizes, int n_in,
                              void* d_out, int out_size, void* d_ws, size_t ws_size,
                              hipStream_t stream) {
  const float* enc = (const float*)d_in[0];
  const float* hidden = (const float*)d_in[1];
  const float* attn_w = (const float*)d_in[2];
  // d_in[3] = attn_b: constant shift along softmax axis -> irrelevant.
  const float* w_ih = (const float*)d_in[4];
  const float* w_hh = (const float*)d_in[5];
  const float* b_ih = (const float*)d_in[6];
  const float* b_hh = (const float*)d_in[7];
  const float* fc_w = (const float*)d_in[8];
  const float* fc_b = (const float*)d_in[9];
  float* out = (float*)d_out;

  float* ws = (float*)d_ws;
  float* ctx      = ws;                  // 32768
  float* part_ctx = ctx + 32768;         // 262144
  float* part_ml  = part_ctx + 262144;   // 1024
  float* weff     = part_ml + 1024;      // 1048576
  float* gbase    = weff + 1048576;      // 131072
  float* gbase2   = gbase + 131072;      // 131072
  float* hs       = gbase2 + 131072;     // 32*32768 = 1048576
  unsigned int* bar = (unsigned int*)(hs + 1048576);  // 256 uints

  hipMemsetAsync(bar, 0, 256 * sizeof(unsigned int), stream);

  k_ctx_partial<<<dim3(8, 64), 256, 0, stream>>>(enc, attn_w, part_ctx, part_ml);
  k_weff<<<1024, 256, 0, stream>>>(w_ih, w_hh, fc_w, weff);
  k_ctx_reduce<<<64, 256, 0, stream>>>(part_ctx, part_ml, ctx);
  k_gbase<<<dim3(128, 4), 256, 0, stream>>>(w_ih, b_ih, b_hh, fc_b, ctx, gbase, gbase2);

  const float* hidden_p = hidden;
  const float* whh_p = w_hh;
  const float* weff_p = weff;
  const float* gbase_p = gbase;
  const float* gbase2_p = gbase2;
  float* hs_p = hs;
  unsigned int* bar_p = bar;
  void* kargs[] = {(void*)&hidden_p, (void*)&whh_p, (void*)&weff_p,
                   (void*)&gbase_p, (void*)&gbase2_p, (void*)&hs_p, (void*)&bar_p};
  hipLaunchCooperativeKernel(reinterpret_cast<const void*>(k_recur), dim3(256),
                             dim3(256), kargs, 0, stream);

  k_dec2<<<dim3(64, 4), 256, 0, stream>>>(hs, fc_w, fc_b, out);
}

// Round 6
// 413.256 us; speedup vs baseline: 1.7491x; 1.3637x over previous
//
#include <hip/hip_runtime.h>
#include <math.h>

#define B 64
#define S 1024
#define H 512
#define OUT 256
#define STEPS 32
#define NG 2048   // 4*H
#define X 768     // OUT + H

typedef __attribute__((ext_vector_type(8))) short short8;   // 8 bf16 = 4 VGPR
typedef __attribute__((ext_vector_type(4))) short s16x4;
typedef __attribute__((ext_vector_type(4))) float f32x4;

__device__ __forceinline__ float sigf(float x) { return 1.0f / (1.0f + __expf(-x)); }

__device__ __forceinline__ short f2bf(float x) {  // RNE float->bf16 bits
  union { float f; unsigned u; } a; a.f = x;
  unsigned r = a.u + 0x7fffu + ((a.u >> 16) & 1u);
  return (short)(r >> 16);
}
__device__ __forceinline__ float bf2f(short s) {
  union { unsigned u; float f; } a; a.u = ((unsigned)(unsigned short)s) << 16;
  return a.f;
}

// ---------------- context: flash softmax-weighted sum over S ----------------
__global__ __launch_bounds__(256) void k_ctx_partial(
    const float* __restrict__ enc, const float* __restrict__ attn_w,
    float* __restrict__ part_ctx, float* __restrict__ part_ml) {
  const int b = blockIdx.y, chunk = blockIdx.x;
  const int wave = threadIdx.x >> 6, lane = threadIdx.x & 63;
  const float4 wa0 = *(const float4*)(attn_w + lane * 8);
  const float4 wa1 = *(const float4*)(attn_w + lane * 8 + 4);
  const float* eb = enc + (long)b * S * H;
  float m = -1e30f, l = 0.0f;
  float acc[8];
#pragma unroll
  for (int r = 0; r < 8; ++r) acc[r] = 0.0f;
  for (int i = 0; i < 32; ++i) {
    const int s = chunk * 128 + i * 4 + wave;
    const float* row = eb + (long)s * H + lane * 8;
    const float4 v0 = *(const float4*)row;
    const float4 v1 = *(const float4*)(row + 4);
    float e = v0.x * wa0.x + v0.y * wa0.y + v0.z * wa0.z + v0.w * wa0.w +
              v1.x * wa1.x + v1.y * wa1.y + v1.z * wa1.z + v1.w * wa1.w;
#pragma unroll
    for (int msk = 1; msk < 64; msk <<= 1) e += __shfl_xor(e, msk, 64);
    const float mn = fmaxf(m, e);
    const float sc = __expf(m - mn);
    const float p = __expf(e - mn);
    l = l * sc + p;
    m = mn;
    acc[0] = acc[0] * sc + p * v0.x; acc[1] = acc[1] * sc + p * v0.y;
    acc[2] = acc[2] * sc + p * v0.z; acc[3] = acc[3] * sc + p * v0.w;
    acc[4] = acc[4] * sc + p * v1.x; acc[5] = acc[5] * sc + p * v1.y;
    acc[6] = acc[6] * sc + p * v1.z; acc[7] = acc[7] * sc + p * v1.w;
  }
  __shared__ float sm_acc[4][H];
  __shared__ float sm_m[4], sm_l[4];
#pragma unroll
  for (int r = 0; r < 8; ++r) sm_acc[wave][lane * 8 + r] = acc[r];
  if (lane == 0) { sm_m[wave] = m; sm_l[wave] = l; }
  __syncthreads();
  const float mb = fmaxf(fmaxf(sm_m[0], sm_m[1]), fmaxf(sm_m[2], sm_m[3]));
  float e0[4];
#pragma unroll
  for (int w = 0; w < 4; ++w) e0[w] = __expf(sm_m[w] - mb);
  const int h0 = threadIdx.x * 2;
  float s0 = 0.f, s1 = 0.f;
#pragma unroll
  for (int w = 0; w < 4; ++w) { s0 += sm_acc[w][h0] * e0[w]; s1 += sm_acc[w][h0 + 1] * e0[w]; }
  float* pc = part_ctx + ((long)chunk * B + b) * H;
  pc[h0] = s0; pc[h0 + 1] = s1;
  if (threadIdx.x == 0) {
    const float lb = sm_l[0] * e0[0] + sm_l[1] * e0[1] + sm_l[2] * e0[2] + sm_l[3] * e0[3];
    part_ml[(chunk * B + b) * 2] = mb;
    part_ml[(chunk * B + b) * 2 + 1] = lb;
  }
}

__global__ __launch_bounds__(256) void k_ctx_reduce(
    const float* __restrict__ part_ctx, const float* __restrict__ part_ml,
    float* __restrict__ ctx) {
  const int b = blockIdx.x;
  float m = -1e30f;
#pragma unroll
  for (int c = 0; c < 8; ++c) m = fmaxf(m, part_ml[(c * B + b) * 2]);
  float L = 0.f, sc[8];
#pragma unroll
  for (int c = 0; c < 8; ++c) {
    sc[c] = __expf(part_ml[(c * B + b) * 2] - m);
    L += part_ml[(c * B + b) * 2 + 1] * sc[c];
  }
  const float inv = 1.0f / L;
  const int h0 = threadIdx.x * 2;
  float s0 = 0.f, s1 = 0.f;
#pragma unroll
  for (int c = 0; c < 8; ++c) {
    const float* pc = part_ctx + ((long)c * B + b) * H;
    s0 += pc[h0] * sc[c]; s1 += pc[h0 + 1] * sc[c];
  }
  ctx[(long)b * H + h0] = s0 * inv;
  ctx[(long)b * H + h0 + 1] = s1 * inv;
}

// ---------------- Weff = w_hh + Wd @ fc_w, stored as split-bf16 hi/lo -------
// whi/wlo layout: [row 0..2047][k 0..511] — MFMA-B-fragment-ready shorts.
__global__ __launch_bounds__(256) void k_weff(
    const float* __restrict__ w_ih, const float* __restrict__ w_hh,
    const float* __restrict__ fc_w, short* __restrict__ whi,
    short* __restrict__ wlo) {
  const int flat4 = blockIdx.x * 256 + threadIdx.x;
  const int n = flat4 >> 7;
  const int k = (flat4 & 127) << 2;
  const float* wd = w_ih + (long)n * X;
  float v[4] = {0.f, 0.f, 0.f, 0.f};
  for (int j = 0; j < OUT; ++j) {
    const float w = wd[j];
    const float4 f = *(const float4*)(fc_w + (long)j * H + k);
    v[0] = fmaf(w, f.x, v[0]); v[1] = fmaf(w, f.y, v[1]);
    v[2] = fmaf(w, f.z, v[2]); v[3] = fmaf(w, f.w, v[3]);
  }
  const float4 hh = *(const float4*)(w_hh + (long)n * H + k);
  v[0] += hh.x; v[1] += hh.y; v[2] += hh.z; v[3] += hh.w;
  s16x4 hi4, lo4;
#pragma unroll
  for (int e = 0; e < 4; ++e) {
    const short hb = f2bf(v[e]);
    hi4[e] = hb;
    lo4[e] = f2bf(v[e] - bf2f(hb));
  }
  *(s16x4*)(whi + (long)n * H + k) = hi4;
  *(s16x4*)(wlo + (long)n * H + k) = lo4;
}

// ---------------- gates0 / gbase2 ----------------
// gates0[b,n] = b_ih+b_hh + Wc[n]·ctx[b] + Whh[n]·hidden[b]   (dec_in(0)=0)
// gbase2[b,n] = b_ih+b_hh + Wc[n]·ctx[b] + Wd[n]·fc_b
__global__ __launch_bounds__(256) void k_gbase(
    const float* __restrict__ w_ih, const float* __restrict__ w_hh,
    const float* __restrict__ b_ih, const float* __restrict__ b_hh,
    const float* __restrict__ fc_b, const float* __restrict__ ctx,
    const float* __restrict__ hidden, float* __restrict__ gates0,
    float* __restrict__ gbase2) {
  __shared__ float lbuf[16][H + 4];
  const int nt = blockIdx.x, bq = blockIdx.y;
  const int n_l = threadIdx.x & 15, b_l = threadIdx.x >> 4;
  const int n = nt * 16 + n_l;
  const float* wr = w_ih + (long)n * X;
  const float* whr = w_hh + (long)n * H;
  // pass 1: ctx dot
  for (int i = threadIdx.x; i < 16 * 128; i += 256) {
    const int bb = i >> 7, kk = (i & 127) << 2;
    *(float4*)&lbuf[bb][kk] = *(const float4*)(ctx + (long)(bq * 16 + bb) * H + kk);
  }
  __syncthreads();
  float acc = 0.f;
  for (int k = 0; k < H; k += 4) {
    const float4 c4 = *(float4*)&lbuf[b_l][k];
    const float4 w4 = *(const float4*)(wr + OUT + k);
    acc += c4.x * w4.x + c4.y * w4.y + c4.z * w4.z + c4.w * w4.w;
  }
  __syncthreads();
  // pass 2: hidden dot
  for (int i = threadIdx.x; i < 16 * 128; i += 256) {
    const int bb = i >> 7, kk = (i & 127) << 2;
    *(float4*)&lbuf[bb][kk] = *(const float4*)(hidden + (long)(bq * 16 + bb) * H + kk);
  }
  __syncthreads();
  float hacc = 0.f;
  for (int k = 0; k < H; k += 4) {
    const float4 c4 = *(float4*)&lbuf[b_l][k];
    const float4 w4 = *(const float4*)(whr + k);
    hacc += c4.x * w4.x + c4.y * w4.y + c4.z * w4.z + c4.w * w4.w;
  }
  float db = 0.f;
  for (int j = 0; j < OUT; j += 4) {
    const float4 w4 = *(const float4*)(wr + j);
    const float4 f4v = *(const float4*)(fc_b + j);
    db += w4.x * f4v.x + w4.y * f4v.y + w4.z * f4v.z + w4.w * f4v.w;
  }
  const float g = acc + b_ih[n] + b_hh[n];
  const int b = bq * 16 + b_l;
  gates0[(long)b * NG + n] = g + hacc;
  gbase2[(long)b * NG + n] = g + db;
}

// ---------------- step 0 cell update (c0 = 0) ----------------
__global__ __launch_bounds__(256) void k_cell0(
    const float* __restrict__ gates0, float* __restrict__ h0,
    float* __restrict__ c0) {
  const int idx = blockIdx.x * 256 + threadIdx.x;  // 0..32767 = b*512+col
  const int b = idx >> 9, col = idx & 511;
  const float* g = gates0 + (long)b * NG;
  const float cn = sigf(g[col]) * tanhf(g[1024 + col]);
  const float hn = sigf(g[1536 + col]) * tanhf(cn);
  h0[idx] = hn;
  c0[idx] = cn;
}

// ---------------- one LSTM step, MFMA, split-bf16 weights from L2 ----------
// 256 blocks x 256 thr (4 waves). Block = (bgroup = blk>>5 : 8 batches,
// colslice = blk&31 : 16 hidden cols). Wave w = gate w (i,f,g,o).
// Cross-step coherence = implicit device-scope release/acquire at kernel
// dispatch boundaries (architectural; no custom cache ops).
#define HSTR 520  // shorts per h row (512 + 8 pad)
__global__ __launch_bounds__(256) void k_stepm(
    const short* __restrict__ whi, const short* __restrict__ wlo,
    const float* __restrict__ gb2, const float* __restrict__ h_in,
    const float* __restrict__ c_in, float* __restrict__ h_out,
    float* __restrict__ c_out) {
  __shared__ short sh_hi[16 * HSTR];  // rows 8..15 never read for used D rows
  __shared__ short sh_lo[16 * HSTR];
  __shared__ float sG[4][8][20];
  __shared__ float sgb[8][64];

  const int blk = blockIdx.x;
  const int b8 = (blk >> 5) << 3;
  const int hc0 = (blk & 31) << 4;
  const int tid = threadIdx.x;
  const int w = tid >> 6, l = tid & 63;
  const int ln = l & 15, lk = l >> 4;

  // B-fragments: lane holds W[(w*512)+hc0+ln][kk*32 + lk*8 + e], pre-split.
  short8 wh[16], wl[16];
  {
    const long wb = (long)((w << 9) + hc0 + ln) * H + (lk << 3);
#pragma unroll
    for (int kk = 0; kk < 16; ++kk) {
      wh[kk] = *(const short8*)(whi + wb + kk * 32);
      wl[kk] = *(const short8*)(wlo + wb + kk * 32);
    }
  }

  // stage gb2 slice
  for (int idx = tid; idx < 512; idx += 256) {
    const int b = idx >> 6, gr = idx & 63, g = gr >> 4, j = gr & 15;
    sgb[b][gr] = gb2[(long)(b8 + b) * NG + (g << 9) + hc0 + j];
  }
  // stage h(t-1): fp32 -> split bf16 LDS (8 rows x 512)
  for (int idx = tid; idx < 1024; idx += 256) {
    const int row = idx >> 7, kq = (idx & 127) << 2;
    float v[4];
    *(float4*)v = *(const float4*)(h_in + (long)(b8 + row) * H + kq);
    s16x4 hi4, lo4;
#pragma unroll
    for (int e = 0; e < 4; ++e) {
      const short hb = f2bf(v[e]);
      hi4[e] = hb;
      lo4[e] = f2bf(v[e] - bf2f(hb));
    }
    *(s16x4*)&sh_hi[row * HSTR + kq] = hi4;
    *(s16x4*)&sh_lo[row * HSTR + kq] = lo4;
  }
  __syncthreads();

  // D[b][j] = sum_k h[b][k] * W[row_j][k]  (split-bf16, 3 MFMA per kk)
  f32x4 acc = {0.f, 0.f, 0.f, 0.f};
  const int abase = ln * HSTR + (lk << 3);
#pragma unroll
  for (int kk = 0; kk < 16; ++kk) {
    const short8 ah = *(const short8*)&sh_hi[abase + kk * 32];
    const short8 al = *(const short8*)&sh_lo[abase + kk * 32];
    acc = __builtin_amdgcn_mfma_f32_16x16x32_bf16(ah, wh[kk], acc, 0, 0, 0);
    acc = __builtin_amdgcn_mfma_f32_16x16x32_bf16(al, wh[kk], acc, 0, 0, 0);
    acc = __builtin_amdgcn_mfma_f32_16x16x32_bf16(ah, wl[kk], acc, 0, 0, 0);
  }
  if (lk < 2) {
#pragma unroll
    for (int r = 0; r < 4; ++r) sG[w][(lk << 2) + r][ln] = acc[r];
  }
  __syncthreads();

  // cell update
  if (tid < 128) {
    const int b = tid >> 4, j = tid & 15;
    const float gi = sG[0][b][j] + sgb[b][j];
    const float gf = sG[1][b][j] + sgb[b][16 + j];
    const float gg = sG[2][b][j] + sgb[b][32 + j];
    const float go = sG[3][b][j] + sgb[b][48 + j];
    const long cix = (long)(b8 + b) * H + hc0 + j;
    const float cn = sigf(gf) * c_in[cix] + sigf(gi) * tanhf(gg);
    const float hn = sigf(go) * tanhf(cn);
    c_out[cix] = cn;
    h_out[cix] = hn;
  }
}

// ---------------- final dec GEMM: out[b,t,:] = hs[t,b,:] @ fc_w^T + fc_b ----
__global__ __launch_bounds__(256) void k_dec2(
    const float* __restrict__ hs, const float* __restrict__ fc_w,
    const float* __restrict__ fc_b, float* __restrict__ out) {
  __shared__ float A[32 * 68];
  __shared__ float Bm[64 * 68];
  const int m0 = blockIdx.x * 32;
  const int o0 = blockIdx.y * 64;
  const int tid = threadIdx.x;
  const int tn = tid & 15, tm = tid >> 4;
  float acc[2][4] = {{0.f, 0.f, 0.f, 0.f}, {0.f, 0.f, 0.f, 0.f}};
  for (int k0 = 0; k0 < H; k0 += 64) {
    for (int idx = tid; idx < 512; idx += 256) {
      const int r = idx >> 4, k4 = idx & 15;
      *(float4*)&A[r * 68 + k4 * 4] =
          *(const float4*)&hs[(long)(m0 + r) * H + k0 + k4 * 4];
    }
    for (int idx = tid; idx < 1024; idx += 256) {
      const int r = idx >> 4, k4 = idx & 15;
      *(float4*)&Bm[r * 68 + k4 * 4] =
          *(const float4*)&fc_w[(long)(o0 + r) * H + k0 + k4 * 4];
    }
    __syncthreads();
#pragma unroll
    for (int k4 = 0; k4 < 16; ++k4) {
      const float4 a0 = *(float4*)&A[tm * 68 + k4 * 4];
      const float4 a1 = *(float4*)&A[(tm + 16) * 68 + k4 * 4];
      const float4 b0 = *(float4*)&Bm[tn * 68 + k4 * 4];
      const float4 b1 = *(float4*)&Bm[(tn + 16) * 68 + k4 * 4];
      const float4 b2 = *(float4*)&Bm[(tn + 32) * 68 + k4 * 4];
      const float4 b3 = *(float4*)&Bm[(tn + 48) * 68 + k4 * 4];
      acc[0][0] += a0.x * b0.x + a0.y * b0.y + a0.z * b0.z + a0.w * b0.w;
      acc[0][1] += a0.x * b1.x + a0.y * b1.y + a0.z * b1.z + a0.w * b1.w;
      acc[0][2] += a0.x * b2.x + a0.y * b2.y + a0.z * b2.z + a0.w * b2.w;
      acc[0][3] += a0.x * b3.x + a0.y * b3.y + a0.z * b3.z + a0.w * b3.w;
      acc[1][0] += a1.x * b0.x + a1.y * b0.y + a1.z * b0.z + a1.w * b0.w;
      acc[1][1] += a1.x * b1.x + a1.y * b1.y + a1.z * b1.z + a1.w * b1.w;
      acc[1][2] += a1.x * b2.x + a1.y * b2.y + a1.z * b2.z + a1.w * b2.w;
      acc[1][3] += a1.x * b3.x + a1.y * b3.y + a1.z * b3.z + a1.w * b3.w;
    }
    __syncthreads();
  }
#pragma unroll
  for (int i = 0; i < 2; ++i) {
    const int m = m0 + tm + 16 * i;
    const int t = m >> 6, b = m & 63;
#pragma unroll
    for (int j = 0; j < 4; ++j) {
      const int o = o0 + tn + 16 * j;
      out[((long)b * STEPS + t) * OUT + o] = acc[i][j] + fc_b[o];
    }
  }
}

extern "C" void kernel_launch(void* const* d_in, const int* in_sizes, int n_in,
                              void* d_out, int out_size, void* d_ws, size_t ws_size,
                              hipStream_t stream) {
  const float* enc = (const float*)d_in[0];
  const float* hidden = (const float*)d_in[1];
  const float* attn_w = (const float*)d_in[2];
  // d_in[3] = attn_b: constant shift along softmax axis -> irrelevant.
  const float* w_ih = (const float*)d_in[4];
  const float* w_hh = (const float*)d_in[5];
  const float* b_ih = (const float*)d_in[6];
  const float* b_hh = (const float*)d_in[7];
  const float* fc_w = (const float*)d_in[8];
  const float* fc_b = (const float*)d_in[9];
  float* out = (float*)d_out;

  float* ws = (float*)d_ws;
  float* ctx      = ws;                  //   32768 f
  float* part_ctx = ctx + 32768;         //  262144 f
  float* part_ml  = part_ctx + 262144;   //    1024 f
  short* whi      = (short*)(part_ml + 1024);      // 1048576 shorts (524288 f)
  short* wlo      = whi + 1048576;                 // 1048576 shorts (524288 f)
  float* gates0   = (float*)(wlo + 1048576);       //  131072 f
  float* gbase2   = gates0 + 131072;     //  131072 f
  float* hs       = gbase2 + 131072;     // 32*32768 = 1048576 f
  float* cbuf     = hs + 1048576;        //   32768 f
  // total = 2,688,000 floats ~= 10.75 MB

  k_ctx_partial<<<dim3(8, 64), 256, 0, stream>>>(enc, attn_w, part_ctx, part_ml);
  k_weff<<<1024, 256, 0, stream>>>(w_ih, w_hh, fc_w, whi, wlo);
  k_ctx_reduce<<<64, 256, 0, stream>>>(part_ctx, part_ml, ctx);
  k_gbase<<<dim3(128, 4), 256, 0, stream>>>(w_ih, w_hh, b_ih, b_hh, fc_b, ctx,
                                            hidden, gates0, gbase2);
  k_cell0<<<128, 256, 0, stream>>>(gates0, hs, cbuf);

  for (int t = 1; t < STEPS; ++t) {
    k_stepm<<<256, 256, 0, stream>>>(whi, wlo, gbase2,
                                     hs + (long)(t - 1) * B * H, cbuf,
                                     hs + (long)t * B * H, cbuf);
  }

  k_dec2<<<dim3(64, 4), 256, 0, stream>>>(hs, fc_w, fc_b, out);
}

// Round 7
// 346.683 us; speedup vs baseline: 2.0850x; 1.1920x over previous
//
#include <hip/hip_runtime.h>
#include <math.h>

#define B 64
#define S 1024
#define H 512
#define OUT 256
#define STEPS 32
#define NG 2048   // 4*H
#define X 768     // OUT + H

typedef __attribute__((ext_vector_type(8))) short short8;   // 8 bf16 = 4 VGPR
typedef __attribute__((ext_vector_type(4))) short s16x4;
typedef __attribute__((ext_vector_type(4))) float f32x4;

__device__ __forceinline__ float sigf(float x) { return 1.0f / (1.0f + __expf(-x)); }

__device__ __forceinline__ short f2bf(float x) {  // RNE float->bf16 bits
  union { float f; unsigned u; } a; a.f = x;
  unsigned r = a.u + 0x7fffu + ((a.u >> 16) & 1u);
  return (short)(r >> 16);
}
__device__ __forceinline__ float bf2f(short s) {
  union { unsigned u; float f; } a; a.u = ((unsigned)(unsigned short)s) << 16;
  return a.f;
}

// MALL-visible flag read (bypasses L1/L2) — proven in rounds 2/3/6 polling.
__device__ __forceinline__ unsigned load_u32_cg(const unsigned* p) {
  unsigned r;
  asm volatile("global_load_dword %0, %1, off sc0 sc1\n\ts_waitcnt vmcnt(0)"
               : "=v"(r) : "v"(p) : "memory");
  return r;
}

// ---------------- context: flash softmax-weighted sum over S ----------------
__global__ __launch_bounds__(256) void k_ctx_partial(
    const float* __restrict__ enc, const float* __restrict__ attn_w,
    float* __restrict__ part_ctx, float* __restrict__ part_ml) {
  const int b = blockIdx.y, chunk = blockIdx.x;
  const int wave = threadIdx.x >> 6, lane = threadIdx.x & 63;
  const float4 wa0 = *(const float4*)(attn_w + lane * 8);
  const float4 wa1 = *(const float4*)(attn_w + lane * 8 + 4);
  const float* eb = enc + (long)b * S * H;
  float m = -1e30f, l = 0.0f;
  float acc[8];
#pragma unroll
  for (int r = 0; r < 8; ++r) acc[r] = 0.0f;
  for (int i = 0; i < 32; ++i) {
    const int s = chunk * 128 + i * 4 + wave;
    const float* row = eb + (long)s * H + lane * 8;
    const float4 v0 = *(const float4*)row;
    const float4 v1 = *(const float4*)(row + 4);
    float e = v0.x * wa0.x + v0.y * wa0.y + v0.z * wa0.z + v0.w * wa0.w +
              v1.x * wa1.x + v1.y * wa1.y + v1.z * wa1.z + v1.w * wa1.w;
#pragma unroll
    for (int msk = 1; msk < 64; msk <<= 1) e += __shfl_xor(e, msk, 64);
    const float mn = fmaxf(m, e);
    const float sc = __expf(m - mn);
    const float p = __expf(e - mn);
    l = l * sc + p;
    m = mn;
    acc[0] = acc[0] * sc + p * v0.x; acc[1] = acc[1] * sc + p * v0.y;
    acc[2] = acc[2] * sc + p * v0.z; acc[3] = acc[3] * sc + p * v0.w;
    acc[4] = acc[4] * sc + p * v1.x; acc[5] = acc[5] * sc + p * v1.y;
    acc[6] = acc[6] * sc + p * v1.z; acc[7] = acc[7] * sc + p * v1.w;
  }
  __shared__ float sm_acc[4][H];
  __shared__ float sm_m[4], sm_l[4];
#pragma unroll
  for (int r = 0; r < 8; ++r) sm_acc[wave][lane * 8 + r] = acc[r];
  if (lane == 0) { sm_m[wave] = m; sm_l[wave] = l; }
  __syncthreads();
  const float mb = fmaxf(fmaxf(sm_m[0], sm_m[1]), fmaxf(sm_m[2], sm_m[3]));
  float e0[4];
#pragma unroll
  for (int w = 0; w < 4; ++w) e0[w] = __expf(sm_m[w] - mb);
  const int h0 = threadIdx.x * 2;
  float s0 = 0.f, s1 = 0.f;
#pragma unroll
  for (int w = 0; w < 4; ++w) { s0 += sm_acc[w][h0] * e0[w]; s1 += sm_acc[w][h0 + 1] * e0[w]; }
  float* pc = part_ctx + ((long)chunk * B + b) * H;
  pc[h0] = s0; pc[h0 + 1] = s1;
  if (threadIdx.x == 0) {
    const float lb = sm_l[0] * e0[0] + sm_l[1] * e0[1] + sm_l[2] * e0[2] + sm_l[3] * e0[3];
    part_ml[(chunk * B + b) * 2] = mb;
    part_ml[(chunk * B + b) * 2 + 1] = lb;
  }
}

__global__ __launch_bounds__(256) void k_ctx_reduce(
    const float* __restrict__ part_ctx, const float* __restrict__ part_ml,
    float* __restrict__ ctx) {
  const int b = blockIdx.x;
  float m = -1e30f;
#pragma unroll
  for (int c = 0; c < 8; ++c) m = fmaxf(m, part_ml[(c * B + b) * 2]);
  float L = 0.f, sc[8];
#pragma unroll
  for (int c = 0; c < 8; ++c) {
    sc[c] = __expf(part_ml[(c * B + b) * 2] - m);
    L += part_ml[(c * B + b) * 2 + 1] * sc[c];
  }
  const float inv = 1.0f / L;
  const int h0 = threadIdx.x * 2;
  float s0 = 0.f, s1 = 0.f;
#pragma unroll
  for (int c = 0; c < 8; ++c) {
    const float* pc = part_ctx + ((long)c * B + b) * H;
    s0 += pc[h0] * sc[c]; s1 += pc[h0 + 1] * sc[c];
  }
  ctx[(long)b * H + h0] = s0 * inv;
  ctx[(long)b * H + h0 + 1] = s1 * inv;
}

// ---------------- Weff = w_hh + Wd @ fc_w, stored as split-bf16 hi/lo -------
__global__ __launch_bounds__(256) void k_weff(
    const float* __restrict__ w_ih, const float* __restrict__ w_hh,
    const float* __restrict__ fc_w, short* __restrict__ whi,
    short* __restrict__ wlo) {
  const int flat4 = blockIdx.x * 256 + threadIdx.x;
  const int n = flat4 >> 7;
  const int k = (flat4 & 127) << 2;
  const float* wd = w_ih + (long)n * X;
  float v[4] = {0.f, 0.f, 0.f, 0.f};
  for (int j = 0; j < OUT; ++j) {
    const float w = wd[j];
    const float4 f = *(const float4*)(fc_w + (long)j * H + k);
    v[0] = fmaf(w, f.x, v[0]); v[1] = fmaf(w, f.y, v[1]);
    v[2] = fmaf(w, f.z, v[2]); v[3] = fmaf(w, f.w, v[3]);
  }
  const float4 hh = *(const float4*)(w_hh + (long)n * H + k);
  v[0] += hh.x; v[1] += hh.y; v[2] += hh.z; v[3] += hh.w;
  s16x4 hi4, lo4;
#pragma unroll
  for (int e = 0; e < 4; ++e) {
    const short hb = f2bf(v[e]);
    hi4[e] = hb;
    lo4[e] = f2bf(v[e] - bf2f(hb));
  }
  *(s16x4*)(whi + (long)n * H + k) = hi4;
  *(s16x4*)(wlo + (long)n * H + k) = lo4;
}

// ---------------- gates0 / gbase2 ----------------
__global__ __launch_bounds__(256) void k_gbase(
    const float* __restrict__ w_ih, const float* __restrict__ w_hh,
    const float* __restrict__ b_ih, const float* __restrict__ b_hh,
    const float* __restrict__ fc_b, const float* __restrict__ ctx,
    const float* __restrict__ hidden, float* __restrict__ gates0,
    float* __restrict__ gbase2) {
  __shared__ float lbuf[16][H + 4];
  const int nt = blockIdx.x, bq = blockIdx.y;
  const int n_l = threadIdx.x & 15, b_l = threadIdx.x >> 4;
  const int n = nt * 16 + n_l;
  const float* wr = w_ih + (long)n * X;
  const float* whr = w_hh + (long)n * H;
  for (int i = threadIdx.x; i < 16 * 128; i += 256) {
    const int bb = i >> 7, kk = (i & 127) << 2;
    *(float4*)&lbuf[bb][kk] = *(const float4*)(ctx + (long)(bq * 16 + bb) * H + kk);
  }
  __syncthreads();
  float acc = 0.f;
  for (int k = 0; k < H; k += 4) {
    const float4 c4 = *(float4*)&lbuf[b_l][k];
    const float4 w4 = *(const float4*)(wr + OUT + k);
    acc += c4.x * w4.x + c4.y * w4.y + c4.z * w4.z + c4.w * w4.w;
  }
  __syncthreads();
  for (int i = threadIdx.x; i < 16 * 128; i += 256) {
    const int bb = i >> 7, kk = (i & 127) << 2;
    *(float4*)&lbuf[bb][kk] = *(const float4*)(hidden + (long)(bq * 16 + bb) * H + kk);
  }
  __syncthreads();
  float hacc = 0.f;
  for (int k = 0; k < H; k += 4) {
    const float4 c4 = *(float4*)&lbuf[b_l][k];
    const float4 w4 = *(const float4*)(whr + k);
    hacc += c4.x * w4.x + c4.y * w4.y + c4.z * w4.z + c4.w * w4.w;
  }
  float db = 0.f;
  for (int j = 0; j < OUT; j += 4) {
    const float4 w4 = *(const float4*)(wr + j);
    const float4 f4v = *(const float4*)(fc_b + j);
    db += w4.x * f4v.x + w4.y * f4v.y + w4.z * f4v.z + w4.w * f4v.w;
  }
  const float g = acc + b_ih[n] + b_hh[n];
  const int b = bq * 16 + b_l;
  gates0[(long)b * NG + n] = g + hacc;
  gbase2[(long)b * NG + n] = g + db;
}

// ---------------- step 0 cell update (c0 = 0) ----------------
__global__ __launch_bounds__(256) void k_cell0(
    const float* __restrict__ gates0, float* __restrict__ h0,
    float* __restrict__ c0) {
  const int idx = blockIdx.x * 256 + threadIdx.x;
  const int b = idx >> 9, col = idx & 511;
  const float* g = gates0 + (long)b * NG;
  const float cn = sigf(g[col]) * tanhf(g[1024 + col]);
  const float hn = sigf(g[1536 + col]) * tanhf(cn);
  h0[idx] = hn;
  c0[idx] = cn;
}

// ---------------- persistent recurrence, XCD-local sync fast path ----------
// 256 blocks x 256 thr, 1/CU (cooperative). Group = 32 blocks sharing bgroup
// bg = blk&7 (8 batches); slice = blk>>3 (16 hidden cols). Weights (Weff
// split-bf16) live in VGPRs for ALL 31 steps. c lives in LDS.
//
// Sync per step: if the group's 32 blocks are co-resident on ONE XCD
// (verified at runtime via HW_REG_XCC_ID vote), plain stores/loads are
// coherent through the shared L2 -> flag barrier is a relaxed MALL atomic,
// NO cache maintenance. Otherwise: device-scope RELEASE/ACQUIRE protocol
// (round-3-proven correct, slower). Mixed mode per group is fine.
#define HSTR 520
__global__ __launch_bounds__(256, 1) void k_recur2(
    const short* __restrict__ whi, const short* __restrict__ wlo,
    const float* __restrict__ gb2, const float* __restrict__ cbuf,
    float* __restrict__ hs, unsigned int* __restrict__ bar) {
  __shared__ short sh_hi[16 * HSTR];
  __shared__ short sh_lo[16 * HSTR];
  __shared__ float sG[4][8][20];
  __shared__ float sgb[8][64];
  __shared__ float scell[8][16];
  __shared__ int s_fast;

  const int blk = blockIdx.x;
  const int bg = blk & 7;
  const int b8 = bg << 3;
  const int hc0 = (blk >> 3) << 4;
  const int tid = threadIdx.x;
  const int w = tid >> 6, l = tid & 63;
  const int ln = l & 15, lk = l >> 4;

  // ---- placement vote (BEFORE weight loads: ACQUIRE may invalidate L2) ----
  if (tid == 0) {
    unsigned xcc;
    asm volatile("s_getreg_b32 %0, hwreg(20, 0, 32)" : "=s"(xcc));  // HW_REG_XCC_ID
    __hip_atomic_fetch_or(&bar[256 + bg], 1u << (xcc & 0xFu),
                          __ATOMIC_RELEASE, __HIP_MEMORY_SCOPE_AGENT);
    unsigned* gbar = &bar[264 + bg];
    __hip_atomic_fetch_add(gbar, 1u, __ATOMIC_RELEASE, __HIP_MEMORY_SCOPE_AGENT);
    while (load_u32_cg(gbar) < 32u) __builtin_amdgcn_s_sleep(1);
    const unsigned mask = __hip_atomic_load(&bar[256 + bg], __ATOMIC_ACQUIRE,
                                            __HIP_MEMORY_SCOPE_AGENT);
    s_fast = (__popc(mask) == 1) ? 1 : 0;
  }
  __syncthreads();
  const bool fast = (s_fast != 0);

  // zero h tile (rows 8..15 stay zero forever)
  for (int i = tid; i < 16 * HSTR; i += 256) { sh_hi[i] = 0; sh_lo[i] = 0; }

  // stage gbase2 slice and c(0) slice
  for (int idx = tid; idx < 512; idx += 256) {
    const int b = idx >> 6, gr = idx & 63, g = gr >> 4, j = gr & 15;
    sgb[b][gr] = gb2[(long)(b8 + b) * NG + (g << 9) + hc0 + j];
  }
  if (tid < 128) {
    const int b = tid >> 4, j = tid & 15;
    scell[b][j] = cbuf[(long)(b8 + b) * H + hc0 + j];
  }

  // Weff fragments (loaded ONCE for all 31 steps)
  short8 wh[16], wl[16];
  {
    const long wb = (long)((w << 9) + hc0 + ln) * H + (lk << 3);
#pragma unroll
    for (int kk = 0; kk < 16; ++kk) {
      wh[kk] = *(const short8*)(whi + wb + kk * 32);
      wl[kk] = *(const short8*)(wlo + wb + kk * 32);
    }
  }
  __syncthreads();

  for (int t = 1; t < STEPS; ++t) {
    // stage h(t-1): plain loads (fast: same-XCD L2; fallback: post-inv fresh)
    const float* hsrc = hs + (long)(t - 1) * B * H + (long)b8 * H;
    for (int idx = tid; idx < 1024; idx += 256) {
      const int row = idx >> 7, kq = (idx & 127) << 2;
      float v[4];
      *(float4*)v = *(const float4*)(hsrc + (long)row * H + kq);
      s16x4 hi4, lo4;
#pragma unroll
      for (int e = 0; e < 4; ++e) {
        const short hb = f2bf(v[e]);
        hi4[e] = hb;
        lo4[e] = f2bf(v[e] - bf2f(hb));
      }
      *(s16x4*)&sh_hi[row * HSTR + kq] = hi4;
      *(s16x4*)&sh_lo[row * HSTR + kq] = lo4;
    }
    __syncthreads();

    // gates: D[b][j] = sum_k h[b][k] * Weff[row_j][k]  (split-bf16, 3 MFMA)
    f32x4 acc = {0.f, 0.f, 0.f, 0.f};
    const int abase = ln * HSTR + (lk << 3);
#pragma unroll
    for (int kk = 0; kk < 16; ++kk) {
      const short8 ah = *(const short8*)&sh_hi[abase + kk * 32];
      const short8 al = *(const short8*)&sh_lo[abase + kk * 32];
      acc = __builtin_amdgcn_mfma_f32_16x16x32_bf16(ah, wh[kk], acc, 0, 0, 0);
      acc = __builtin_amdgcn_mfma_f32_16x16x32_bf16(al, wh[kk], acc, 0, 0, 0);
      acc = __builtin_amdgcn_mfma_f32_16x16x32_bf16(ah, wl[kk], acc, 0, 0, 0);
    }
    if (lk < 2) {
#pragma unroll
      for (int r = 0; r < 4; ++r) sG[w][(lk << 2) + r][ln] = acc[r];
    }
    __syncthreads();

    // cell update + h store (plain)
    if (tid < 128) {
      const int b = tid >> 4, j = tid & 15;
      const float gi = sG[0][b][j] + sgb[b][j];
      const float gf = sG[1][b][j] + sgb[b][16 + j];
      const float gg = sG[2][b][j] + sgb[b][32 + j];
      const float go = sG[3][b][j] + sgb[b][48 + j];
      const float c_old = scell[b][j];
      const float cn = sigf(gf) * c_old + sigf(gi) * tanhf(gg);
      const float hn = sigf(go) * tanhf(cn);
      scell[b][j] = cn;
      hs[(long)t * B * H + (long)(b8 + b) * H + hc0 + j] = hn;
      asm volatile("s_waitcnt vmcnt(0)" ::: "memory");  // store in L2
    }
    __syncthreads();

    if (t < STEPS - 1) {
      if (tid == 0) {
        unsigned int* flag = bar + t * 8 + bg;
        if (fast) {
          // same-XCD: L2 is the coherence point; no cache maintenance
          __hip_atomic_fetch_add(flag, 1u, __ATOMIC_RELAXED, __HIP_MEMORY_SCOPE_AGENT);
          while (load_u32_cg(flag) < 32u) __builtin_amdgcn_s_sleep(1);
        } else {
          // cross-XCD fallback: device-scope release/acquire (round-3 proven)
          __hip_atomic_fetch_add(flag, 1u, __ATOMIC_RELEASE, __HIP_MEMORY_SCOPE_AGENT);
          while (load_u32_cg(flag) < 32u) __builtin_amdgcn_s_sleep(1);
          (void)__hip_atomic_load(flag, __ATOMIC_ACQUIRE, __HIP_MEMORY_SCOPE_AGENT);
        }
      }
      __syncthreads();
    }
  }
}

// ---------------- final dec GEMM: out[b,t,:] = hs[t,b,:] @ fc_w^T + fc_b ----
__global__ __launch_bounds__(256) void k_dec2(
    const float* __restrict__ hs, const float* __restrict__ fc_w,
    const float* __restrict__ fc_b, float* __restrict__ out) {
  __shared__ float A[32 * 68];
  __shared__ float Bm[64 * 68];
  const int m0 = blockIdx.x * 32;
  const int o0 = blockIdx.y * 64;
  const int tid = threadIdx.x;
  const int tn = tid & 15, tm = tid >> 4;
  float acc[2][4] = {{0.f, 0.f, 0.f, 0.f}, {0.f, 0.f, 0.f, 0.f}};
  for (int k0 = 0; k0 < H; k0 += 64) {
    for (int idx = tid; idx < 512; idx += 256) {
      const int r = idx >> 4, k4 = idx & 15;
      *(float4*)&A[r * 68 + k4 * 4] =
          *(const float4*)&hs[(long)(m0 + r) * H + k0 + k4 * 4];
    }
    for (int idx = tid; idx < 1024; idx += 256) {
      const int r = idx >> 4, k4 = idx & 15;
      *(float4*)&Bm[r * 68 + k4 * 4] =
          *(const float4*)&fc_w[(long)(o0 + r) * H + k0 + k4 * 4];
    }
    __syncthreads();
#pragma unroll
    for (int k4 = 0; k4 < 16; ++k4) {
      const float4 a0 = *(float4*)&A[tm * 68 + k4 * 4];
      const float4 a1 = *(float4*)&A[(tm + 16) * 68 + k4 * 4];
      const float4 b0 = *(float4*)&Bm[tn * 68 + k4 * 4];
      const float4 b1 = *(float4*)&Bm[(tn + 16) * 68 + k4 * 4];
      const float4 b2 = *(float4*)&Bm[(tn + 32) * 68 + k4 * 4];
      const float4 b3 = *(float4*)&Bm[(tn + 48) * 68 + k4 * 4];
      acc[0][0] += a0.x * b0.x + a0.y * b0.y + a0.z * b0.z + a0.w * b0.w;
      acc[0][1] += a0.x * b1.x + a0.y * b1.y + a0.z * b1.z + a0.w * b1.w;
      acc[0][2] += a0.x * b2.x + a0.y * b2.y + a0.z * b2.z + a0.w * b2.w;
      acc[0][3] += a0.x * b3.x + a0.y * b3.y + a0.z * b3.z + a0.w * b3.w;
      acc[1][0] += a1.x * b0.x + a1.y * b0.y + a1.z * b0.z + a1.w * b0.w;
      acc[1][1] += a1.x * b1.x + a1.y * b1.y + a1.z * b1.z + a1.w * b1.w;
      acc[1][2] += a1.x * b2.x + a1.y * b2.y + a1.z * b2.z + a1.w * b2.w;
      acc[1][3] += a1.x * b3.x + a1.y * b3.y + a1.z * b3.z + a1.w * b3.w;
    }
    __syncthreads();
  }
#pragma unroll
  for (int i = 0; i < 2; ++i) {
    const int m = m0 + tm + 16 * i;
    const int t = m >> 6, b = m & 63;
#pragma unroll
    for (int j = 0; j < 4; ++j) {
      const int o = o0 + tn + 16 * j;
      out[((long)b * STEPS + t) * OUT + o] = acc[i][j] + fc_b[o];
    }
  }
}

extern "C" void kernel_launch(void* const* d_in, const int* in_sizes, int n_in,
                              void* d_out, int out_size, void* d_ws, size_t ws_size,
                              hipStream_t stream) {
  const float* enc = (const float*)d_in[0];
  const float* hidden = (const float*)d_in[1];
  const float* attn_w = (const float*)d_in[2];
  // d_in[3] = attn_b: constant shift along softmax axis -> irrelevant.
  const float* w_ih = (const float*)d_in[4];
  const float* w_hh = (const float*)d_in[5];
  const float* b_ih = (const float*)d_in[6];
  const float* b_hh = (const float*)d_in[7];
  const float* fc_w = (const float*)d_in[8];
  const float* fc_b = (const float*)d_in[9];
  float* out = (float*)d_out;

  float* ws = (float*)d_ws;
  float* ctx      = ws;                  //   32768 f
  float* part_ctx = ctx + 32768;         //  262144 f
  float* part_ml  = part_ctx + 262144;   //    1024 f
  short* whi      = (short*)(part_ml + 1024);      // 1048576 shorts
  short* wlo      = whi + 1048576;                 // 1048576 shorts
  float* gates0   = (float*)(wlo + 1048576);       //  131072 f
  float* gbase2   = gates0 + 131072;     //  131072 f
  float* hs       = gbase2 + 131072;     // 32*32768 = 1048576 f
  float* cbuf     = hs + 1048576;        //   32768 f
  unsigned int* bar = (unsigned int*)(cbuf + 32768);  // 512 uints

  hipMemsetAsync(bar, 0, 512 * sizeof(unsigned int), stream);

  k_ctx_partial<<<dim3(8, 64), 256, 0, stream>>>(enc, attn_w, part_ctx, part_ml);
  k_weff<<<1024, 256, 0, stream>>>(w_ih, w_hh, fc_w, whi, wlo);
  k_ctx_reduce<<<64, 256, 0, stream>>>(part_ctx, part_ml, ctx);
  k_gbase<<<dim3(128, 4), 256, 0, stream>>>(w_ih, w_hh, b_ih, b_hh, fc_b, ctx,
                                            hidden, gates0, gbase2);
  k_cell0<<<128, 256, 0, stream>>>(gates0, hs, cbuf);

  const short* whi_p = whi;
  const short* wlo_p = wlo;
  const float* gbase2_p = gbase2;
  const float* cbuf_p = cbuf;
  float* hs_p = hs;
  unsigned int* bar_p = bar;
  void* kargs[] = {(void*)&whi_p, (void*)&wlo_p, (void*)&gbase2_p,
                   (void*)&cbuf_p, (void*)&hs_p, (void*)&bar_p};
  hipLaunchCooperativeKernel(reinterpret_cast<const void*>(k_recur2), dim3(256),
                             dim3(256), kargs, 0, stream);

  k_dec2<<<dim3(64, 4), 256, 0, stream>>>(hs, fc_w, fc_b, out);
}

// Round 9
// 315.514 us; speedup vs baseline: 2.2909x; 1.0988x over previous
//
#include <hip/hip_runtime.h>
#include <math.h>

#define B 64
#define S 1024
#define H 512
#define OUT 256
#define STEPS 32
#define NG 2048   // 4*H
#define X 768     // OUT + H

typedef __attribute__((ext_vector_type(8))) short short8;   // 8 bf16 = 4 VGPR
typedef __attribute__((ext_vector_type(4))) short s16x4;
typedef __attribute__((ext_vector_type(4))) float f32x4;

__device__ __forceinline__ float sigf(float x) { return 1.0f / (1.0f + __expf(-x)); }

__device__ __forceinline__ short f2bf(float x) {  // RNE float->bf16 bits
  union { float f; unsigned u; } a; a.f = x;
  unsigned r = a.u + 0x7fffu + ((a.u >> 16) & 1u);
  return (short)(r >> 16);
}
__device__ __forceinline__ float bf2f(short s) {
  union { unsigned u; float f; } a; a.u = ((unsigned)(unsigned short)s) << 16;
  return a.f;
}

// MALL-visible flag read (bypasses L1/L2) — proven in rounds 2/3/6/7 polling.
__device__ __forceinline__ unsigned load_u32_cg(const unsigned* p) {
  unsigned r;
  asm volatile("global_load_dword %0, %1, off sc0 sc1\n\ts_waitcnt vmcnt(0)"
               : "=v"(r) : "v"(p) : "memory");
  return r;
}

// ---------------- context: flash softmax-weighted sum over S ----------------
__global__ __launch_bounds__(256) void k_ctx_partial(
    const float* __restrict__ enc, const float* __restrict__ attn_w,
    float* __restrict__ part_ctx, float* __restrict__ part_ml) {
  const int b = blockIdx.y, chunk = blockIdx.x;
  const int wave = threadIdx.x >> 6, lane = threadIdx.x & 63;
  const float4 wa0 = *(const float4*)(attn_w + lane * 8);
  const float4 wa1 = *(const float4*)(attn_w + lane * 8 + 4);
  const float* eb = enc + (long)b * S * H;
  float m = -1e30f, l = 0.0f;
  float acc[8];
#pragma unroll
  for (int r = 0; r < 8; ++r) acc[r] = 0.0f;
  for (int i = 0; i < 32; ++i) {
    const int s = chunk * 128 + i * 4 + wave;
    const float* row = eb + (long)s * H + lane * 8;
    const float4 v0 = *(const float4*)row;
    const float4 v1 = *(const float4*)(row + 4);
    float e = v0.x * wa0.x + v0.y * wa0.y + v0.z * wa0.z + v0.w * wa0.w +
              v1.x * wa1.x + v1.y * wa1.y + v1.z * wa1.z + v1.w * wa1.w;
#pragma unroll
    for (int msk = 1; msk < 64; msk <<= 1) e += __shfl_xor(e, msk, 64);
    const float mn = fmaxf(m, e);
    const float sc = __expf(m - mn);
    const float p = __expf(e - mn);
    l = l * sc + p;
    m = mn;
    acc[0] = acc[0] * sc + p * v0.x; acc[1] = acc[1] * sc + p * v0.y;
    acc[2] = acc[2] * sc + p * v0.z; acc[3] = acc[3] * sc + p * v0.w;
    acc[4] = acc[4] * sc + p * v1.x; acc[5] = acc[5] * sc + p * v1.y;
    acc[6] = acc[6] * sc + p * v1.z; acc[7] = acc[7] * sc + p * v1.w;
  }
  __shared__ float sm_acc[4][H];
  __shared__ float sm_m[4], sm_l[4];
#pragma unroll
  for (int r = 0; r < 8; ++r) sm_acc[wave][lane * 8 + r] = acc[r];
  if (lane == 0) { sm_m[wave] = m; sm_l[wave] = l; }
  __syncthreads();
  const float mb = fmaxf(fmaxf(sm_m[0], sm_m[1]), fmaxf(sm_m[2], sm_m[3]));
  float e0[4];
#pragma unroll
  for (int w = 0; w < 4; ++w) e0[w] = __expf(sm_m[w] - mb);
  const int h0 = threadIdx.x * 2;
  float s0 = 0.f, s1 = 0.f;
#pragma unroll
  for (int w = 0; w < 4; ++w) { s0 += sm_acc[w][h0] * e0[w]; s1 += sm_acc[w][h0 + 1] * e0[w]; }
  float* pc = part_ctx + ((long)chunk * B + b) * H;
  pc[h0] = s0; pc[h0 + 1] = s1;
  if (threadIdx.x == 0) {
    const float lb = sm_l[0] * e0[0] + sm_l[1] * e0[1] + sm_l[2] * e0[2] + sm_l[3] * e0[3];
    part_ml[(chunk * B + b) * 2] = mb;
    part_ml[(chunk * B + b) * 2 + 1] = lb;
  }
}

__global__ __launch_bounds__(256) void k_ctx_reduce(
    const float* __restrict__ part_ctx, const float* __restrict__ part_ml,
    float* __restrict__ ctx) {
  const int b = blockIdx.x;
  float m = -1e30f;
#pragma unroll
  for (int c = 0; c < 8; ++c) m = fmaxf(m, part_ml[(c * B + b) * 2]);
  float L = 0.f, sc[8];
#pragma unroll
  for (int c = 0; c < 8; ++c) {
    sc[c] = __expf(part_ml[(c * B + b) * 2] - m);
    L += part_ml[(c * B + b) * 2 + 1] * sc[c];
  }
  const float inv = 1.0f / L;
  const int h0 = threadIdx.x * 2;
  float s0 = 0.f, s1 = 0.f;
#pragma unroll
  for (int c = 0; c < 8; ++c) {
    const float* pc = part_ctx + ((long)c * B + b) * H;
    s0 += pc[h0] * sc[c]; s1 += pc[h0 + 1] * sc[c];
  }
  ctx[(long)b * H + h0] = s0 * inv;
  ctx[(long)b * H + h0 + 1] = s1 * inv;
}

// ---------------- Weff = w_hh + Wd @ fc_w, split-bf16 (round-6 proven) ------
__global__ __launch_bounds__(256) void k_weff(
    const float* __restrict__ w_ih, const float* __restrict__ w_hh,
    const float* __restrict__ fc_w, short* __restrict__ whi,
    short* __restrict__ wlo) {
  const int flat4 = blockIdx.x * 256 + threadIdx.x;
  const int n = flat4 >> 7;
  const int k = (flat4 & 127) << 2;
  const float* wd = w_ih + (long)n * X;
  float v[4] = {0.f, 0.f, 0.f, 0.f};
  for (int j = 0; j < OUT; ++j) {
    const float w = wd[j];
    const float4 f = *(const float4*)(fc_w + (long)j * H + k);
    v[0] = fmaf(w, f.x, v[0]); v[1] = fmaf(w, f.y, v[1]);
    v[2] = fmaf(w, f.z, v[2]); v[3] = fmaf(w, f.w, v[3]);
  }
  const float4 hh = *(const float4*)(w_hh + (long)n * H + k);
  v[0] += hh.x; v[1] += hh.y; v[2] += hh.z; v[3] += hh.w;
  s16x4 hi4, lo4;
#pragma unroll
  for (int e = 0; e < 4; ++e) {
    const short hb = f2bf(v[e]);
    hi4[e] = hb;
    lo4[e] = f2bf(v[e] - bf2f(hb));
  }
  *(s16x4*)(whi + (long)n * H + k) = hi4;
  *(s16x4*)(wlo + (long)n * H + k) = lo4;
}

// ---------------- gates0 / gbase2 — coalesced, LDS-staged (51 KB) ----------
// gates0[b,n] = bias + Wc[n]·ctx[b] + Whh[n]·hidden[b];  gbase2 = bias + Wc·ctx + Wd·fc_b
// grid (64 n-tiles of 32, 4 b-quads of 16), 256 thr: n_l = tid&31, bh = tid>>5
// (each thread covers batches bh and bh+8). Weight tiles staged TRANSPOSED
// (wt[k][n], stride 33 -> conflict-free reads & writes); ctx/hidden rows in
// rb (stride 524 -> distinct banks for the 8 bh lanes).
__global__ __launch_bounds__(256) void k_gbase(
    const float* __restrict__ w_ih, const float* __restrict__ w_hh,
    const float* __restrict__ b_ih, const float* __restrict__ b_hh,
    const float* __restrict__ fc_b, const float* __restrict__ ctx,
    const float* __restrict__ hidden, float* __restrict__ gates0,
    float* __restrict__ gbase2) {
  __shared__ float wt[128][33];   // 16.9 KB
  __shared__ float rb[16][524];   // 33.5 KB
  __shared__ float sfc[256];
  const int n0 = blockIdx.x * 32, b0 = blockIdx.y * 16;
  const int tid = threadIdx.x;
  const int n_l = tid & 31, bh = tid >> 5;
  const int n = n0 + n_l;

  // stage ctx rows (coalesced float4)
  for (int i = tid; i < 16 * 128; i += 256) {
    const int r = i >> 7, c = (i & 127) << 2;
    *(float4*)&rb[r][c] = *(const float4*)(ctx + (long)(b0 + r) * H + c);
  }
  sfc[tid] = fc_b[tid];

  // pass 1: Wc . ctx  (4 k-chunks of 128)
  float a1a = 0.f, a1b = 0.f;
  for (int kc = 0; kc < 4; ++kc) {
    __syncthreads();
    for (int i = tid; i < 4096; i += 256) {
      const int r = i >> 7, c = i & 127;  // consecutive tid -> consecutive c: coalesced
      wt[c][r] = w_ih[(long)(n0 + r) * X + OUT + kc * 128 + c];
    }
    __syncthreads();
#pragma unroll 8
    for (int k = 0; k < 128; ++k) {
      const float wv = wt[k][n_l];
      a1a = fmaf(wv, rb[bh][kc * 128 + k], a1a);
      a1b = fmaf(wv, rb[bh + 8][kc * 128 + k], a1b);
    }
  }

  // db = Wd . fc_b  (2 k-chunks of 128)
  float db = 0.f;
  for (int kc = 0; kc < 2; ++kc) {
    __syncthreads();
    for (int i = tid; i < 4096; i += 256) {
      const int r = i >> 7, c = i & 127;
      wt[c][r] = w_ih[(long)(n0 + r) * X + kc * 128 + c];
    }
    __syncthreads();
#pragma unroll 8
    for (int k = 0; k < 128; ++k) db = fmaf(wt[k][n_l], sfc[kc * 128 + k], db);
  }

  // pass 2: Whh . hidden
  __syncthreads();
  for (int i = tid; i < 16 * 128; i += 256) {
    const int r = i >> 7, c = (i & 127) << 2;
    *(float4*)&rb[r][c] = *(const float4*)(hidden + (long)(b0 + r) * H + c);
  }
  float a2a = 0.f, a2b = 0.f;
  for (int kc = 0; kc < 4; ++kc) {
    __syncthreads();
    for (int i = tid; i < 4096; i += 256) {
      const int r = i >> 7, c = i & 127;
      wt[c][r] = w_hh[(long)(n0 + r) * H + kc * 128 + c];
    }
    __syncthreads();
#pragma unroll 8
    for (int k = 0; k < 128; ++k) {
      const float wv = wt[k][n_l];
      a2a = fmaf(wv, rb[bh][kc * 128 + k], a2a);
      a2b = fmaf(wv, rb[bh + 8][kc * 128 + k], a2b);
    }
  }

  const float bias = b_ih[n] + b_hh[n];
  gates0[(long)(b0 + bh) * NG + n]     = a1a + bias + a2a;
  gates0[(long)(b0 + bh + 8) * NG + n] = a1b + bias + a2b;
  gbase2[(long)(b0 + bh) * NG + n]     = a1a + bias + db;
  gbase2[(long)(b0 + bh + 8) * NG + n] = a1b + bias + db;
}

// ---------------- step 0 cell update (c0 = 0) ----------------
__global__ __launch_bounds__(256) void k_cell0(
    const float* __restrict__ gates0, float* __restrict__ h0,
    float* __restrict__ c0) {
  const int idx = blockIdx.x * 256 + threadIdx.x;
  const int b = idx >> 9, col = idx & 511;
  const float* g = gates0 + (long)b * NG;
  const float cn = sigf(g[col]) * tanhf(g[1024 + col]);
  const float hn = sigf(g[1536 + col]) * tanhf(cn);
  h0[idx] = hn;
  c0[idx] = cn;
}

// ---------------- persistent recurrence (round-7 sync protocol, verbatim) ---
// 256 blocks x 256 thr, 1/CU (cooperative). bg = blk&7 (8 batches);
// slice = blk>>3 (16 hidden cols). Weff split-bf16 PINNED in VGPRs (opaque
// asm -> no remat). c in LDS. Barrier: XCD vote; fast = relaxed MALL atomic
// + sc0sc1 poll; fallback = device-scope release/acquire. (Round-7-proven.)
#define HSTR 520
__global__ __launch_bounds__(256, 1) void k_recur2(
    const short* __restrict__ whi, const short* __restrict__ wlo,
    const float* __restrict__ gb2, const float* __restrict__ cbuf,
    float* __restrict__ hs, unsigned int* __restrict__ bar) {
  __shared__ short sh_hi[16 * HSTR];
  __shared__ short sh_lo[16 * HSTR];
  __shared__ float sG[4][8][20];
  __shared__ float sgb[8][64];
  __shared__ float scell[8][16];
  __shared__ int s_fast;

  const int blk = blockIdx.x;
  const int bg = blk & 7;
  const int b8 = bg << 3;
  const int hc0 = (blk >> 3) << 4;
  const int tid = threadIdx.x;
  const int w = tid >> 6, l = tid & 63;
  const int ln = l & 15, lk = l >> 4;

  // ---- placement vote (BEFORE weight loads: ACQUIRE may invalidate L2) ----
  if (tid == 0) {
    unsigned xcc;
    asm volatile("s_getreg_b32 %0, hwreg(20, 0, 32)" : "=s"(xcc));  // HW_REG_XCC_ID
    __hip_atomic_fetch_or(&bar[256 + bg], 1u << (xcc & 0xFu),
                          __ATOMIC_RELEASE, __HIP_MEMORY_SCOPE_AGENT);
    unsigned* gbar = &bar[264 + bg];
    __hip_atomic_fetch_add(gbar, 1u, __ATOMIC_RELEASE, __HIP_MEMORY_SCOPE_AGENT);
    while (load_u32_cg(gbar) < 32u) __builtin_amdgcn_s_sleep(1);
    const unsigned mask = __hip_atomic_load(&bar[256 + bg], __ATOMIC_ACQUIRE,
                                            __HIP_MEMORY_SCOPE_AGENT);
    s_fast = (__popc(mask) == 1) ? 1 : 0;
  }
  __syncthreads();
  const bool fast = (s_fast != 0);

  // zero h tile (rows 8..15 stay zero forever)
  for (int i = tid; i < 16 * HSTR; i += 256) { sh_hi[i] = 0; sh_lo[i] = 0; }

  // stage gbase2 slice and c(0) slice
  for (int idx = tid; idx < 512; idx += 256) {
    const int b = idx >> 6, gr = idx & 63, g = gr >> 4, j = gr & 15;
    sgb[b][gr] = gb2[(long)(b8 + b) * NG + (g << 9) + hc0 + j];
  }
  if (tid < 128) {
    const int b = tid >> 4, j = tid & 15;
    scell[b][j] = cbuf[(long)(b8 + b) * H + hc0 + j];
  }

  // Weff fragments: loaded ONCE, then PINNED opaque so the compiler cannot
  // rematerialize the loads inside the step loop (round 7: VGPR=88 proved it
  // re-loaded 128 KB/block/step from L2).
  short8 wh[16], wl[16];
  {
    const long wb = (long)((w << 9) + hc0 + ln) * H + (lk << 3);
#pragma unroll
    for (int kk = 0; kk < 16; ++kk) {
      wh[kk] = *(const short8*)(whi + wb + kk * 32);
      wl[kk] = *(const short8*)(wlo + wb + kk * 32);
    }
  }
#pragma unroll
  for (int kk = 0; kk < 16; ++kk) {
    asm volatile("" : "+v"(wh[kk]));
    asm volatile("" : "+v"(wl[kk]));
  }
  __syncthreads();

  for (int t = 1; t < STEPS; ++t) {
    // stage h(t-1): plain loads (fresh addresses each step -> L1 cannot be stale)
    const float* hsrc = hs + (long)(t - 1) * B * H + (long)b8 * H;
    for (int idx = tid; idx < 1024; idx += 256) {
      const int row = idx >> 7, kq = (idx & 127) << 2;
      float v[4];
      *(float4*)v = *(const float4*)(hsrc + (long)row * H + kq);
      s16x4 hi4, lo4;
#pragma unroll
      for (int e = 0; e < 4; ++e) {
        const short hb = f2bf(v[e]);
        hi4[e] = hb;
        lo4[e] = f2bf(v[e] - bf2f(hb));
      }
      *(s16x4*)&sh_hi[row * HSTR + kq] = hi4;
      *(s16x4*)&sh_lo[row * HSTR + kq] = lo4;
    }
    __syncthreads();

    // gates: 3 INDEPENDENT accumulator chains (was 48-deep single chain)
    f32x4 a0 = {0.f, 0.f, 0.f, 0.f};
    f32x4 a1 = {0.f, 0.f, 0.f, 0.f};
    f32x4 a2 = {0.f, 0.f, 0.f, 0.f};
    const int abase = ln * HSTR + (lk << 3);
#pragma unroll
    for (int kk = 0; kk < 16; ++kk) {
      const short8 ah = *(const short8*)&sh_hi[abase + kk * 32];
      const short8 al = *(const short8*)&sh_lo[abase + kk * 32];
      a0 = __builtin_amdgcn_mfma_f32_16x16x32_bf16(ah, wh[kk], a0, 0, 0, 0);
      a1 = __builtin_amdgcn_mfma_f32_16x16x32_bf16(al, wh[kk], a1, 0, 0, 0);
      a2 = __builtin_amdgcn_mfma_f32_16x16x32_bf16(ah, wl[kk], a2, 0, 0, 0);
    }
    if (lk < 2) {
#pragma unroll
      for (int r = 0; r < 4; ++r)
        sG[w][(lk << 2) + r][ln] = a0[r] + a1[r] + a2[r];
    }
    __syncthreads();

    // cell update + h store (plain; drained before barrier)
    if (tid < 128) {
      const int b = tid >> 4, j = tid & 15;
      const float gi = sG[0][b][j] + sgb[b][j];
      const float gf = sG[1][b][j] + sgb[b][16 + j];
      const float gg = sG[2][b][j] + sgb[b][32 + j];
      const float go = sG[3][b][j] + sgb[b][48 + j];
      const float c_old = scell[b][j];
      const float cn = sigf(gf) * c_old + sigf(gi) * tanhf(gg);
      const float hn = sigf(go) * tanhf(cn);
      scell[b][j] = cn;
      hs[(long)t * B * H + (long)(b8 + b) * H + hc0 + j] = hn;
      asm volatile("s_waitcnt vmcnt(0)" ::: "memory");  // store in L2
    }
    __syncthreads();

    if (t < STEPS - 1) {
      if (tid == 0) {
        unsigned int* flag = bar + t * 8 + bg;
        if (fast) {
          // same-XCD: L2 is the coherence point; no cache maintenance
          __hip_atomic_fetch_add(flag, 1u, __ATOMIC_RELAXED, __HIP_MEMORY_SCOPE_AGENT);
          while (load_u32_cg(flag) < 32u) __builtin_amdgcn_s_sleep(1);
        } else {
          // cross-XCD fallback: device-scope release/acquire (round-3 proven)
          __hip_atomic_fetch_add(flag, 1u, __ATOMIC_RELEASE, __HIP_MEMORY_SCOPE_AGENT);
          while (load_u32_cg(flag) < 32u) __builtin_amdgcn_s_sleep(1);
          (void)__hip_atomic_load(flag, __ATOMIC_ACQUIRE, __HIP_MEMORY_SCOPE_AGENT);
        }
      }
      __syncthreads();
    }
  }
}

// ---------------- final dec GEMM: out[b,t,:] = hs[t,b,:] @ fc_w^T + fc_b ----
__global__ __launch_bounds__(256) void k_dec2(
    const float* __restrict__ hs, const float* __restrict__ fc_w,
    const float* __restrict__ fc_b, float* __restrict__ out) {
  __shared__ float A[32 * 68];
  __shared__ float Bm[64 * 68];
  const int m0 = blockIdx.x * 32;
  const int o0 = blockIdx.y * 64;
  const int tid = threadIdx.x;
  const int tn = tid & 15, tm = tid >> 4;
  float acc[2][4] = {{0.f, 0.f, 0.f, 0.f}, {0.f, 0.f, 0.f, 0.f}};
  for (int k0 = 0; k0 < H; k0 += 64) {
    for (int idx = tid; idx < 512; idx += 256) {
      const int r = idx >> 4, k4 = idx & 15;
      *(float4*)&A[r * 68 + k4 * 4] =
          *(const float4*)&hs[(long)(m0 + r) * H + k0 + k4 * 4];
    }
    for (int idx = tid; idx < 1024; idx += 256) {
      const int r = idx >> 4, k4 = idx & 15;
      *(float4*)&Bm[r * 68 + k4 * 4] =
          *(const float4*)&fc_w[(long)(o0 + r) * H + k0 + k4 * 4];
    }
    __syncthreads();
#pragma unroll
    for (int k4 = 0; k4 < 16; ++k4) {
      const float4 a0 = *(float4*)&A[tm * 68 + k4 * 4];
      const float4 a1 = *(float4*)&A[(tm + 16) * 68 + k4 * 4];
      const float4 b0 = *(float4*)&Bm[tn * 68 + k4 * 4];
      const float4 b1 = *(float4*)&Bm[(tn + 16) * 68 + k4 * 4];
      const float4 b2 = *(float4*)&Bm[(tn + 32) * 68 + k4 * 4];
      const float4 b3 = *(float4*)&Bm[(tn + 48) * 68 + k4 * 4];
      acc[0][0] += a0.x * b0.x + a0.y * b0.y + a0.z * b0.z + a0.w * b0.w;
      acc[0][1] += a0.x * b1.x + a0.y * b1.y + a0.z * b1.z + a0.w * b1.w;
      acc[0][2] += a0.x * b2.x + a0.y * b2.y + a0.z * b2.z + a0.w * b2.w;
      acc[0][3] += a0.x * b3.x + a0.y * b3.y + a0.z * b3.z + a0.w * b3.w;
      acc[1][0] += a1.x * b0.x + a1.y * b0.y + a1.z * b0.z + a1.w * b0.w;
      acc[1][1] += a1.x * b1.x + a1.y * b1.y + a1.z * b1.z + a1.w * b1.w;
      acc[1][2] += a1.x * b2.x + a1.y * b2.y + a1.z * b2.z + a1.w * b2.w;
      acc[1][3] += a1.x * b3.x + a1.y * b3.y + a1.z * b3.z + a1.w * b3.w;
    }
    __syncthreads();
  }
#pragma unroll
  for (int i = 0; i < 2; ++i) {
    const int m = m0 + tm + 16 * i;
    const int t = m >> 6, b = m & 63;
#pragma unroll
    for (int j = 0; j < 4; ++j) {
      const int o = o0 + tn + 16 * j;
      out[((long)b * STEPS + t) * OUT + o] = acc[i][j] + fc_b[o];
    }
  }
}

extern "C" void kernel_launch(void* const* d_in, const int* in_sizes, int n_in,
                              void* d_out, int out_size, void* d_ws, size_t ws_size,
                              hipStream_t stream) {
  const float* enc = (const float*)d_in[0];
  const float* hidden = (const float*)d_in[1];
  const float* attn_w = (const float*)d_in[2];
  // d_in[3] = attn_b: constant shift along softmax axis -> irrelevant.
  const float* w_ih = (const float*)d_in[4];
  const float* w_hh = (const float*)d_in[5];
  const float* b_ih = (const float*)d_in[6];
  const float* b_hh = (const float*)d_in[7];
  const float* fc_w = (const float*)d_in[8];
  const float* fc_b = (const float*)d_in[9];
  float* out = (float*)d_out;

  float* ws = (float*)d_ws;
  float* ctx      = ws;                  //   32768 f
  float* part_ctx = ctx + 32768;         //  262144 f
  float* part_ml  = part_ctx + 262144;   //    1024 f
  short* whi      = (short*)(part_ml + 1024);      // 1048576 shorts
  short* wlo      = whi + 1048576;                 // 1048576 shorts
  float* gates0   = (float*)(wlo + 1048576);       //  131072 f
  float* gbase2   = gates0 + 131072;     //  131072 f
  float* hs       = gbase2 + 131072;     // 32*32768 = 1048576 f
  float* cbuf     = hs + 1048576;        //   32768 f
  unsigned int* bar = (unsigned int*)(cbuf + 32768);  // 512 uints

  hipMemsetAsync(bar, 0, 512 * sizeof(unsigned int), stream);

  k_ctx_partial<<<dim3(8, 64), 256, 0, stream>>>(enc, attn_w, part_ctx, part_ml);
  k_weff<<<1024, 256, 0, stream>>>(w_ih, w_hh, fc_w, whi, wlo);
  k_ctx_reduce<<<64, 256, 0, stream>>>(part_ctx, part_ml, ctx);
  k_gbase<<<dim3(64, 4), 256, 0, stream>>>(w_ih, w_hh, b_ih, b_hh, fc_b, ctx,
                                           hidden, gates0, gbase2);
  k_cell0<<<128, 256, 0, stream>>>(gates0, hs, cbuf);

  const short* whi_p = whi;
  const short* wlo_p = wlo;
  const float* gbase2_p = gbase2;
  const float* cbuf_p = cbuf;
  float* hs_p = hs;
  unsigned int* bar_p = bar;
  void* kargs[] = {(void*)&whi_p, (void*)&wlo_p, (void*)&gbase2_p,
                   (void*)&cbuf_p, (void*)&hs_p, (void*)&bar_p};
  hipLaunchCooperativeKernel(reinterpret_cast<const void*>(k_recur2), dim3(256),
                             dim3(256), kargs, 0, stream);

  k_dec2<<<dim3(64, 4), 256, 0, stream>>>(hs, fc_w, fc_b, out);
}

// Round 10
// 291.097 us; speedup vs baseline: 2.4831x; 1.0839x over previous
//
#include <hip/hip_runtime.h>
#include <math.h>

#define B 64
#define S 1024
#define H 512
#define OUT 256
#define STEPS 32
#define NG 2048   // 4*H
#define X 768     // OUT + H

typedef __attribute__((ext_vector_type(8))) short short8;   // 8 bf16 = 4 VGPR
typedef __attribute__((ext_vector_type(4))) short s16x4;
typedef __attribute__((ext_vector_type(4))) float f32x4;

__device__ __forceinline__ float sigf(float x) { return 1.0f / (1.0f + __expf(-x)); }

__device__ __forceinline__ short f2bf(float x) {  // RNE float->bf16 bits
  union { float f; unsigned u; } a; a.f = x;
  unsigned r = a.u + 0x7fffu + ((a.u >> 16) & 1u);
  return (short)(r >> 16);
}
__device__ __forceinline__ float bf2f(short s) {
  union { unsigned u; float f; } a; a.u = ((unsigned)(unsigned short)s) << 16;
  return a.f;
}

// MALL-visible flag read (bypasses L1/L2) — proven rounds 2/3/6/7/9.
__device__ __forceinline__ unsigned load_u32_cg(const unsigned* p) {
  unsigned r;
  asm volatile("global_load_dword %0, %1, off sc0 sc1\n\ts_waitcnt vmcnt(0)"
               : "=v"(r) : "v"(p) : "memory");
  return r;
}

// ---------------- context: flash softmax-weighted sum over S ----------------
__global__ __launch_bounds__(256) void k_ctx_partial(
    const float* __restrict__ enc, const float* __restrict__ attn_w,
    float* __restrict__ part_ctx, float* __restrict__ part_ml) {
  const int b = blockIdx.y, chunk = blockIdx.x;
  const int wave = threadIdx.x >> 6, lane = threadIdx.x & 63;
  const float4 wa0 = *(const float4*)(attn_w + lane * 8);
  const float4 wa1 = *(const float4*)(attn_w + lane * 8 + 4);
  const float* eb = enc + (long)b * S * H;
  float m = -1e30f, l = 0.0f;
  float acc[8];
#pragma unroll
  for (int r = 0; r < 8; ++r) acc[r] = 0.0f;
  for (int i = 0; i < 32; ++i) {
    const int s = chunk * 128 + i * 4 + wave;
    const float* row = eb + (long)s * H + lane * 8;
    const float4 v0 = *(const float4*)row;
    const float4 v1 = *(const float4*)(row + 4);
    float e = v0.x * wa0.x + v0.y * wa0.y + v0.z * wa0.z + v0.w * wa0.w +
              v1.x * wa1.x + v1.y * wa1.y + v1.z * wa1.z + v1.w * wa1.w;
#pragma unroll
    for (int msk = 1; msk < 64; msk <<= 1) e += __shfl_xor(e, msk, 64);
    const float mn = fmaxf(m, e);
    const float sc = __expf(m - mn);
    const float p = __expf(e - mn);
    l = l * sc + p;
    m = mn;
    acc[0] = acc[0] * sc + p * v0.x; acc[1] = acc[1] * sc + p * v0.y;
    acc[2] = acc[2] * sc + p * v0.z; acc[3] = acc[3] * sc + p * v0.w;
    acc[4] = acc[4] * sc + p * v1.x; acc[5] = acc[5] * sc + p * v1.y;
    acc[6] = acc[6] * sc + p * v1.z; acc[7] = acc[7] * sc + p * v1.w;
  }
  __shared__ float sm_acc[4][H];
  __shared__ float sm_m[4], sm_l[4];
#pragma unroll
  for (int r = 0; r < 8; ++r) sm_acc[wave][lane * 8 + r] = acc[r];
  if (lane == 0) { sm_m[wave] = m; sm_l[wave] = l; }
  __syncthreads();
  const float mb = fmaxf(fmaxf(sm_m[0], sm_m[1]), fmaxf(sm_m[2], sm_m[3]));
  float e0[4];
#pragma unroll
  for (int w = 0; w < 4; ++w) e0[w] = __expf(sm_m[w] - mb);
  const int h0 = threadIdx.x * 2;
  float s0 = 0.f, s1 = 0.f;
#pragma unroll
  for (int w = 0; w < 4; ++w) { s0 += sm_acc[w][h0] * e0[w]; s1 += sm_acc[w][h0 + 1] * e0[w]; }
  float* pc = part_ctx + ((long)chunk * B + b) * H;
  pc[h0] = s0; pc[h0 + 1] = s1;
  if (threadIdx.x == 0) {
    const float lb = sm_l[0] * e0[0] + sm_l[1] * e0[1] + sm_l[2] * e0[2] + sm_l[3] * e0[3];
    part_ml[(chunk * B + b) * 2] = mb;
    part_ml[(chunk * B + b) * 2 + 1] = lb;
  }
}

__global__ __launch_bounds__(256) void k_ctx_reduce(
    const float* __restrict__ part_ctx, const float* __restrict__ part_ml,
    float* __restrict__ ctx) {
  const int b = blockIdx.x;
  float m = -1e30f;
#pragma unroll
  for (int c = 0; c < 8; ++c) m = fmaxf(m, part_ml[(c * B + b) * 2]);
  float L = 0.f, sc[8];
#pragma unroll
  for (int c = 0; c < 8; ++c) {
    sc[c] = __expf(part_ml[(c * B + b) * 2] - m);
    L += part_ml[(c * B + b) * 2 + 1] * sc[c];
  }
  const float inv = 1.0f / L;
  const int h0 = threadIdx.x * 2;
  float s0 = 0.f, s1 = 0.f;
#pragma unroll
  for (int c = 0; c < 8; ++c) {
    const float* pc = part_ctx + ((long)c * B + b) * H;
    s0 += pc[h0] * sc[c]; s1 += pc[h0 + 1] * sc[c];
  }
  ctx[(long)b * H + h0] = s0 * inv;
  ctx[(long)b * H + h0 + 1] = s1 * inv;
}

// ---------------- Weff = w_hh + Wd @ fc_w, split-bf16 (round-6 proven) ------
__global__ __launch_bounds__(256) void k_weff(
    const float* __restrict__ w_ih, const float* __restrict__ w_hh,
    const float* __restrict__ fc_w, short* __restrict__ whi,
    short* __restrict__ wlo) {
  const int flat4 = blockIdx.x * 256 + threadIdx.x;
  const int n = flat4 >> 7;
  const int k = (flat4 & 127) << 2;
  const float* wd = w_ih + (long)n * X;
  float v[4] = {0.f, 0.f, 0.f, 0.f};
  for (int j = 0; j < OUT; ++j) {
    const float w = wd[j];
    const float4 f = *(const float4*)(fc_w + (long)j * H + k);
    v[0] = fmaf(w, f.x, v[0]); v[1] = fmaf(w, f.y, v[1]);
    v[2] = fmaf(w, f.z, v[2]); v[3] = fmaf(w, f.w, v[3]);
  }
  const float4 hh = *(const float4*)(w_hh + (long)n * H + k);
  v[0] += hh.x; v[1] += hh.y; v[2] += hh.z; v[3] += hh.w;
  s16x4 hi4, lo4;
#pragma unroll
  for (int e = 0; e < 4; ++e) {
    const short hb = f2bf(v[e]);
    hi4[e] = hb;
    lo4[e] = f2bf(v[e] - bf2f(hb));
  }
  *(s16x4*)(whi + (long)n * H + k) = hi4;
  *(s16x4*)(wlo + (long)n * H + k) = lo4;
}

// ---------------- gates0 / gbase2 — coalesced, LDS-staged (round-9 proven) --
__global__ __launch_bounds__(256) void k_gbase(
    const float* __restrict__ w_ih, const float* __restrict__ w_hh,
    const float* __restrict__ b_ih, const float* __restrict__ b_hh,
    const float* __restrict__ fc_b, const float* __restrict__ ctx,
    const float* __restrict__ hidden, float* __restrict__ gates0,
    float* __restrict__ gbase2) {
  __shared__ float wt[128][33];
  __shared__ float rb[16][524];
  __shared__ float sfc[256];
  const int n0 = blockIdx.x * 32, b0 = blockIdx.y * 16;
  const int tid = threadIdx.x;
  const int n_l = tid & 31, bh = tid >> 5;
  const int n = n0 + n_l;

  for (int i = tid; i < 16 * 128; i += 256) {
    const int r = i >> 7, c = (i & 127) << 2;
    *(float4*)&rb[r][c] = *(const float4*)(ctx + (long)(b0 + r) * H + c);
  }
  sfc[tid] = fc_b[tid];

  float a1a = 0.f, a1b = 0.f;
  for (int kc = 0; kc < 4; ++kc) {
    __syncthreads();
    for (int i = tid; i < 4096; i += 256) {
      const int r = i >> 7, c = i & 127;
      wt[c][r] = w_ih[(long)(n0 + r) * X + OUT + kc * 128 + c];
    }
    __syncthreads();
#pragma unroll 8
    for (int k = 0; k < 128; ++k) {
      const float wv = wt[k][n_l];
      a1a = fmaf(wv, rb[bh][kc * 128 + k], a1a);
      a1b = fmaf(wv, rb[bh + 8][kc * 128 + k], a1b);
    }
  }

  float db = 0.f;
  for (int kc = 0; kc < 2; ++kc) {
    __syncthreads();
    for (int i = tid; i < 4096; i += 256) {
      const int r = i >> 7, c = i & 127;
      wt[c][r] = w_ih[(long)(n0 + r) * X + kc * 128 + c];
    }
    __syncthreads();
#pragma unroll 8
    for (int k = 0; k < 128; ++k) db = fmaf(wt[k][n_l], sfc[kc * 128 + k], db);
  }

  __syncthreads();
  for (int i = tid; i < 16 * 128; i += 256) {
    const int r = i >> 7, c = (i & 127) << 2;
    *(float4*)&rb[r][c] = *(const float4*)(hidden + (long)(b0 + r) * H + c);
  }
  float a2a = 0.f, a2b = 0.f;
  for (int kc = 0; kc < 4; ++kc) {
    __syncthreads();
    for (int i = tid; i < 4096; i += 256) {
      const int r = i >> 7, c = i & 127;
      wt[c][r] = w_hh[(long)(n0 + r) * H + kc * 128 + c];
    }
    __syncthreads();
#pragma unroll 8
    for (int k = 0; k < 128; ++k) {
      const float wv = wt[k][n_l];
      a2a = fmaf(wv, rb[bh][kc * 128 + k], a2a);
      a2b = fmaf(wv, rb[bh + 8][kc * 128 + k], a2b);
    }
  }

  const float bias = b_ih[n] + b_hh[n];
  gates0[(long)(b0 + bh) * NG + n]     = a1a + bias + a2a;
  gates0[(long)(b0 + bh + 8) * NG + n] = a1b + bias + a2b;
  gbase2[(long)(b0 + bh) * NG + n]     = a1a + bias + db;
  gbase2[(long)(b0 + bh + 8) * NG + n] = a1b + bias + db;
}

// ---------------- step 0 cell update (c0 = 0) ----------------
__global__ __launch_bounds__(256) void k_cell0(
    const float* __restrict__ gates0, float* __restrict__ h0,
    float* __restrict__ c0) {
  const int idx = blockIdx.x * 256 + threadIdx.x;
  const int b = idx >> 9, col = idx & 511;
  const float* g = gates0 + (long)b * NG;
  const float cn = sigf(g[col]) * tanhf(g[1024 + col]);
  const float hn = sigf(g[1536 + col]) * tanhf(cn);
  h0[idx] = hn;
  c0[idx] = cn;
}

// ---------------- persistent recurrence ----------------
// 256 blocks x 256 thr, 1/CU (cooperative). bg = blk&7 (8 batches);
// slice = blk>>3 (16 hidden cols). Weff split-bf16 held in AGPRS: MFMA is
// inline asm with the B operand under an "a" constraint -> allocator must
// keep the 128 weight dwords/lane in AGPRs for the kernel lifetime (no
// remat/streaming; round 7/9 showed the compiler re-streams "v" weights).
// Barrier (round-7 protocol semantics, parallelized): per-slice MALL flags,
// one relaxed fetch_add per block on its OWN flag + wave-parallel sc0sc1
// poll. Fallback (cross-XCD group): device-scope release/acquire.
#define HSTR 520
__global__ __launch_bounds__(256, 1) void k_recur2(
    const short* __restrict__ whi, const short* __restrict__ wlo,
    const float* __restrict__ gb2, const float* __restrict__ cbuf,
    float* __restrict__ hs, unsigned int* __restrict__ bar) {
  __shared__ short sh_hi[16 * HSTR];
  __shared__ short sh_lo[16 * HSTR];
  __shared__ float sG[4][8][20];
  __shared__ float sgb[8][64];
  __shared__ float scell[8][16];
  __shared__ int s_fast;

  const int blk = blockIdx.x;
  const int bg = blk & 7;
  const int slice = blk >> 3;
  const int b8 = bg << 3;
  const int hc0 = slice << 4;
  const int tid = threadIdx.x;
  const int w = tid >> 6, l = tid & 63;
  const int ln = l & 15, lk = l >> 4;

  // ---- placement vote (vote words live at bar[7936..7951]) ----
  if (tid == 0) {
    unsigned xcc;
    asm volatile("s_getreg_b32 %0, hwreg(20, 0, 32)" : "=s"(xcc));  // HW_REG_XCC_ID
    __hip_atomic_fetch_or(&bar[7936 + bg], 1u << (xcc & 0xFu),
                          __ATOMIC_RELEASE, __HIP_MEMORY_SCOPE_AGENT);
    unsigned* gbar = &bar[7944 + bg];
    __hip_atomic_fetch_add(gbar, 1u, __ATOMIC_RELEASE, __HIP_MEMORY_SCOPE_AGENT);
    while (load_u32_cg(gbar) < 32u) __builtin_amdgcn_s_sleep(1);
    const unsigned mask = __hip_atomic_load(&bar[7936 + bg], __ATOMIC_ACQUIRE,
                                            __HIP_MEMORY_SCOPE_AGENT);
    s_fast = (__popc(mask) == 1) ? 1 : 0;
  }
  __syncthreads();
  const bool fast = (s_fast != 0);

  // zero h tile (rows 8..15 stay zero forever)
  for (int i = tid; i < 16 * HSTR; i += 256) { sh_hi[i] = 0; sh_lo[i] = 0; }

  // stage gbase2 slice and c(0) slice
  for (int idx = tid; idx < 512; idx += 256) {
    const int b = idx >> 6, gr = idx & 63, g = gr >> 4, j = gr & 15;
    sgb[b][gr] = gb2[(long)(b8 + b) * NG + (g << 9) + hc0 + j];
  }
  if (tid < 128) {
    const int b = tid >> 4, j = tid & 15;
    scell[b][j] = cbuf[(long)(b8 + b) * H + hc0 + j];
  }

  // Weff fragments -> AGPRs (used only through "a" asm constraints below)
  short8 wh[16], wl[16];
  {
    const long wb = (long)((w << 9) + hc0 + ln) * H + (lk << 3);
#pragma unroll
    for (int kk = 0; kk < 16; ++kk) {
      wh[kk] = *(const short8*)(whi + wb + kk * 32);
      wl[kk] = *(const short8*)(wlo + wb + kk * 32);
    }
  }
  __syncthreads();

  for (int t = 1; t < STEPS; ++t) {
    // stage h(t-1)
    const float* hsrc = hs + (long)(t - 1) * B * H + (long)b8 * H;
    for (int idx = tid; idx < 1024; idx += 256) {
      const int row = idx >> 7, kq = (idx & 127) << 2;
      float v[4];
      *(float4*)v = *(const float4*)(hsrc + (long)row * H + kq);
      s16x4 hi4, lo4;
#pragma unroll
      for (int e = 0; e < 4; ++e) {
        const short hb = f2bf(v[e]);
        hi4[e] = hb;
        lo4[e] = f2bf(v[e] - bf2f(hb));
      }
      *(s16x4*)&sh_hi[row * HSTR + kq] = hi4;
      *(s16x4*)&sh_lo[row * HSTR + kq] = lo4;
    }
    __syncthreads();

    // gates: 3 independent chains; B operands read straight from AGPRs.
    f32x4 a0 = {0.f, 0.f, 0.f, 0.f};
    f32x4 a1 = {0.f, 0.f, 0.f, 0.f};
    f32x4 a2 = {0.f, 0.f, 0.f, 0.f};
    asm volatile("s_nop 3" ::);  // VALU acc-init -> MFMA srcC hazard
    const int abase = ln * HSTR + (lk << 3);
#pragma unroll
    for (int kk = 0; kk < 16; ++kk) {
      const short8 ah = *(const short8*)&sh_hi[abase + kk * 32];
      const short8 al = *(const short8*)&sh_lo[abase + kk * 32];
      asm volatile("v_mfma_f32_16x16x32_bf16 %0, %1, %2, %0"
                   : "+v"(a0) : "v"(ah), "a"(wh[kk]));
      asm volatile("v_mfma_f32_16x16x32_bf16 %0, %1, %2, %0"
                   : "+v"(a1) : "v"(al), "a"(wh[kk]));
      asm volatile("v_mfma_f32_16x16x32_bf16 %0, %1, %2, %0"
                   : "+v"(a2) : "v"(ah), "a"(wl[kk]));
    }
    asm volatile("s_nop 7\n\ts_nop 7" ::);  // MFMA result latency before VALU read
    if (lk < 2) {
#pragma unroll
      for (int r = 0; r < 4; ++r)
        sG[w][(lk << 2) + r][ln] = a0[r] + a1[r] + a2[r];
    }
    __syncthreads();

    // cell update + h store (plain; drained before flag)
    if (tid < 128) {
      const int b = tid >> 4, j = tid & 15;
      const float gi = sG[0][b][j] + sgb[b][j];
      const float gf = sG[1][b][j] + sgb[b][16 + j];
      const float gg = sG[2][b][j] + sgb[b][32 + j];
      const float go = sG[3][b][j] + sgb[b][48 + j];
      const float c_old = scell[b][j];
      const float cn = sigf(gf) * c_old + sigf(gi) * tanhf(gg);
      const float hn = sigf(go) * tanhf(cn);
      scell[b][j] = cn;
      hs[(long)t * B * H + (long)(b8 + b) * H + hc0 + j] = hn;
      asm volatile("s_waitcnt vmcnt(0)" ::: "memory");  // store committed to L2
    }
    __syncthreads();

    if (t < STEPS - 1) {
      unsigned* flags = bar + t * 256 + bg * 32;  // 32 per-slice words
      if (fast) {
        // same-XCD: h via shared L2; flags via MALL atomics (parallel adds)
        if (tid == 0)
          __hip_atomic_fetch_add(&flags[slice], 1u, __ATOMIC_RELAXED,
                                 __HIP_MEMORY_SCOPE_AGENT);
        if (tid < 64) {
          while (!__all(load_u32_cg(flags + (tid & 31)) != 0u))
            __builtin_amdgcn_s_sleep(1);
        }
      } else {
        // cross-XCD fallback: device-scope release/acquire
        if (tid == 0)
          __hip_atomic_fetch_add(&flags[slice], 1u, __ATOMIC_RELEASE,
                                 __HIP_MEMORY_SCOPE_AGENT);
        if (tid < 64) {
          while (!__all(load_u32_cg(flags + (tid & 31)) != 0u))
            __builtin_amdgcn_s_sleep(1);
        }
        if (tid == 0)
          (void)__hip_atomic_load(&flags[0], __ATOMIC_ACQUIRE,
                                  __HIP_MEMORY_SCOPE_AGENT);
      }
      __syncthreads();
    }
  }
}

// ---------------- final dec GEMM: out[b,t,:] = hs[t,b,:] @ fc_w^T + fc_b ----
__global__ __launch_bounds__(256) void k_dec2(
    const float* __restrict__ hs, const float* __restrict__ fc_w,
    const float* __restrict__ fc_b, float* __restrict__ out) {
  __shared__ float A[32 * 68];
  __shared__ float Bm[64 * 68];
  const int m0 = blockIdx.x * 32;
  const int o0 = blockIdx.y * 64;
  const int tid = threadIdx.x;
  const int tn = tid & 15, tm = tid >> 4;
  float acc[2][4] = {{0.f, 0.f, 0.f, 0.f}, {0.f, 0.f, 0.f, 0.f}};
  for (int k0 = 0; k0 < H; k0 += 64) {
    for (int idx = tid; idx < 512; idx += 256) {
      const int r = idx >> 4, k4 = idx & 15;
      *(float4*)&A[r * 68 + k4 * 4] =
          *(const float4*)&hs[(long)(m0 + r) * H + k0 + k4 * 4];
    }
    for (int idx = tid; idx < 1024; idx += 256) {
      const int r = idx >> 4, k4 = idx & 15;
      *(float4*)&Bm[r * 68 + k4 * 4] =
          *(const float4*)&fc_w[(long)(o0 + r) * H + k0 + k4 * 4];
    }
    __syncthreads();
#pragma unroll
    for (int k4 = 0; k4 < 16; ++k4) {
      const float4 a0 = *(float4*)&A[tm * 68 + k4 * 4];
      const float4 a1 = *(float4*)&A[(tm + 16) * 68 + k4 * 4];
      const float4 b0 = *(float4*)&Bm[tn * 68 + k4 * 4];
      const float4 b1 = *(float4*)&Bm[(tn + 16) * 68 + k4 * 4];
      const float4 b2 = *(float4*)&Bm[(tn + 32) * 68 + k4 * 4];
      const float4 b3 = *(float4*)&Bm[(tn + 48) * 68 + k4 * 4];
      acc[0][0] += a0.x * b0.x + a0.y * b0.y + a0.z * b0.z + a0.w * b0.w;
      acc[0][1] += a0.x * b1.x + a0.y * b1.y + a0.z * b1.z + a0.w * b1.w;
      acc[0][2] += a0.x * b2.x + a0.y * b2.y + a0.z * b2.z + a0.w * b2.w;
      acc[0][3] += a0.x * b3.x + a0.y * b3.y + a0.z * b3.z + a0.w * b3.w;
      acc[1][0] += a1.x * b0.x + a1.y * b0.y + a1.z * b0.z + a1.w * b0.w;
      acc[1][1] += a1.x * b1.x + a1.y * b1.y + a1.z * b1.z + a1.w * b1.w;
      acc[1][2] += a1.x * b2.x + a1.y * b2.y + a1.z * b2.z + a1.w * b2.w;
      acc[1][3] += a1.x * b3.x + a1.y * b3.y + a1.z * b3.z + a1.w * b3.w;
    }
    __syncthreads();
  }
#pragma unroll
  for (int i = 0; i < 2; ++i) {
    const int m = m0 + tm + 16 * i;
    const int t = m >> 6, b = m & 63;
#pragma unroll
    for (int j = 0; j < 4; ++j) {
      const int o = o0 + tn + 16 * j;
      out[((long)b * STEPS + t) * OUT + o] = acc[i][j] + fc_b[o];
    }
  }
}

extern "C" void kernel_launch(void* const* d_in, const int* in_sizes, int n_in,
                              void* d_out, int out_size, void* d_ws, size_t ws_size,
                              hipStream_t stream) {
  const float* enc = (const float*)d_in[0];
  const float* hidden = (const float*)d_in[1];
  const float* attn_w = (const float*)d_in[2];
  // d_in[3] = attn_b: constant shift along softmax axis -> irrelevant.
  const float* w_ih = (const float*)d_in[4];
  const float* w_hh = (const float*)d_in[5];
  const float* b_ih = (const float*)d_in[6];
  const float* b_hh = (const float*)d_in[7];
  const float* fc_w = (const float*)d_in[8];
  const float* fc_b = (const float*)d_in[9];
  float* out = (float*)d_out;

  float* ws = (float*)d_ws;
  float* ctx      = ws;                  //   32768 f
  float* part_ctx = ctx + 32768;         //  262144 f  (reused as bar after reduce)
  float* part_ml  = part_ctx + 262144;   //    1024 f
  short* whi      = (short*)(part_ml + 1024);      // 1048576 shorts
  short* wlo      = whi + 1048576;                 // 1048576 shorts
  float* gates0   = (float*)(wlo + 1048576);       //  131072 f
  float* gbase2   = gates0 + 131072;     //  131072 f
  float* hs       = gbase2 + 131072;     // 32*32768 = 1048576 f
  float* cbuf     = hs + 1048576;        //   32768 f
  unsigned int* bar = (unsigned int*)part_ctx;  // 7952 uints, dead after reduce

  k_ctx_partial<<<dim3(8, 64), 256, 0, stream>>>(enc, attn_w, part_ctx, part_ml);
  k_weff<<<1024, 256, 0, stream>>>(w_ih, w_hh, fc_w, whi, wlo);
  k_ctx_reduce<<<64, 256, 0, stream>>>(part_ctx, part_ml, ctx);
  // part_ctx is dead now; zero the flag region (stream-ordered)
  hipMemsetAsync(bar, 0, 7952 * sizeof(unsigned int), stream);
  k_gbase<<<dim3(64, 4), 256, 0, stream>>>(w_ih, w_hh, b_ih, b_hh, fc_b, ctx,
                                           hidden, gates0, gbase2);
  k_cell0<<<128, 256, 0, stream>>>(gates0, hs, cbuf);

  const short* whi_p = whi;
  const short* wlo_p = wlo;
  const float* gbase2_p = gbase2;
  const float* cbuf_p = cbuf;
  float* hs_p = hs;
  unsigned int* bar_p = bar;
  void* kargs[] = {(void*)&whi_p, (void*)&wlo_p, (void*)&gbase2_p,
                   (void*)&cbuf_p, (void*)&hs_p, (void*)&bar_p};
  hipLaunchCooperativeKernel(reinterpret_cast<const void*>(k_recur2), dim3(256),
                             dim3(256), kargs, 0, stream);

  k_dec2<<<dim3(64, 4), 256, 0, stream>>>(hs, fc_w, fc_b, out);
}

// Round 11
// 246.150 us; speedup vs baseline: 2.9365x; 1.1826x over previous
//
#include <hip/hip_runtime.h>
#include <math.h>

#define B 64
#define S 1024
#define H 512
#define OUT 256
#define STEPS 32
#define NG 2048   // 4*H
#define X 768     // OUT + H

typedef __attribute__((ext_vector_type(8))) short short8;   // 8 bf16 = 4 VGPR
typedef __attribute__((ext_vector_type(4))) short s16x4;
typedef __attribute__((ext_vector_type(4))) float f32x4;
typedef __attribute__((ext_vector_type(4))) unsigned u32x4;

__device__ __forceinline__ float sigf(float x) { return 1.0f / (1.0f + __expf(-x)); }
// saturation-safe fast tanh: 2*sigmoid(2x)-1 (exp->inf => rcp->0 => -1; exp->0 => +1)
__device__ __forceinline__ float tanhf_fast(float x) {
  return 2.0f / (1.0f + __expf(-2.0f * x)) - 1.0f;
}

__device__ __forceinline__ short f2bf(float x) {  // RNE float->bf16 bits
  union { float f; unsigned u; } a; a.f = x;
  unsigned r = a.u + 0x7fffu + ((a.u >> 16) & 1u);
  return (short)(r >> 16);
}
__device__ __forceinline__ float bf2f(short s) {
  union { unsigned u; float f; } a; a.u = ((unsigned)(unsigned short)s) << 16;
  return a.f;
}

// MALL-visible flag read (bypasses L1/L2) — proven rounds 2/3/6/7/9/10.
__device__ __forceinline__ unsigned load_u32_cg(const unsigned* p) {
  unsigned r;
  asm volatile("global_load_dword %0, %1, off sc0 sc1\n\ts_waitcnt vmcnt(0)"
               : "=v"(r) : "v"(p) : "memory");
  return r;
}

// ---------------- fused: ctx flash-partial (blocks 0..511) + Weff (512..1535)
__global__ __launch_bounds__(256) void k_pre(
    const float* __restrict__ enc, const float* __restrict__ attn_w,
    float* __restrict__ part_ctx, float* __restrict__ part_ml,
    const float* __restrict__ w_ih, const float* __restrict__ w_hh,
    const float* __restrict__ fc_w, short* __restrict__ whi,
    short* __restrict__ wlo) {
  __shared__ float sm_acc[4][H];
  __shared__ float sm_m[4], sm_l[4];
  const int cid = blockIdx.x;
  if (cid < 512) {
    // ---- ctx partial: chunk = cid&7, b = cid>>3 ----
    const int b = cid >> 3, chunk = cid & 7;
    const int wave = threadIdx.x >> 6, lane = threadIdx.x & 63;
    const float4 wa0 = *(const float4*)(attn_w + lane * 8);
    const float4 wa1 = *(const float4*)(attn_w + lane * 8 + 4);
    const float* eb = enc + (long)b * S * H;
    float m = -1e30f, l = 0.0f;
    float acc[8];
#pragma unroll
    for (int r = 0; r < 8; ++r) acc[r] = 0.0f;
    for (int i = 0; i < 32; ++i) {
      const int s = chunk * 128 + i * 4 + wave;
      const float* row = eb + (long)s * H + lane * 8;
      const float4 v0 = *(const float4*)row;
      const float4 v1 = *(const float4*)(row + 4);
      float e = v0.x * wa0.x + v0.y * wa0.y + v0.z * wa0.z + v0.w * wa0.w +
                v1.x * wa1.x + v1.y * wa1.y + v1.z * wa1.z + v1.w * wa1.w;
#pragma unroll
      for (int msk = 1; msk < 64; msk <<= 1) e += __shfl_xor(e, msk, 64);
      const float mn = fmaxf(m, e);
      const float sc = __expf(m - mn);
      const float p = __expf(e - mn);
      l = l * sc + p;
      m = mn;
      acc[0] = acc[0] * sc + p * v0.x; acc[1] = acc[1] * sc + p * v0.y;
      acc[2] = acc[2] * sc + p * v0.z; acc[3] = acc[3] * sc + p * v0.w;
      acc[4] = acc[4] * sc + p * v1.x; acc[5] = acc[5] * sc + p * v1.y;
      acc[6] = acc[6] * sc + p * v1.z; acc[7] = acc[7] * sc + p * v1.w;
    }
#pragma unroll
    for (int r = 0; r < 8; ++r) sm_acc[wave][lane * 8 + r] = acc[r];
    if (lane == 0) { sm_m[wave] = m; sm_l[wave] = l; }
    __syncthreads();
    const float mb = fmaxf(fmaxf(sm_m[0], sm_m[1]), fmaxf(sm_m[2], sm_m[3]));
    float e0[4];
#pragma unroll
    for (int w = 0; w < 4; ++w) e0[w] = __expf(sm_m[w] - mb);
    const int h0 = threadIdx.x * 2;
    float s0 = 0.f, s1 = 0.f;
#pragma unroll
    for (int w = 0; w < 4; ++w) { s0 += sm_acc[w][h0] * e0[w]; s1 += sm_acc[w][h0 + 1] * e0[w]; }
    float* pc = part_ctx + ((long)chunk * B + b) * H;
    pc[h0] = s0; pc[h0 + 1] = s1;
    if (threadIdx.x == 0) {
      const float lb = sm_l[0] * e0[0] + sm_l[1] * e0[1] + sm_l[2] * e0[2] + sm_l[3] * e0[3];
      part_ml[(chunk * B + b) * 2] = mb;
      part_ml[(chunk * B + b) * 2 + 1] = lb;
    }
  } else {
    // ---- Weff = w_hh + Wd @ fc_w, split-bf16 (round-6 proven body) ----
    const int flat4 = (cid - 512) * 256 + threadIdx.x;
    const int n = flat4 >> 7;
    const int k = (flat4 & 127) << 2;
    const float* wd = w_ih + (long)n * X;
    float v[4] = {0.f, 0.f, 0.f, 0.f};
    for (int j = 0; j < OUT; ++j) {
      const float w = wd[j];
      const float4 f = *(const float4*)(fc_w + (long)j * H + k);
      v[0] = fmaf(w, f.x, v[0]); v[1] = fmaf(w, f.y, v[1]);
      v[2] = fmaf(w, f.z, v[2]); v[3] = fmaf(w, f.w, v[3]);
    }
    const float4 hh = *(const float4*)(w_hh + (long)n * H + k);
    v[0] += hh.x; v[1] += hh.y; v[2] += hh.z; v[3] += hh.w;
    s16x4 hi4, lo4;
#pragma unroll
    for (int e = 0; e < 4; ++e) {
      const short hb = f2bf(v[e]);
      hi4[e] = hb;
      lo4[e] = f2bf(v[e] - bf2f(hb));
    }
    *(s16x4*)(whi + (long)n * H + k) = hi4;
    *(s16x4*)(wlo + (long)n * H + k) = lo4;
  }
}

__global__ __launch_bounds__(256) void k_ctx_reduce(
    const float* __restrict__ part_ctx, const float* __restrict__ part_ml,
    float* __restrict__ ctx) {
  const int b = blockIdx.x;
  float m = -1e30f;
#pragma unroll
  for (int c = 0; c < 8; ++c) m = fmaxf(m, part_ml[(c * B + b) * 2]);
  float L = 0.f, sc[8];
#pragma unroll
  for (int c = 0; c < 8; ++c) {
    sc[c] = __expf(part_ml[(c * B + b) * 2] - m);
    L += part_ml[(c * B + b) * 2 + 1] * sc[c];
  }
  const float inv = 1.0f / L;
  const int h0 = threadIdx.x * 2;
  float s0 = 0.f, s1 = 0.f;
#pragma unroll
  for (int c = 0; c < 8; ++c) {
    const float* pc = part_ctx + ((long)c * B + b) * H;
    s0 += pc[h0] * sc[c]; s1 += pc[h0 + 1] * sc[c];
  }
  ctx[(long)b * H + h0] = s0 * inv;
  ctx[(long)b * H + h0 + 1] = s1 * inv;
}

// ---------------- gates0 / gbase2 — coalesced, LDS-staged (round-9 proven) --
__global__ __launch_bounds__(256) void k_gbase(
    const float* __restrict__ w_ih, const float* __restrict__ w_hh,
    const float* __restrict__ b_ih, const float* __restrict__ b_hh,
    const float* __restrict__ fc_b, const float* __restrict__ ctx,
    const float* __restrict__ hidden, float* __restrict__ gates0,
    float* __restrict__ gbase2) {
  __shared__ float wt[128][33];
  __shared__ float rb[16][524];
  __shared__ float sfc[256];
  const int n0 = blockIdx.x * 32, b0 = blockIdx.y * 16;
  const int tid = threadIdx.x;
  const int n_l = tid & 31, bh = tid >> 5;
  const int n = n0 + n_l;

  for (int i = tid; i < 16 * 128; i += 256) {
    const int r = i >> 7, c = (i & 127) << 2;
    *(float4*)&rb[r][c] = *(const float4*)(ctx + (long)(b0 + r) * H + c);
  }
  sfc[tid] = fc_b[tid];

  float a1a = 0.f, a1b = 0.f;
  for (int kc = 0; kc < 4; ++kc) {
    __syncthreads();
    for (int i = tid; i < 4096; i += 256) {
      const int r = i >> 7, c = i & 127;
      wt[c][r] = w_ih[(long)(n0 + r) * X + OUT + kc * 128 + c];
    }
    __syncthreads();
#pragma unroll 8
    for (int k = 0; k < 128; ++k) {
      const float wv = wt[k][n_l];
      a1a = fmaf(wv, rb[bh][kc * 128 + k], a1a);
      a1b = fmaf(wv, rb[bh + 8][kc * 128 + k], a1b);
    }
  }

  float db = 0.f;
  for (int kc = 0; kc < 2; ++kc) {
    __syncthreads();
    for (int i = tid; i < 4096; i += 256) {
      const int r = i >> 7, c = i & 127;
      wt[c][r] = w_ih[(long)(n0 + r) * X + kc * 128 + c];
    }
    __syncthreads();
#pragma unroll 8
    for (int k = 0; k < 128; ++k) db = fmaf(wt[k][n_l], sfc[kc * 128 + k], db);
  }

  __syncthreads();
  for (int i = tid; i < 16 * 128; i += 256) {
    const int r = i >> 7, c = (i & 127) << 2;
    *(float4*)&rb[r][c] = *(const float4*)(hidden + (long)(b0 + r) * H + c);
  }
  float a2a = 0.f, a2b = 0.f;
  for (int kc = 0; kc < 4; ++kc) {
    __syncthreads();
    for (int i = tid; i < 4096; i += 256) {
      const int r = i >> 7, c = i & 127;
      wt[c][r] = w_hh[(long)(n0 + r) * H + kc * 128 + c];
    }
    __syncthreads();
#pragma unroll 8
    for (int k = 0; k < 128; ++k) {
      const float wv = wt[k][n_l];
      a2a = fmaf(wv, rb[bh][kc * 128 + k], a2a);
      a2b = fmaf(wv, rb[bh + 8][kc * 128 + k], a2b);
    }
  }

  const float bias = b_ih[n] + b_hh[n];
  gates0[(long)(b0 + bh) * NG + n]     = a1a + bias + a2a;
  gates0[(long)(b0 + bh + 8) * NG + n] = a1b + bias + a2b;
  gbase2[(long)(b0 + bh) * NG + n]     = a1a + bias + db;
  gbase2[(long)(b0 + bh + 8) * NG + n] = a1b + bias + db;
}

// ---------------- persistent recurrence (round-10 proven sync, cell0 fused) -
// 256 blocks x 256 thr, 1/CU. bg = blk&7 (8 batches); slice = blk>>3 (16
// cols). Weff split-bf16 via "a"-constrained asm MFMA. h exchanged as PACKED
// split-bf16 (hi | lo<<16) through the same-XCD L2; per-step per-slice MALL
// flags (relaxed add + sc0sc1 wave-parallel poll); cross-XCD fallback uses
// device-scope release/acquire. Step 0 (cell-only, c0=0) fused as prologue.
#define HSTR 520
__global__ __launch_bounds__(256, 1) void k_recur3(
    const short* __restrict__ whi, const short* __restrict__ wlo,
    const float* __restrict__ gb2, const float* __restrict__ gates0,
    unsigned* __restrict__ hsbf, unsigned int* __restrict__ bar) {
  __shared__ short sh_hi[16 * HSTR];
  __shared__ short sh_lo[16 * HSTR];
  __shared__ float sG[4][8][20];
  __shared__ float sgb[8][64];
  __shared__ float scell[8][16];
  __shared__ int s_fast;

  const int blk = blockIdx.x;
  const int bg = blk & 7;
  const int slice = blk >> 3;
  const int b8 = bg << 3;
  const int hc0 = slice << 4;
  const int tid = threadIdx.x;
  const int w = tid >> 6, l = tid & 63;
  const int ln = l & 15, lk = l >> 4;

  // ---- placement vote (vote words at bar[7936..7951]) ----
  if (tid == 0) {
    unsigned xcc;
    asm volatile("s_getreg_b32 %0, hwreg(20, 0, 32)" : "=s"(xcc));  // HW_REG_XCC_ID
    __hip_atomic_fetch_or(&bar[7936 + bg], 1u << (xcc & 0xFu),
                          __ATOMIC_RELEASE, __HIP_MEMORY_SCOPE_AGENT);
    unsigned* gbar = &bar[7944 + bg];
    __hip_atomic_fetch_add(gbar, 1u, __ATOMIC_RELEASE, __HIP_MEMORY_SCOPE_AGENT);
    while (load_u32_cg(gbar) < 32u) __builtin_amdgcn_s_sleep(1);
    const unsigned mask = __hip_atomic_load(&bar[7936 + bg], __ATOMIC_ACQUIRE,
                                            __HIP_MEMORY_SCOPE_AGENT);
    s_fast = (__popc(mask) == 1) ? 1 : 0;
  }
  __syncthreads();
  const bool fast = (s_fast != 0);

  // zero h tile (rows 8..15 stay zero forever)
  for (int i = tid; i < 16 * HSTR; i += 256) { sh_hi[i] = 0; sh_lo[i] = 0; }

  // stage gbase2 slice
  for (int idx = tid; idx < 512; idx += 256) {
    const int b = idx >> 6, gr = idx & 63, g = gr >> 4, j = gr & 15;
    sgb[b][gr] = gb2[(long)(b8 + b) * NG + (g << 9) + hc0 + j];
  }

  // Weff fragments (AGPR-bound via "a" asm constraints in the MFMA)
  short8 wh[16], wl[16];
  {
    const long wb = (long)((w << 9) + hc0 + ln) * H + (lk << 3);
#pragma unroll
    for (int kk = 0; kk < 16; ++kk) {
      wh[kk] = *(const short8*)(whi + wb + kk * 32);
      wl[kk] = *(const short8*)(wlo + wb + kk * 32);
    }
  }
  __syncthreads();

  // ---- fused step 0: cell update from precomputed gates0 (c0 = 0) ----
  if (tid < 128) {
    const int b = tid >> 4, j = tid & 15;
    const float* g0 = gates0 + (long)(b8 + b) * NG + hc0 + j;
    const float gi = g0[0];
    const float gg = g0[1024];
    const float go = g0[1536];
    const float cn = sigf(gi) * tanhf_fast(gg);
    const float hn = sigf(go) * tanhf_fast(cn);
    scell[b][j] = cn;
    const short hi = f2bf(hn);
    const short lo = f2bf(hn - bf2f(hi));
    hsbf[(long)(b8 + b) * H + hc0 + j] =
        (unsigned)(unsigned short)hi | ((unsigned)(unsigned short)lo << 16);
  }
  __syncthreads();  // drains h stores to L2
  {
    unsigned* flags = bar + bg * 32;  // t = 0 region
    if (fast) {
      if (tid == 0)
        __hip_atomic_fetch_add(&flags[slice], 1u, __ATOMIC_RELAXED,
                               __HIP_MEMORY_SCOPE_AGENT);
      if (tid < 64) {
        while (!__all(load_u32_cg(flags + (tid & 31)) != 0u)) {}
      }
    } else {
      if (tid == 0)
        __hip_atomic_fetch_add(&flags[slice], 1u, __ATOMIC_RELEASE,
                               __HIP_MEMORY_SCOPE_AGENT);
      if (tid < 64) {
        while (!__all(load_u32_cg(flags + (tid & 31)) != 0u)) {}
      }
      if (tid == 0)
        (void)__hip_atomic_load(&flags[0], __ATOMIC_ACQUIRE,
                                __HIP_MEMORY_SCOPE_AGENT);
    }
    __syncthreads();
  }

  for (int t = 1; t < STEPS; ++t) {
    // stage h(t-1): packed uints -> split-bf16 LDS (pure bit ops)
    const unsigned* hb = hsbf + (long)(t - 1) * B * H + (long)b8 * H;
#pragma unroll
    for (int q = 0; q < 4; ++q) {
      const int d0 = q * 1024 + tid * 4;  // 4 consecutive dwords, coalesced
      const u32x4 v = *(const u32x4*)(hb + d0);
      const int row = d0 >> 9, col = d0 & 511;
      s16x4 hi4, lo4;
#pragma unroll
      for (int e = 0; e < 4; ++e) {
        hi4[e] = (short)(v[e] & 0xFFFFu);
        lo4[e] = (short)(v[e] >> 16);
      }
      *(s16x4*)&sh_hi[row * HSTR + col] = hi4;
      *(s16x4*)&sh_lo[row * HSTR + col] = lo4;
    }
    __syncthreads();

    // gates: 3 independent chains; B operands from AGPRs
    f32x4 a0 = {0.f, 0.f, 0.f, 0.f};
    f32x4 a1 = {0.f, 0.f, 0.f, 0.f};
    f32x4 a2 = {0.f, 0.f, 0.f, 0.f};
    asm volatile("s_nop 3" ::);  // VALU acc-init -> MFMA srcC hazard
    const int abase = ln * HSTR + (lk << 3);
#pragma unroll
    for (int kk = 0; kk < 16; ++kk) {
      const short8 ah = *(const short8*)&sh_hi[abase + kk * 32];
      const short8 al = *(const short8*)&sh_lo[abase + kk * 32];
      asm volatile("v_mfma_f32_16x16x32_bf16 %0, %1, %2, %0"
                   : "+v"(a0) : "v"(ah), "a"(wh[kk]));
      asm volatile("v_mfma_f32_16x16x32_bf16 %0, %1, %2, %0"
                   : "+v"(a1) : "v"(al), "a"(wh[kk]));
      asm volatile("v_mfma_f32_16x16x32_bf16 %0, %1, %2, %0"
                   : "+v"(a2) : "v"(ah), "a"(wl[kk]));
    }
    asm volatile("s_nop 7\n\ts_nop 7" ::);  // MFMA result latency
    if (lk < 2) {
#pragma unroll
      for (int r = 0; r < 4; ++r)
        sG[w][(lk << 2) + r][ln] = a0[r] + a1[r] + a2[r];
    }
    __syncthreads();

    // cell update + packed h store
    if (tid < 128) {
      const int b = tid >> 4, j = tid & 15;
      const float gi = sG[0][b][j] + sgb[b][j];
      const float gf = sG[1][b][j] + sgb[b][16 + j];
      const float gg = sG[2][b][j] + sgb[b][32 + j];
      const float go = sG[3][b][j] + sgb[b][48 + j];
      const float c_old = scell[b][j];
      const float cn = sigf(gf) * c_old + sigf(gi) * tanhf_fast(gg);
      const float hn = sigf(go) * tanhf_fast(cn);
      scell[b][j] = cn;
      const short hi = f2bf(hn);
      const short lo = f2bf(hn - bf2f(hi));
      hsbf[(long)t * B * H + (long)(b8 + b) * H + hc0 + j] =
          (unsigned)(unsigned short)hi | ((unsigned)(unsigned short)lo << 16);
    }
    __syncthreads();  // drains h stores to L2

    if (t < STEPS - 1) {
      unsigned* flags = bar + t * 256 + bg * 32;
      if (fast) {
        if (tid == 0)
          __hip_atomic_fetch_add(&flags[slice], 1u, __ATOMIC_RELAXED,
                                 __HIP_MEMORY_SCOPE_AGENT);
        if (tid < 64) {
          while (!__all(load_u32_cg(flags + (tid & 31)) != 0u)) {}
        }
      } else {
        if (tid == 0)
          __hip_atomic_fetch_add(&flags[slice], 1u, __ATOMIC_RELEASE,
                                 __HIP_MEMORY_SCOPE_AGENT);
        if (tid < 64) {
          while (!__all(load_u32_cg(flags + (tid & 31)) != 0u)) {}
        }
        if (tid == 0)
          (void)__hip_atomic_load(&flags[0], __ATOMIC_ACQUIRE,
                                  __HIP_MEMORY_SCOPE_AGENT);
      }
      __syncthreads();
    }
  }
}

// ---------------- final dec GEMM: out[b,t,:] = h(t,b,:) @ fc_w^T + fc_b ----
// A read from packed split-bf16 hsbf (f = hi + lo, rel err ~2^-17).
__global__ __launch_bounds__(256) void k_dec2(
    const unsigned* __restrict__ hsbf, const float* __restrict__ fc_w,
    const float* __restrict__ fc_b, float* __restrict__ out) {
  __shared__ float A[32 * 68];
  __shared__ float Bm[64 * 68];
  const int m0 = blockIdx.x * 32;
  const int o0 = blockIdx.y * 64;
  const int tid = threadIdx.x;
  const int tn = tid & 15, tm = tid >> 4;
  float acc[2][4] = {{0.f, 0.f, 0.f, 0.f}, {0.f, 0.f, 0.f, 0.f}};
  for (int k0 = 0; k0 < H; k0 += 64) {
    for (int idx = tid; idx < 512; idx += 256) {
      const int r = idx >> 4, k4 = idx & 15;
      const u32x4 v = *(const u32x4*)&hsbf[(long)(m0 + r) * H + k0 + k4 * 4];
#pragma unroll
      for (int e = 0; e < 4; ++e)
        A[r * 68 + k4 * 4 + e] =
            bf2f((short)(v[e] & 0xFFFFu)) + bf2f((short)(v[e] >> 16));
    }
    for (int idx = tid; idx < 1024; idx += 256) {
      const int r = idx >> 4, k4 = idx & 15;
      *(float4*)&Bm[r * 68 + k4 * 4] =
          *(const float4*)&fc_w[(long)(o0 + r) * H + k0 + k4 * 4];
    }
    __syncthreads();
#pragma unroll
    for (int k4 = 0; k4 < 16; ++k4) {
      const float4 a0 = *(float4*)&A[tm * 68 + k4 * 4];
      const float4 a1 = *(float4*)&A[(tm + 16) * 68 + k4 * 4];
      const float4 b0 = *(float4*)&Bm[tn * 68 + k4 * 4];
      const float4 b1 = *(float4*)&Bm[(tn + 16) * 68 + k4 * 4];
      const float4 b2 = *(float4*)&Bm[(tn + 32) * 68 + k4 * 4];
      const float4 b3 = *(float4*)&Bm[(tn + 48) * 68 + k4 * 4];
      acc[0][0] += a0.x * b0.x + a0.y * b0.y + a0.z * b0.z + a0.w * b0.w;
      acc[0][1] += a0.x * b1.x + a0.y * b1.y + a0.z * b1.z + a0.w * b1.w;
      acc[0][2] += a0.x * b2.x + a0.y * b2.y + a0.z * b2.z + a0.w * b2.w;
      acc[0][3] += a0.x * b3.x + a0.y * b3.y + a0.z * b3.z + a0.w * b3.w;
      acc[1][0] += a1.x * b0.x + a1.y * b0.y + a1.z * b0.z + a1.w * b0.w;
      acc[1][1] += a1.x * b1.x + a1.y * b1.y + a1.z * b1.z + a1.w * b1.w;
      acc[1][2] += a1.x * b2.x + a1.y * b2.y + a1.z * b2.z + a1.w * b2.w;
      acc[1][3] += a1.x * b3.x + a1.y * b3.y + a1.z * b3.z + a1.w * b3.w;
    }
    __syncthreads();
  }
#pragma unroll
  for (int i = 0; i < 2; ++i) {
    const int m = m0 + tm + 16 * i;
    const int t = m >> 6, b = m & 63;
#pragma unroll
    for (int j = 0; j < 4; ++j) {
      const int o = o0 + tn + 16 * j;
      out[((long)b * STEPS + t) * OUT + o] = acc[i][j] + fc_b[o];
    }
  }
}

extern "C" void kernel_launch(void* const* d_in, const int* in_sizes, int n_in,
                              void* d_out, int out_size, void* d_ws, size_t ws_size,
                              hipStream_t stream) {
  const float* enc = (const float*)d_in[0];
  const float* hidden = (const float*)d_in[1];
  const float* attn_w = (const float*)d_in[2];
  // d_in[3] = attn_b: constant shift along softmax axis -> irrelevant.
  const float* w_ih = (const float*)d_in[4];
  const float* w_hh = (const float*)d_in[5];
  const float* b_ih = (const float*)d_in[6];
  const float* b_hh = (const float*)d_in[7];
  const float* fc_w = (const float*)d_in[8];
  const float* fc_b = (const float*)d_in[9];
  float* out = (float*)d_out;

  float* ws = (float*)d_ws;
  float* ctx      = ws;                  //   32768 f
  float* part_ctx = ctx + 32768;         //  262144 f
  float* part_ml  = part_ctx + 262144;   //    1024 f
  short* whi      = (short*)(part_ml + 1024);      // 1048576 shorts
  short* wlo      = whi + 1048576;                 // 1048576 shorts
  float* gates0   = (float*)(wlo + 1048576);       //  131072 f
  float* gbase2   = gates0 + 131072;     //  131072 f
  unsigned* hsbf  = (unsigned*)(gbase2 + 131072);  // 1048576 u32 (packed h)
  unsigned int* bar = (unsigned int*)(hsbf + 1048576);  // 7952 u32
  // total ~10.65 MB

  hipMemsetAsync(bar, 0, 7952 * sizeof(unsigned int), stream);
  k_pre<<<1536, 256, 0, stream>>>(enc, attn_w, part_ctx, part_ml,
                                  w_ih, w_hh, fc_w, whi, wlo);
  k_ctx_reduce<<<64, 256, 0, stream>>>(part_ctx, part_ml, ctx);
  k_gbase<<<dim3(64, 4), 256, 0, stream>>>(w_ih, w_hh, b_ih, b_hh, fc_b, ctx,
                                           hidden, gates0, gbase2);

  const short* whi_p = whi;
  const short* wlo_p = wlo;
  const float* gbase2_p = gbase2;
  const float* gates0_p = gates0;
  unsigned* hsbf_p = hsbf;
  unsigned int* bar_p = bar;
  void* kargs[] = {(void*)&whi_p, (void*)&wlo_p, (void*)&gbase2_p,
                   (void*)&gates0_p, (void*)&hsbf_p, (void*)&bar_p};
  hipLaunchCooperativeKernel(reinterpret_cast<const void*>(k_recur3), dim3(256),
                             dim3(256), kargs, 0, stream);

  k_dec2<<<dim3(64, 4), 256, 0, stream>>>(hsbf, fc_w, fc_b, out);
}

// Round 12
// 242.125 us; speedup vs baseline: 2.9853x; 1.0166x over previous
//
#include <hip/hip_runtime.h>
#include <math.h>

#define B 64
#define S 1024
#define H 512
#define OUT 256
#define STEPS 32
#define NG 2048   // 4*H
#define X 768     // OUT + H

typedef __attribute__((ext_vector_type(8))) short short8;   // 8 bf16 = 4 VGPR
typedef __attribute__((ext_vector_type(4))) short s16x4;
typedef __attribute__((ext_vector_type(4))) float f32x4;
typedef __attribute__((ext_vector_type(4))) unsigned u32x4;

__device__ __forceinline__ float sigf(float x) { return 1.0f / (1.0f + __expf(-x)); }
// saturation-safe fast tanh: 2*sigmoid(2x)-1
__device__ __forceinline__ float tanhf_fast(float x) {
  return 2.0f / (1.0f + __expf(-2.0f * x)) - 1.0f;
}

__device__ __forceinline__ short f2bf(float x) {  // RNE float->bf16 bits
  union { float f; unsigned u; } a; a.f = x;
  unsigned r = a.u + 0x7fffu + ((a.u >> 16) & 1u);
  return (short)(r >> 16);
}
__device__ __forceinline__ float bf2f(short s) {
  union { unsigned u; float f; } a; a.u = ((unsigned)(unsigned short)s) << 16;
  return a.f;
}

// MALL-visible flag read (bypasses L1/L2) — proven rounds 2/3/6/7/9/10/11.
__device__ __forceinline__ unsigned load_u32_cg(const unsigned* p) {
  unsigned r;
  asm volatile("global_load_dword %0, %1, off sc0 sc1\n\ts_waitcnt vmcnt(0)"
               : "=v"(r) : "v"(p) : "memory");
  return r;
}

// ---------------- fused: ctx flash-partial (blocks 0..511) + tiled Weff
// (blocks 512..767). LDS is a union carve: ctx uses 2056 f, weff 10336 f.
__global__ __launch_bounds__(256) void k_pre(
    const float* __restrict__ enc, const float* __restrict__ attn_w,
    float* __restrict__ part_ctx, float* __restrict__ part_ml,
    const float* __restrict__ w_ih, const float* __restrict__ w_hh,
    const float* __restrict__ fc_w, short* __restrict__ whi,
    short* __restrict__ wlo) {
  __shared__ float smem[10336];  // 41.3 KB
  const int cid = blockIdx.x;
  const int tid = threadIdx.x;
  if (cid < 512) {
    // ---- ctx partial: chunk = cid&7, b = cid>>3 ----
    float* sm_acc = smem;           // [4][512]
    float* sm_m = smem + 2048;      // [4]
    float* sm_l = smem + 2052;      // [4]
    const int b = cid >> 3, chunk = cid & 7;
    const int wave = tid >> 6, lane = tid & 63;
    const float4 wa0 = *(const float4*)(attn_w + lane * 8);
    const float4 wa1 = *(const float4*)(attn_w + lane * 8 + 4);
    const float* eb = enc + (long)b * S * H;
    float m = -1e30f, l = 0.0f;
    float acc[8];
#pragma unroll
    for (int r = 0; r < 8; ++r) acc[r] = 0.0f;
    for (int i = 0; i < 32; ++i) {
      const int s = chunk * 128 + i * 4 + wave;
      const float* row = eb + (long)s * H + lane * 8;
      const float4 v0 = *(const float4*)row;
      const float4 v1 = *(const float4*)(row + 4);
      float e = v0.x * wa0.x + v0.y * wa0.y + v0.z * wa0.z + v0.w * wa0.w +
                v1.x * wa1.x + v1.y * wa1.y + v1.z * wa1.z + v1.w * wa1.w;
#pragma unroll
      for (int msk = 1; msk < 64; msk <<= 1) e += __shfl_xor(e, msk, 64);
      const float mn = fmaxf(m, e);
      const float sc = __expf(m - mn);
      const float p = __expf(e - mn);
      l = l * sc + p;
      m = mn;
      acc[0] = acc[0] * sc + p * v0.x; acc[1] = acc[1] * sc + p * v0.y;
      acc[2] = acc[2] * sc + p * v0.z; acc[3] = acc[3] * sc + p * v0.w;
      acc[4] = acc[4] * sc + p * v1.x; acc[5] = acc[5] * sc + p * v1.y;
      acc[6] = acc[6] * sc + p * v1.z; acc[7] = acc[7] * sc + p * v1.w;
    }
#pragma unroll
    for (int r = 0; r < 8; ++r) sm_acc[wave * 512 + lane * 8 + r] = acc[r];
    if (lane == 0) { sm_m[wave] = m; sm_l[wave] = l; }
    __syncthreads();
    const float mb = fmaxf(fmaxf(sm_m[0], sm_m[1]), fmaxf(sm_m[2], sm_m[3]));
    float e0[4];
#pragma unroll
    for (int w = 0; w < 4; ++w) e0[w] = __expf(sm_m[w] - mb);
    const int h0 = tid * 2;
    float s0 = 0.f, s1 = 0.f;
#pragma unroll
    for (int w = 0; w < 4; ++w) {
      s0 += sm_acc[w * 512 + h0] * e0[w];
      s1 += sm_acc[w * 512 + h0 + 1] * e0[w];
    }
    float* pc = part_ctx + ((long)chunk * B + b) * H;
    pc[h0] = s0; pc[h0 + 1] = s1;
    if (tid == 0) {
      const float lb = sm_l[0] * e0[0] + sm_l[1] * e0[1] + sm_l[2] * e0[2] + sm_l[3] * e0[3];
      part_ml[(chunk * B + b) * 2] = mb;
      part_ml[(chunk * B + b) * 2 + 1] = lb;
    }
  } else {
    // ---- tiled Weff = w_hh + Wd @ fc_w, split-bf16. Block = 8 n-rows. ----
    float* ft = smem;            // [16][516] fc_w j-tile
    float* wd = smem + 8256;     // [8][260]  Wd rows
    const int n0 = (cid - 512) * 8;
    // stage Wd rows (coalesced float4)
    for (int i = tid; i < 512; i += 256) {
      const int r = i >> 6, c4 = (i & 63) << 2;
      *(float4*)&wd[r * 260 + c4] = *(const float4*)(w_ih + (long)(n0 + r) * X + c4);
    }
    float acc[16];
#pragma unroll
    for (int e = 0; e < 16; ++e) acc[e] = 0.f;
    const int n_l = tid >> 5, kq = tid & 31;
    for (int jt = 0; jt < 16; ++jt) {
      __syncthreads();
      for (int i = tid; i < 2048; i += 256) {
        const int r = i >> 7, c4 = (i & 127) << 2;
        *(float4*)&ft[r * 516 + c4] =
            *(const float4*)(fc_w + (long)(jt * 16 + r) * H + c4);
      }
      __syncthreads();
#pragma unroll 4
      for (int j = 0; j < 16; ++j) {
        const float w = wd[n_l * 260 + jt * 16 + j];
#pragma unroll
        for (int e4 = 0; e4 < 4; ++e4) {
          const float4 f = *(float4*)&ft[j * 516 + kq * 4 + e4 * 128];
          acc[e4 * 4 + 0] = fmaf(w, f.x, acc[e4 * 4 + 0]);
          acc[e4 * 4 + 1] = fmaf(w, f.y, acc[e4 * 4 + 1]);
          acc[e4 * 4 + 2] = fmaf(w, f.z, acc[e4 * 4 + 2]);
          acc[e4 * 4 + 3] = fmaf(w, f.w, acc[e4 * 4 + 3]);
        }
      }
    }
    const long rbase = (long)(n0 + n_l) * H;
#pragma unroll
    for (int e4 = 0; e4 < 4; ++e4) {
      const int k = kq * 4 + e4 * 128;
      const float4 hh = *(const float4*)(w_hh + rbase + k);
      float v[4] = {acc[e4 * 4] + hh.x, acc[e4 * 4 + 1] + hh.y,
                    acc[e4 * 4 + 2] + hh.z, acc[e4 * 4 + 3] + hh.w};
      s16x4 hi4, lo4;
#pragma unroll
      for (int e = 0; e < 4; ++e) {
        const short hb = f2bf(v[e]);
        hi4[e] = hb;
        lo4[e] = f2bf(v[e] - bf2f(hb));
      }
      *(s16x4*)(whi + rbase + k) = hi4;
      *(s16x4*)(wlo + rbase + k) = lo4;
    }
  }
}

// ---------------- gates0 / gbase2 — fused ctx-reduce + coalesced LDS-staged -
// rb[r][:] = ctx[b0+r][:] combined from 8 part_ctx chunks with softmax factors.
__global__ __launch_bounds__(256) void k_gbase(
    const float* __restrict__ w_ih, const float* __restrict__ w_hh,
    const float* __restrict__ b_ih, const float* __restrict__ b_hh,
    const float* __restrict__ fc_b, const float* __restrict__ part_ctx,
    const float* __restrict__ part_ml, const float* __restrict__ hidden,
    float* __restrict__ gates0, float* __restrict__ gbase2) {
  __shared__ float wt[128][33];
  __shared__ float rb[16][524];
  __shared__ float sfc[256];
  __shared__ float sf[16][8];
  const int n0 = blockIdx.x * 32, b0 = blockIdx.y * 16;
  const int tid = threadIdx.x;
  const int n_l = tid & 31, bh = tid >> 5;
  const int n = n0 + n_l;

  // per-row softmax combine factors: sf[r][c] = e^{m_c - m} / L
  if (tid < 16) {
    const int r = tid;
    float ml[8], ll[8];
    float m = -1e30f;
#pragma unroll
    for (int c = 0; c < 8; ++c) {
      ml[c] = part_ml[(c * B + b0 + r) * 2];
      ll[c] = part_ml[(c * B + b0 + r) * 2 + 1];
      m = fmaxf(m, ml[c]);
    }
    float L = 0.f;
#pragma unroll
    for (int c = 0; c < 8; ++c) L += ll[c] * __expf(ml[c] - m);
    const float inv = 1.0f / L;
#pragma unroll
    for (int c = 0; c < 8; ++c) sf[r][c] = __expf(ml[c] - m) * inv;
  }
  sfc[tid] = fc_b[tid];
  __syncthreads();

  // stage combined ctx rows
  for (int i = tid; i < 16 * 128; i += 256) {
    const int r = i >> 7, c4 = (i & 127) << 2;
    float4 s = {0.f, 0.f, 0.f, 0.f};
#pragma unroll
    for (int c8 = 0; c8 < 8; ++c8) {
      const float4 p = *(const float4*)(part_ctx + ((long)c8 * B + b0 + r) * H + c4);
      const float f = sf[r][c8];
      s.x = fmaf(p.x, f, s.x); s.y = fmaf(p.y, f, s.y);
      s.z = fmaf(p.z, f, s.z); s.w = fmaf(p.w, f, s.w);
    }
    *(float4*)&rb[r][c4] = s;
  }

  float a1a = 0.f, a1b = 0.f;
  for (int kc = 0; kc < 4; ++kc) {
    __syncthreads();
    for (int i = tid; i < 4096; i += 256) {
      const int r = i >> 7, c = i & 127;
      wt[c][r] = w_ih[(long)(n0 + r) * X + OUT + kc * 128 + c];
    }
    __syncthreads();
#pragma unroll 8
    for (int k = 0; k < 128; ++k) {
      const float wv = wt[k][n_l];
      a1a = fmaf(wv, rb[bh][kc * 128 + k], a1a);
      a1b = fmaf(wv, rb[bh + 8][kc * 128 + k], a1b);
    }
  }

  float db = 0.f;
  for (int kc = 0; kc < 2; ++kc) {
    __syncthreads();
    for (int i = tid; i < 4096; i += 256) {
      const int r = i >> 7, c = i & 127;
      wt[c][r] = w_ih[(long)(n0 + r) * X + kc * 128 + c];
    }
    __syncthreads();
#pragma unroll 8
    for (int k = 0; k < 128; ++k) db = fmaf(wt[k][n_l], sfc[kc * 128 + k], db);
  }

  __syncthreads();
  for (int i = tid; i < 16 * 128; i += 256) {
    const int r = i >> 7, c = (i & 127) << 2;
    *(float4*)&rb[r][c] = *(const float4*)(hidden + (long)(b0 + r) * H + c);
  }
  float a2a = 0.f, a2b = 0.f;
  for (int kc = 0; kc < 4; ++kc) {
    __syncthreads();
    for (int i = tid; i < 4096; i += 256) {
      const int r = i >> 7, c = i & 127;
      wt[c][r] = w_hh[(long)(n0 + r) * H + kc * 128 + c];
    }
    __syncthreads();
#pragma unroll 8
    for (int k = 0; k < 128; ++k) {
      const float wv = wt[k][n_l];
      a2a = fmaf(wv, rb[bh][kc * 128 + k], a2a);
      a2b = fmaf(wv, rb[bh + 8][kc * 128 + k], a2b);
    }
  }

  const float bias = b_ih[n] + b_hh[n];
  gates0[(long)(b0 + bh) * NG + n]     = a1a + bias + a2a;
  gates0[(long)(b0 + bh + 8) * NG + n] = a1b + bias + a2b;
  gbase2[(long)(b0 + bh) * NG + n]     = a1a + bias + db;
  gbase2[(long)(b0 + bh + 8) * NG + n] = a1b + bias + db;
}

// ---------------- persistent recurrence (round-11 proven, verbatim) --------
#define HSTR 520
__global__ __launch_bounds__(256, 1) void k_recur3(
    const short* __restrict__ whi, const short* __restrict__ wlo,
    const float* __restrict__ gb2, const float* __restrict__ gates0,
    unsigned* __restrict__ hsbf, unsigned int* __restrict__ bar) {
  __shared__ short sh_hi[16 * HSTR];
  __shared__ short sh_lo[16 * HSTR];
  __shared__ float sG[4][8][20];
  __shared__ float sgb[8][64];
  __shared__ float scell[8][16];
  __shared__ int s_fast;

  const int blk = blockIdx.x;
  const int bg = blk & 7;
  const int slice = blk >> 3;
  const int b8 = bg << 3;
  const int hc0 = slice << 4;
  const int tid = threadIdx.x;
  const int w = tid >> 6, l = tid & 63;
  const int ln = l & 15, lk = l >> 4;

  // ---- placement vote (vote words at bar[7936..7951]) ----
  if (tid == 0) {
    unsigned xcc;
    asm volatile("s_getreg_b32 %0, hwreg(20, 0, 32)" : "=s"(xcc));  // HW_REG_XCC_ID
    __hip_atomic_fetch_or(&bar[7936 + bg], 1u << (xcc & 0xFu),
                          __ATOMIC_RELEASE, __HIP_MEMORY_SCOPE_AGENT);
    unsigned* gbar = &bar[7944 + bg];
    __hip_atomic_fetch_add(gbar, 1u, __ATOMIC_RELEASE, __HIP_MEMORY_SCOPE_AGENT);
    while (load_u32_cg(gbar) < 32u) __builtin_amdgcn_s_sleep(1);
    const unsigned mask = __hip_atomic_load(&bar[7936 + bg], __ATOMIC_ACQUIRE,
                                            __HIP_MEMORY_SCOPE_AGENT);
    s_fast = (__popc(mask) == 1) ? 1 : 0;
  }
  __syncthreads();
  const bool fast = (s_fast != 0);

  for (int i = tid; i < 16 * HSTR; i += 256) { sh_hi[i] = 0; sh_lo[i] = 0; }

  for (int idx = tid; idx < 512; idx += 256) {
    const int b = idx >> 6, gr = idx & 63, g = gr >> 4, j = gr & 15;
    sgb[b][gr] = gb2[(long)(b8 + b) * NG + (g << 9) + hc0 + j];
  }

  short8 wh[16], wl[16];
  {
    const long wb = (long)((w << 9) + hc0 + ln) * H + (lk << 3);
#pragma unroll
    for (int kk = 0; kk < 16; ++kk) {
      wh[kk] = *(const short8*)(whi + wb + kk * 32);
      wl[kk] = *(const short8*)(wlo + wb + kk * 32);
    }
  }
  __syncthreads();

  // ---- fused step 0: cell update from precomputed gates0 (c0 = 0) ----
  if (tid < 128) {
    const int b = tid >> 4, j = tid & 15;
    const float* g0 = gates0 + (long)(b8 + b) * NG + hc0 + j;
    const float gi = g0[0];
    const float gg = g0[1024];
    const float go = g0[1536];
    const float cn = sigf(gi) * tanhf_fast(gg);
    const float hn = sigf(go) * tanhf_fast(cn);
    scell[b][j] = cn;
    const short hi = f2bf(hn);
    const short lo = f2bf(hn - bf2f(hi));
    hsbf[(long)(b8 + b) * H + hc0 + j] =
        (unsigned)(unsigned short)hi | ((unsigned)(unsigned short)lo << 16);
  }
  __syncthreads();
  {
    unsigned* flags = bar + bg * 32;
    if (fast) {
      if (tid == 0)
        __hip_atomic_fetch_add(&flags[slice], 1u, __ATOMIC_RELAXED,
                               __HIP_MEMORY_SCOPE_AGENT);
      if (tid < 64) {
        while (!__all(load_u32_cg(flags + (tid & 31)) != 0u)) {}
      }
    } else {
      if (tid == 0)
        __hip_atomic_fetch_add(&flags[slice], 1u, __ATOMIC_RELEASE,
                               __HIP_MEMORY_SCOPE_AGENT);
      if (tid < 64) {
        while (!__all(load_u32_cg(flags + (tid & 31)) != 0u)) {}
      }
      if (tid == 0)
        (void)__hip_atomic_load(&flags[0], __ATOMIC_ACQUIRE,
                                __HIP_MEMORY_SCOPE_AGENT);
    }
    __syncthreads();
  }

  for (int t = 1; t < STEPS; ++t) {
    const unsigned* hb = hsbf + (long)(t - 1) * B * H + (long)b8 * H;
#pragma unroll
    for (int q = 0; q < 4; ++q) {
      const int d0 = q * 1024 + tid * 4;
      const u32x4 v = *(const u32x4*)(hb + d0);
      const int row = d0 >> 9, col = d0 & 511;
      s16x4 hi4, lo4;
#pragma unroll
      for (int e = 0; e < 4; ++e) {
        hi4[e] = (short)(v[e] & 0xFFFFu);
        lo4[e] = (short)(v[e] >> 16);
      }
      *(s16x4*)&sh_hi[row * HSTR + col] = hi4;
      *(s16x4*)&sh_lo[row * HSTR + col] = lo4;
    }
    __syncthreads();

    f32x4 a0 = {0.f, 0.f, 0.f, 0.f};
    f32x4 a1 = {0.f, 0.f, 0.f, 0.f};
    f32x4 a2 = {0.f, 0.f, 0.f, 0.f};
    asm volatile("s_nop 3" ::);
    const int abase = ln * HSTR + (lk << 3);
#pragma unroll
    for (int kk = 0; kk < 16; ++kk) {
      const short8 ah = *(const short8*)&sh_hi[abase + kk * 32];
      const short8 al = *(const short8*)&sh_lo[abase + kk * 32];
      asm volatile("v_mfma_f32_16x16x32_bf16 %0, %1, %2, %0"
                   : "+v"(a0) : "v"(ah), "a"(wh[kk]));
      asm volatile("v_mfma_f32_16x16x32_bf16 %0, %1, %2, %0"
                   : "+v"(a1) : "v"(al), "a"(wh[kk]));
      asm volatile("v_mfma_f32_16x16x32_bf16 %0, %1, %2, %0"
                   : "+v"(a2) : "v"(ah), "a"(wl[kk]));
    }
    asm volatile("s_nop 7\n\ts_nop 7" ::);
    if (lk < 2) {
#pragma unroll
      for (int r = 0; r < 4; ++r)
        sG[w][(lk << 2) + r][ln] = a0[r] + a1[r] + a2[r];
    }
    __syncthreads();

    if (tid < 128) {
      const int b = tid >> 4, j = tid & 15;
      const float gi = sG[0][b][j] + sgb[b][j];
      const float gf = sG[1][b][j] + sgb[b][16 + j];
      const float gg = sG[2][b][j] + sgb[b][32 + j];
      const float go = sG[3][b][j] + sgb[b][48 + j];
      const float c_old = scell[b][j];
      const float cn = sigf(gf) * c_old + sigf(gi) * tanhf_fast(gg);
      const float hn = sigf(go) * tanhf_fast(cn);
      scell[b][j] = cn;
      const short hi = f2bf(hn);
      const short lo = f2bf(hn - bf2f(hi));
      hsbf[(long)t * B * H + (long)(b8 + b) * H + hc0 + j] =
          (unsigned)(unsigned short)hi | ((unsigned)(unsigned short)lo << 16);
    }
    __syncthreads();

    if (t < STEPS - 1) {
      unsigned* flags = bar + t * 256 + bg * 32;
      if (fast) {
        if (tid == 0)
          __hip_atomic_fetch_add(&flags[slice], 1u, __ATOMIC_RELAXED,
                                 __HIP_MEMORY_SCOPE_AGENT);
        if (tid < 64) {
          while (!__all(load_u32_cg(flags + (tid & 31)) != 0u)) {}
        }
      } else {
        if (tid == 0)
          __hip_atomic_fetch_add(&flags[slice], 1u, __ATOMIC_RELEASE,
                                 __HIP_MEMORY_SCOPE_AGENT);
        if (tid < 64) {
          while (!__all(load_u32_cg(flags + (tid & 31)) != 0u)) {}
        }
        if (tid == 0)
          (void)__hip_atomic_load(&flags[0], __ATOMIC_ACQUIRE,
                                  __HIP_MEMORY_SCOPE_AGENT);
      }
      __syncthreads();
    }
  }
}

// ---------------- final dec GEMM (round-11 proven, verbatim) ---------------
__global__ __launch_bounds__(256) void k_dec2(
    const unsigned* __restrict__ hsbf, const float* __restrict__ fc_w,
    const float* __restrict__ fc_b, float* __restrict__ out) {
  __shared__ float A[32 * 68];
  __shared__ float Bm[64 * 68];
  const int m0 = blockIdx.x * 32;
  const int o0 = blockIdx.y * 64;
  const int tid = threadIdx.x;
  const int tn = tid & 15, tm = tid >> 4;
  float acc[2][4] = {{0.f, 0.f, 0.f, 0.f}, {0.f, 0.f, 0.f, 0.f}};
  for (int k0 = 0; k0 < H; k0 += 64) {
    for (int idx = tid; idx < 512; idx += 256) {
      const int r = idx >> 4, k4 = idx & 15;
      const u32x4 v = *(const u32x4*)&hsbf[(long)(m0 + r) * H + k0 + k4 * 4];
#pragma unroll
      for (int e = 0; e < 4; ++e)
        A[r * 68 + k4 * 4 + e] =
            bf2f((short)(v[e] & 0xFFFFu)) + bf2f((short)(v[e] >> 16));
    }
    for (int idx = tid; idx < 1024; idx += 256) {
      const int r = idx >> 4, k4 = idx & 15;
      *(float4*)&Bm[r * 68 + k4 * 4] =
          *(const float4*)&fc_w[(long)(o0 + r) * H + k0 + k4 * 4];
    }
    __syncthreads();
#pragma unroll
    for (int k4 = 0; k4 < 16; ++k4) {
      const float4 a0 = *(float4*)&A[tm * 68 + k4 * 4];
      const float4 a1 = *(float4*)&A[(tm + 16) * 68 + k4 * 4];
      const float4 b0 = *(float4*)&Bm[tn * 68 + k4 * 4];
      const float4 b1 = *(float4*)&Bm[(tn + 16) * 68 + k4 * 4];
      const float4 b2 = *(float4*)&Bm[(tn + 32) * 68 + k4 * 4];
      const float4 b3 = *(float4*)&Bm[(tn + 48) * 68 + k4 * 4];
      acc[0][0] += a0.x * b0.x + a0.y * b0.y + a0.z * b0.z + a0.w * b0.w;
      acc[0][1] += a0.x * b1.x + a0.y * b1.y + a0.z * b1.z + a0.w * b1.w;
      acc[0][2] += a0.x * b2.x + a0.y * b2.y + a0.z * b2.z + a0.w * b2.w;
      acc[0][3] += a0.x * b3.x + a0.y * b3.y + a0.z * b3.z + a0.w * b3.w;
      acc[1][0] += a1.x * b0.x + a1.y * b0.y + a1.z * b0.z + a1.w * b0.w;
      acc[1][1] += a1.x * b1.x + a1.y * b1.y + a1.z * b1.z + a1.w * b1.w;
      acc[1][2] += a1.x * b2.x + a1.y * b2.y + a1.z * b2.z + a1.w * b2.w;
      acc[1][3] += a1.x * b3.x + a1.y * b3.y + a1.z * b3.z + a1.w * b3.w;
    }
    __syncthreads();
  }
#pragma unroll
  for (int i = 0; i < 2; ++i) {
    const int m = m0 + tm + 16 * i;
    const int t = m >> 6, b = m & 63;
#pragma unroll
    for (int j = 0; j < 4; ++j) {
      const int o = o0 + tn + 16 * j;
      out[((long)b * STEPS + t) * OUT + o] = acc[i][j] + fc_b[o];
    }
  }
}

extern "C" void kernel_launch(void* const* d_in, const int* in_sizes, int n_in,
                              void* d_out, int out_size, void* d_ws, size_t ws_size,
                              hipStream_t stream) {
  const float* enc = (const float*)d_in[0];
  const float* hidden = (const float*)d_in[1];
  const float* attn_w = (const float*)d_in[2];
  // d_in[3] = attn_b: constant shift along softmax axis -> irrelevant.
  const float* w_ih = (const float*)d_in[4];
  const float* w_hh = (const float*)d_in[5];
  const float* b_ih = (const float*)d_in[6];
  const float* b_hh = (const float*)d_in[7];
  const float* fc_w = (const float*)d_in[8];
  const float* fc_b = (const float*)d_in[9];
  float* out = (float*)d_out;

  float* ws = (float*)d_ws;
  float* part_ctx = ws;                  //  262144 f
  float* part_ml  = part_ctx + 262144;   //    1024 f
  short* whi      = (short*)(part_ml + 1024);      // 1048576 shorts
  short* wlo      = whi + 1048576;                 // 1048576 shorts
  float* gates0   = (float*)(wlo + 1048576);       //  131072 f
  float* gbase2   = gates0 + 131072;     //  131072 f
  unsigned* hsbf  = (unsigned*)(gbase2 + 131072);  // 1048576 u32 (packed h)
  unsigned int* bar = (unsigned int*)(hsbf + 1048576);  // 7952 u32
  // total ~10.5 MB

  hipMemsetAsync(bar, 0, 7952 * sizeof(unsigned int), stream);
  k_pre<<<768, 256, 0, stream>>>(enc, attn_w, part_ctx, part_ml,
                                 w_ih, w_hh, fc_w, whi, wlo);
  k_gbase<<<dim3(64, 4), 256, 0, stream>>>(w_ih, w_hh, b_ih, b_hh, fc_b,
                                           part_ctx, part_ml, hidden,
                                           gates0, gbase2);

  const short* whi_p = whi;
  const short* wlo_p = wlo;
  const float* gbase2_p = gbase2;
  const float* gates0_p = gates0;
  unsigned* hsbf_p = hsbf;
  unsigned int* bar_p = bar;
  void* kargs[] = {(void*)&whi_p, (void*)&wlo_p, (void*)&gbase2_p,
                   (void*)&gates0_p, (void*)&hsbf_p, (void*)&bar_p};
  hipLaunchCooperativeKernel(reinterpret_cast<const void*>(k_recur3), dim3(256),
                             dim3(256), kargs, 0, stream);

  k_dec2<<<dim3(64, 4), 256, 0, stream>>>(hsbf, fc_w, fc_b, out);
}

// Round 13
// 221.710 us; speedup vs baseline: 3.2602x; 1.0921x over previous
//
#include <hip/hip_runtime.h>
#include <math.h>

#define B 64
#define S 1024
#define H 512
#define OUT 256
#define STEPS 32
#define NG 2048   // 4*H
#define X 768     // OUT + H

typedef __attribute__((ext_vector_type(8))) short short8;   // 8 bf16 = 4 VGPR
typedef __attribute__((ext_vector_type(4))) short s16x4;
typedef __attribute__((ext_vector_type(4))) float f32x4;
typedef __attribute__((ext_vector_type(4))) unsigned u32x4;

__device__ __forceinline__ float sigf(float x) { return 1.0f / (1.0f + __expf(-x)); }
// saturation-safe fast tanh: 2*sigmoid(2x)-1
__device__ __forceinline__ float tanhf_fast(float x) {
  return 2.0f / (1.0f + __expf(-2.0f * x)) - 1.0f;
}

__device__ __forceinline__ short f2bf(float x) {  // RNE float->bf16 bits
  union { float f; unsigned u; } a; a.f = x;
  unsigned r = a.u + 0x7fffu + ((a.u >> 16) & 1u);
  return (short)(r >> 16);
}
__device__ __forceinline__ float bf2f(short s) {
  union { unsigned u; float f; } a; a.u = ((unsigned)(unsigned short)s) << 16;
  return a.f;
}

// MALL-visible flag read (bypasses L1/L2) — proven rounds 2/3/6/7/9/10/11/12.
__device__ __forceinline__ unsigned load_u32_cg(const unsigned* p) {
  unsigned r;
  asm volatile("global_load_dword %0, %1, off sc0 sc1\n\ts_waitcnt vmcnt(0)"
               : "=v"(r) : "v"(p) : "memory");
  return r;
}

// ---------------- fused: ctx flash-partial (blocks 0..511) + tiled Weff
// (blocks 512..767). LDS is a union carve: ctx uses 2056 f, weff 10336 f.
__global__ __launch_bounds__(256) void k_pre(
    const float* __restrict__ enc, const float* __restrict__ attn_w,
    float* __restrict__ part_ctx, float* __restrict__ part_ml,
    const float* __restrict__ w_ih, const float* __restrict__ w_hh,
    const float* __restrict__ fc_w, short* __restrict__ whi,
    short* __restrict__ wlo) {
  __shared__ float smem[10336];  // 41.3 KB
  const int cid = blockIdx.x;
  const int tid = threadIdx.x;
  if (cid < 512) {
    // ---- ctx partial: chunk = cid&7, b = cid>>3 ----
    float* sm_acc = smem;           // [4][512]
    float* sm_m = smem + 2048;      // [4]
    float* sm_l = smem + 2052;      // [4]
    const int b = cid >> 3, chunk = cid & 7;
    const int wave = tid >> 6, lane = tid & 63;
    const float4 wa0 = *(const float4*)(attn_w + lane * 8);
    const float4 wa1 = *(const float4*)(attn_w + lane * 8 + 4);
    const float* eb = enc + (long)b * S * H;
    float m = -1e30f, l = 0.0f;
    float acc[8];
#pragma unroll
    for (int r = 0; r < 8; ++r) acc[r] = 0.0f;
    for (int i = 0; i < 32; ++i) {
      const int s = chunk * 128 + i * 4 + wave;
      const float* row = eb + (long)s * H + lane * 8;
      const float4 v0 = *(const float4*)row;
      const float4 v1 = *(const float4*)(row + 4);
      float e = v0.x * wa0.x + v0.y * wa0.y + v0.z * wa0.z + v0.w * wa0.w +
                v1.x * wa1.x + v1.y * wa1.y + v1.z * wa1.z + v1.w * wa1.w;
#pragma unroll
      for (int msk = 1; msk < 64; msk <<= 1) e += __shfl_xor(e, msk, 64);
      const float mn = fmaxf(m, e);
      const float sc = __expf(m - mn);
      const float p = __expf(e - mn);
      l = l * sc + p;
      m = mn;
      acc[0] = acc[0] * sc + p * v0.x; acc[1] = acc[1] * sc + p * v0.y;
      acc[2] = acc[2] * sc + p * v0.z; acc[3] = acc[3] * sc + p * v0.w;
      acc[4] = acc[4] * sc + p * v1.x; acc[5] = acc[5] * sc + p * v1.y;
      acc[6] = acc[6] * sc + p * v1.z; acc[7] = acc[7] * sc + p * v1.w;
    }
#pragma unroll
    for (int r = 0; r < 8; ++r) sm_acc[wave * 512 + lane * 8 + r] = acc[r];
    if (lane == 0) { sm_m[wave] = m; sm_l[wave] = l; }
    __syncthreads();
    const float mb = fmaxf(fmaxf(sm_m[0], sm_m[1]), fmaxf(sm_m[2], sm_m[3]));
    float e0[4];
#pragma unroll
    for (int w = 0; w < 4; ++w) e0[w] = __expf(sm_m[w] - mb);
    const int h0 = tid * 2;
    float s0 = 0.f, s1 = 0.f;
#pragma unroll
    for (int w = 0; w < 4; ++w) {
      s0 += sm_acc[w * 512 + h0] * e0[w];
      s1 += sm_acc[w * 512 + h0 + 1] * e0[w];
    }
    float* pc = part_ctx + ((long)chunk * B + b) * H;
    pc[h0] = s0; pc[h0 + 1] = s1;
    if (tid == 0) {
      const float lb = sm_l[0] * e0[0] + sm_l[1] * e0[1] + sm_l[2] * e0[2] + sm_l[3] * e0[3];
      part_ml[(chunk * B + b) * 2] = mb;
      part_ml[(chunk * B + b) * 2 + 1] = lb;
    }
  } else {
    // ---- tiled Weff = w_hh + Wd @ fc_w, split-bf16. Block = 8 n-rows. ----
    float* ft = smem;            // [16][516] fc_w j-tile
    float* wd = smem + 8256;     // [8][260]  Wd rows
    const int n0 = (cid - 512) * 8;
    for (int i = tid; i < 512; i += 256) {
      const int r = i >> 6, c4 = (i & 63) << 2;
      *(float4*)&wd[r * 260 + c4] = *(const float4*)(w_ih + (long)(n0 + r) * X + c4);
    }
    float acc[16];
#pragma unroll
    for (int e = 0; e < 16; ++e) acc[e] = 0.f;
    const int n_l = tid >> 5, kq = tid & 31;
    for (int jt = 0; jt < 16; ++jt) {
      __syncthreads();
      for (int i = tid; i < 2048; i += 256) {
        const int r = i >> 7, c4 = (i & 127) << 2;
        *(float4*)&ft[r * 516 + c4] =
            *(const float4*)(fc_w + (long)(jt * 16 + r) * H + c4);
      }
      __syncthreads();
#pragma unroll 4
      for (int j = 0; j < 16; ++j) {
        const float w = wd[n_l * 260 + jt * 16 + j];
#pragma unroll
        for (int e4 = 0; e4 < 4; ++e4) {
          const float4 f = *(float4*)&ft[j * 516 + kq * 4 + e4 * 128];
          acc[e4 * 4 + 0] = fmaf(w, f.x, acc[e4 * 4 + 0]);
          acc[e4 * 4 + 1] = fmaf(w, f.y, acc[e4 * 4 + 1]);
          acc[e4 * 4 + 2] = fmaf(w, f.z, acc[e4 * 4 + 2]);
          acc[e4 * 4 + 3] = fmaf(w, f.w, acc[e4 * 4 + 3]);
        }
      }
    }
    const long rbase = (long)(n0 + n_l) * H;
#pragma unroll
    for (int e4 = 0; e4 < 4; ++e4) {
      const int k = kq * 4 + e4 * 128;
      const float4 hh = *(const float4*)(w_hh + rbase + k);
      float v[4] = {acc[e4 * 4] + hh.x, acc[e4 * 4 + 1] + hh.y,
                    acc[e4 * 4 + 2] + hh.z, acc[e4 * 4 + 3] + hh.w};
      s16x4 hi4, lo4;
#pragma unroll
      for (int e = 0; e < 4; ++e) {
        const short hb = f2bf(v[e]);
        hi4[e] = hb;
        lo4[e] = f2bf(v[e] - bf2f(hb));
      }
      *(s16x4*)(whi + rbase + k) = hi4;
      *(s16x4*)(wlo + rbase + k) = lo4;
    }
  }
}

// ---------------- gates0 / gbase2 — fused ctx-reduce + coalesced LDS-staged -
__global__ __launch_bounds__(256) void k_gbase(
    const float* __restrict__ w_ih, const float* __restrict__ w_hh,
    const float* __restrict__ b_ih, const float* __restrict__ b_hh,
    const float* __restrict__ fc_b, const float* __restrict__ part_ctx,
    const float* __restrict__ part_ml, const float* __restrict__ hidden,
    float* __restrict__ gates0, float* __restrict__ gbase2) {
  __shared__ float wt[128][33];
  __shared__ float rb[16][524];
  __shared__ float sfc[256];
  __shared__ float sf[16][8];
  const int n0 = blockIdx.x * 32, b0 = blockIdx.y * 16;
  const int tid = threadIdx.x;
  const int n_l = tid & 31, bh = tid >> 5;
  const int n = n0 + n_l;

  if (tid < 16) {
    const int r = tid;
    float ml[8], ll[8];
    float m = -1e30f;
#pragma unroll
    for (int c = 0; c < 8; ++c) {
      ml[c] = part_ml[(c * B + b0 + r) * 2];
      ll[c] = part_ml[(c * B + b0 + r) * 2 + 1];
      m = fmaxf(m, ml[c]);
    }
    float L = 0.f;
#pragma unroll
    for (int c = 0; c < 8; ++c) L += ll[c] * __expf(ml[c] - m);
    const float inv = 1.0f / L;
#pragma unroll
    for (int c = 0; c < 8; ++c) sf[r][c] = __expf(ml[c] - m) * inv;
  }
  sfc[tid] = fc_b[tid];
  __syncthreads();

  for (int i = tid; i < 16 * 128; i += 256) {
    const int r = i >> 7, c4 = (i & 127) << 2;
    float4 s = {0.f, 0.f, 0.f, 0.f};
#pragma unroll
    for (int c8 = 0; c8 < 8; ++c8) {
      const float4 p = *(const float4*)(part_ctx + ((long)c8 * B + b0 + r) * H + c4);
      const float f = sf[r][c8];
      s.x = fmaf(p.x, f, s.x); s.y = fmaf(p.y, f, s.y);
      s.z = fmaf(p.z, f, s.z); s.w = fmaf(p.w, f, s.w);
    }
    *(float4*)&rb[r][c4] = s;
  }

  float a1a = 0.f, a1b = 0.f;
  for (int kc = 0; kc < 4; ++kc) {
    __syncthreads();
    for (int i = tid; i < 4096; i += 256) {
      const int r = i >> 7, c = i & 127;
      wt[c][r] = w_ih[(long)(n0 + r) * X + OUT + kc * 128 + c];
    }
    __syncthreads();
#pragma unroll 8
    for (int k = 0; k < 128; ++k) {
      const float wv = wt[k][n_l];
      a1a = fmaf(wv, rb[bh][kc * 128 + k], a1a);
      a1b = fmaf(wv, rb[bh + 8][kc * 128 + k], a1b);
    }
  }

  float db = 0.f;
  for (int kc = 0; kc < 2; ++kc) {
    __syncthreads();
    for (int i = tid; i < 4096; i += 256) {
      const int r = i >> 7, c = i & 127;
      wt[c][r] = w_ih[(long)(n0 + r) * X + kc * 128 + c];
    }
    __syncthreads();
#pragma unroll 8
    for (int k = 0; k < 128; ++k) db = fmaf(wt[k][n_l], sfc[kc * 128 + k], db);
  }

  __syncthreads();
  for (int i = tid; i < 16 * 128; i += 256) {
    const int r = i >> 7, c = (i & 127) << 2;
    *(float4*)&rb[r][c] = *(const float4*)(hidden + (long)(b0 + r) * H + c);
  }
  float a2a = 0.f, a2b = 0.f;
  for (int kc = 0; kc < 4; ++kc) {
    __syncthreads();
    for (int i = tid; i < 4096; i += 256) {
      const int r = i >> 7, c = i & 127;
      wt[c][r] = w_hh[(long)(n0 + r) * H + kc * 128 + c];
    }
    __syncthreads();
#pragma unroll 8
    for (int k = 0; k < 128; ++k) {
      const float wv = wt[k][n_l];
      a2a = fmaf(wv, rb[bh][kc * 128 + k], a2a);
      a2b = fmaf(wv, rb[bh + 8][kc * 128 + k], a2b);
    }
  }

  const float bias = b_ih[n] + b_hh[n];
  gates0[(long)(b0 + bh) * NG + n]     = a1a + bias + a2a;
  gates0[(long)(b0 + bh + 8) * NG + n] = a1b + bias + a2b;
  gbase2[(long)(b0 + bh) * NG + n]     = a1a + bias + db;
  gbase2[(long)(b0 + bh + 8) * NG + n] = a1b + bias + db;
}

// ---------------- persistent recurrence (round-11/12 proven kernel,
// now launched as a PLAIN kernel: co-residency is guaranteed by capacity
// (256 blocks, 38.9KB LDS -> >=4 blocks/CU by LDS, 88 VGPR -> >=2 blocks/CU;
// capacity >= 2x grid), so the hand-rolled barriers are deadlock-free
// without cooperative-launch semantics. Kernel body unchanged. -----------
#define HSTR 520
__global__ __launch_bounds__(256, 1) void k_recur3(
    const short* __restrict__ whi, const short* __restrict__ wlo,
    const float* __restrict__ gb2, const float* __restrict__ gates0,
    unsigned* __restrict__ hsbf, unsigned int* __restrict__ bar) {
  __shared__ short sh_hi[16 * HSTR];
  __shared__ short sh_lo[16 * HSTR];
  __shared__ float sG[4][8][20];
  __shared__ float sgb[8][64];
  __shared__ float scell[8][16];
  __shared__ int s_fast;

  const int blk = blockIdx.x;
  const int bg = blk & 7;
  const int slice = blk >> 3;
  const int b8 = bg << 3;
  const int hc0 = slice << 4;
  const int tid = threadIdx.x;
  const int w = tid >> 6, l = tid & 63;
  const int ln = l & 15, lk = l >> 4;

  // ---- placement vote (vote words at bar[7936..7951]) ----
  if (tid == 0) {
    unsigned xcc;
    asm volatile("s_getreg_b32 %0, hwreg(20, 0, 32)" : "=s"(xcc));  // HW_REG_XCC_ID
    __hip_atomic_fetch_or(&bar[7936 + bg], 1u << (xcc & 0xFu),
                          __ATOMIC_RELEASE, __HIP_MEMORY_SCOPE_AGENT);
    unsigned* gbar = &bar[7944 + bg];
    __hip_atomic_fetch_add(gbar, 1u, __ATOMIC_RELEASE, __HIP_MEMORY_SCOPE_AGENT);
    while (load_u32_cg(gbar) < 32u) __builtin_amdgcn_s_sleep(1);
    const unsigned mask = __hip_atomic_load(&bar[7936 + bg], __ATOMIC_ACQUIRE,
                                            __HIP_MEMORY_SCOPE_AGENT);
    s_fast = (__popc(mask) == 1) ? 1 : 0;
  }
  __syncthreads();
  const bool fast = (s_fast != 0);

  for (int i = tid; i < 16 * HSTR; i += 256) { sh_hi[i] = 0; sh_lo[i] = 0; }

  for (int idx = tid; idx < 512; idx += 256) {
    const int b = idx >> 6, gr = idx & 63, g = gr >> 4, j = gr & 15;
    sgb[b][gr] = gb2[(long)(b8 + b) * NG + (g << 9) + hc0 + j];
  }

  short8 wh[16], wl[16];
  {
    const long wb = (long)((w << 9) + hc0 + ln) * H + (lk << 3);
#pragma unroll
    for (int kk = 0; kk < 16; ++kk) {
      wh[kk] = *(const short8*)(whi + wb + kk * 32);
      wl[kk] = *(const short8*)(wlo + wb + kk * 32);
    }
  }
  __syncthreads();

  // ---- fused step 0: cell update from precomputed gates0 (c0 = 0) ----
  if (tid < 128) {
    const int b = tid >> 4, j = tid & 15;
    const float* g0 = gates0 + (long)(b8 + b) * NG + hc0 + j;
    const float gi = g0[0];
    const float gg = g0[1024];
    const float go = g0[1536];
    const float cn = sigf(gi) * tanhf_fast(gg);
    const float hn = sigf(go) * tanhf_fast(cn);
    scell[b][j] = cn;
    const short hi = f2bf(hn);
    const short lo = f2bf(hn - bf2f(hi));
    hsbf[(long)(b8 + b) * H + hc0 + j] =
        (unsigned)(unsigned short)hi | ((unsigned)(unsigned short)lo << 16);
  }
  __syncthreads();
  {
    unsigned* flags = bar + bg * 32;
    if (fast) {
      if (tid == 0)
        __hip_atomic_fetch_add(&flags[slice], 1u, __ATOMIC_RELAXED,
                               __HIP_MEMORY_SCOPE_AGENT);
      if (tid < 64) {
        while (!__all(load_u32_cg(flags + (tid & 31)) != 0u)) {}
      }
    } else {
      if (tid == 0)
        __hip_atomic_fetch_add(&flags[slice], 1u, __ATOMIC_RELEASE,
                               __HIP_MEMORY_SCOPE_AGENT);
      if (tid < 64) {
        while (!__all(load_u32_cg(flags + (tid & 31)) != 0u)) {}
      }
      if (tid == 0)
        (void)__hip_atomic_load(&flags[0], __ATOMIC_ACQUIRE,
                                __HIP_MEMORY_SCOPE_AGENT);
    }
    __syncthreads();
  }

  for (int t = 1; t < STEPS; ++t) {
    const unsigned* hb = hsbf + (long)(t - 1) * B * H + (long)b8 * H;
#pragma unroll
    for (int q = 0; q < 4; ++q) {
      const int d0 = q * 1024 + tid * 4;
      const u32x4 v = *(const u32x4*)(hb + d0);
      const int row = d0 >> 9, col = d0 & 511;
      s16x4 hi4, lo4;
#pragma unroll
      for (int e = 0; e < 4; ++e) {
        hi4[e] = (short)(v[e] & 0xFFFFu);
        lo4[e] = (short)(v[e] >> 16);
      }
      *(s16x4*)&sh_hi[row * HSTR + col] = hi4;
      *(s16x4*)&sh_lo[row * HSTR + col] = lo4;
    }
    __syncthreads();

    f32x4 a0 = {0.f, 0.f, 0.f, 0.f};
    f32x4 a1 = {0.f, 0.f, 0.f, 0.f};
    f32x4 a2 = {0.f, 0.f, 0.f, 0.f};
    asm volatile("s_nop 3" ::);
    const int abase = ln * HSTR + (lk << 3);
#pragma unroll
    for (int kk = 0; kk < 16; ++kk) {
      const short8 ah = *(const short8*)&sh_hi[abase + kk * 32];
      const short8 al = *(const short8*)&sh_lo[abase + kk * 32];
      asm volatile("v_mfma_f32_16x16x32_bf16 %0, %1, %2, %0"
                   : "+v"(a0) : "v"(ah), "a"(wh[kk]));
      asm volatile("v_mfma_f32_16x16x32_bf16 %0, %1, %2, %0"
                   : "+v"(a1) : "v"(al), "a"(wh[kk]));
      asm volatile("v_mfma_f32_16x16x32_bf16 %0, %1, %2, %0"
                   : "+v"(a2) : "v"(ah), "a"(wl[kk]));
    }
    asm volatile("s_nop 7\n\ts_nop 7" ::);
    if (lk < 2) {
#pragma unroll
      for (int r = 0; r < 4; ++r)
        sG[w][(lk << 2) + r][ln] = a0[r] + a1[r] + a2[r];
    }
    __syncthreads();

    if (tid < 128) {
      const int b = tid >> 4, j = tid & 15;
      const float gi = sG[0][b][j] + sgb[b][j];
      const float gf = sG[1][b][j] + sgb[b][16 + j];
      const float gg = sG[2][b][j] + sgb[b][32 + j];
      const float go = sG[3][b][j] + sgb[b][48 + j];
      const float c_old = scell[b][j];
      const float cn = sigf(gf) * c_old + sigf(gi) * tanhf_fast(gg);
      const float hn = sigf(go) * tanhf_fast(cn);
      scell[b][j] = cn;
      const short hi = f2bf(hn);
      const short lo = f2bf(hn - bf2f(hi));
      hsbf[(long)t * B * H + (long)(b8 + b) * H + hc0 + j] =
          (unsigned)(unsigned short)hi | ((unsigned)(unsigned short)lo << 16);
    }
    __syncthreads();

    if (t < STEPS - 1) {
      unsigned* flags = bar + t * 256 + bg * 32;
      if (fast) {
        if (tid == 0)
          __hip_atomic_fetch_add(&flags[slice], 1u, __ATOMIC_RELAXED,
                                 __HIP_MEMORY_SCOPE_AGENT);
        if (tid < 64) {
          while (!__all(load_u32_cg(flags + (tid & 31)) != 0u)) {}
        }
      } else {
        if (tid == 0)
          __hip_atomic_fetch_add(&flags[slice], 1u, __ATOMIC_RELEASE,
                                 __HIP_MEMORY_SCOPE_AGENT);
        if (tid < 64) {
          while (!__all(load_u32_cg(flags + (tid & 31)) != 0u)) {}
        }
        if (tid == 0)
          (void)__hip_atomic_load(&flags[0], __ATOMIC_ACQUIRE,
                                  __HIP_MEMORY_SCOPE_AGENT);
      }
      __syncthreads();
    }
  }
}

// ---------------- final dec GEMM (round-11 proven, verbatim) ---------------
__global__ __launch_bounds__(256) void k_dec2(
    const unsigned* __restrict__ hsbf, const float* __restrict__ fc_w,
    const float* __restrict__ fc_b, float* __restrict__ out) {
  __shared__ float A[32 * 68];
  __shared__ float Bm[64 * 68];
  const int m0 = blockIdx.x * 32;
  const int o0 = blockIdx.y * 64;
  const int tid = threadIdx.x;
  const int tn = tid & 15, tm = tid >> 4;
  float acc[2][4] = {{0.f, 0.f, 0.f, 0.f}, {0.f, 0.f, 0.f, 0.f}};
  for (int k0 = 0; k0 < H; k0 += 64) {
    for (int idx = tid; idx < 512; idx += 256) {
      const int r = idx >> 4, k4 = idx & 15;
      const u32x4 v = *(const u32x4*)&hsbf[(long)(m0 + r) * H + k0 + k4 * 4];
#pragma unroll
      for (int e = 0; e < 4; ++e)
        A[r * 68 + k4 * 4 + e] =
            bf2f((short)(v[e] & 0xFFFFu)) + bf2f((short)(v[e] >> 16));
    }
    for (int idx = tid; idx < 1024; idx += 256) {
      const int r = idx >> 4, k4 = idx & 15;
      *(float4*)&Bm[r * 68 + k4 * 4] =
          *(const float4*)&fc_w[(long)(o0 + r) * H + k0 + k4 * 4];
    }
    __syncthreads();
#pragma unroll
    for (int k4 = 0; k4 < 16; ++k4) {
      const float4 a0 = *(float4*)&A[tm * 68 + k4 * 4];
      const float4 a1 = *(float4*)&A[(tm + 16) * 68 + k4 * 4];
      const float4 b0 = *(float4*)&Bm[tn * 68 + k4 * 4];
      const float4 b1 = *(float4*)&Bm[(tn + 16) * 68 + k4 * 4];
      const float4 b2 = *(float4*)&Bm[(tn + 32) * 68 + k4 * 4];
      const float4 b3 = *(float4*)&Bm[(tn + 48) * 68 + k4 * 4];
      acc[0][0] += a0.x * b0.x + a0.y * b0.y + a0.z * b0.z + a0.w * b0.w;
      acc[0][1] += a0.x * b1.x + a0.y * b1.y + a0.z * b1.z + a0.w * b1.w;
      acc[0][2] += a0.x * b2.x + a0.y * b2.y + a0.z * b2.z + a0.w * b2.w;
      acc[0][3] += a0.x * b3.x + a0.y * b3.y + a0.z * b3.z + a0.w * b3.w;
      acc[1][0] += a1.x * b0.x + a1.y * b0.y + a1.z * b0.z + a1.w * b0.w;
      acc[1][1] += a1.x * b1.x + a1.y * b1.y + a1.z * b1.z + a1.w * b1.w;
      acc[1][2] += a1.x * b2.x + a1.y * b2.y + a1.z * b2.z + a1.w * b2.w;
      acc[1][3] += a1.x * b3.x + a1.y * b3.y + a1.z * b3.z + a1.w * b3.w;
    }
    __syncthreads();
  }
#pragma unroll
  for (int i = 0; i < 2; ++i) {
    const int m = m0 + tm + 16 * i;
    const int t = m >> 6, b = m & 63;
#pragma unroll
    for (int j = 0; j < 4; ++j) {
      const int o = o0 + tn + 16 * j;
      out[((long)b * STEPS + t) * OUT + o] = acc[i][j] + fc_b[o];
    }
  }
}

extern "C" void kernel_launch(void* const* d_in, const int* in_sizes, int n_in,
                              void* d_out, int out_size, void* d_ws, size_t ws_size,
                              hipStream_t stream) {
  const float* enc = (const float*)d_in[0];
  const float* hidden = (const float*)d_in[1];
  const float* attn_w = (const float*)d_in[2];
  // d_in[3] = attn_b: constant shift along softmax axis -> irrelevant.
  const float* w_ih = (const float*)d_in[4];
  const float* w_hh = (const float*)d_in[5];
  const float* b_ih = (const float*)d_in[6];
  const float* b_hh = (const float*)d_in[7];
  const float* fc_w = (const float*)d_in[8];
  const float* fc_b = (const float*)d_in[9];
  float* out = (float*)d_out;

  float* ws = (float*)d_ws;
  float* part_ctx = ws;                  //  262144 f
  float* part_ml  = part_ctx + 262144;   //    1024 f
  short* whi      = (short*)(part_ml + 1024);      // 1048576 shorts
  short* wlo      = whi + 1048576;                 // 1048576 shorts
  float* gates0   = (float*)(wlo + 1048576);       //  131072 f
  float* gbase2   = gates0 + 131072;     //  131072 f
  unsigned* hsbf  = (unsigned*)(gbase2 + 131072);  // 1048576 u32 (packed h)
  unsigned int* bar = (unsigned int*)(hsbf + 1048576);  // 7952 u32
  // total ~10.5 MB

  hipMemsetAsync(bar, 0, 7952 * sizeof(unsigned int), stream);
  k_pre<<<768, 256, 0, stream>>>(enc, attn_w, part_ctx, part_ml,
                                 w_ih, w_hh, fc_w, whi, wlo);
  k_gbase<<<dim3(64, 4), 256, 0, stream>>>(w_ih, w_hh, b_ih, b_hh, fc_b,
                                           part_ctx, part_ml, hidden,
                                           gates0, gbase2);

  // plain launch (was hipLaunchCooperativeKernel): co-residency guaranteed by
  // capacity (see kernel comment); sync protocol unchanged.
  k_recur3<<<256, 256, 0, stream>>>(whi, wlo, gbase2, gates0, hsbf, bar);

  k_dec2<<<dim3(64, 4), 256, 0, stream>>>(hsbf, fc_w, fc_b, out);
}